// Round 2
// baseline (26250.552 us; speedup 1.0000x reference)
//
#include <hip/hip_runtime.h>
#include <cstdint>
#include <cstddef>

// ---------------- helpers ----------------

__device__ __forceinline__ float sigmoidf_(float x) {
    return 1.0f / (1.0f + __expf(-x));
}

template<int OUT>
__device__ __forceinline__ void load_bias(const float* __restrict__ b, float* __restrict__ acc) {
#pragma unroll
    for (int j = 0; j < OUT; ++j) acc[j] = b[j];
}

template<int OUT>
__device__ __forceinline__ void relu_v(float* __restrict__ acc) {
#pragma unroll
    for (int j = 0; j < OUT; ++j) acc[j] = fmaxf(acc[j], 0.0f);
}

// acc[OUT] += x[IN] @ W[IN,OUT]  (W row-major; W addresses are wave-uniform)
template<int IN, int OUT>
__device__ __forceinline__ void mm_acc(const float* __restrict__ x,
                                       const float* __restrict__ W,
                                       float* __restrict__ acc) {
#pragma unroll 4
    for (int k = 0; k < IN; ++k) {
        const float v = x[k];
#pragma unroll
        for (int j = 0; j < OUT; ++j) acc[j] = fmaf(v, W[k * OUT + j], acc[j]);
    }
}

template<int WIDTH>
__device__ __forceinline__ void load_row(const float* __restrict__ p, float* __restrict__ x) {
#pragma unroll
    for (int k4 = 0; k4 < WIDTH / 4; ++k4) {
        float4 v = reinterpret_cast<const float4*>(p)[k4];
        x[k4 * 4 + 0] = v.x; x[k4 * 4 + 1] = v.y;
        x[k4 * 4 + 2] = v.z; x[k4 * 4 + 3] = v.w;
    }
}

// edge encoder: rbf(16)+raw(2) -> 4 -> 8 (relu after each)
__device__ __forceinline__ void enc_edge(int orig,
                                         const float* __restrict__ dist,
                                         const float* __restrict__ eraw,
                                         const float* __restrict__ We1, const float* __restrict__ be1,
                                         const float* __restrict__ We2, const float* __restrict__ be2,
                                         float* __restrict__ out8) {
    float x[18];
    const float d = dist[orig];
#pragma unroll
    for (int i = 0; i < 16; ++i) {
        const float c = (float)i * (20.0f / 15.0f);
        const float t = d - c;
        x[i] = __expf(-t * t);
    }
    x[16] = eraw[(size_t)orig * 2 + 0];
    x[17] = eraw[(size_t)orig * 2 + 1];
    float h[4];
    load_bias<4>(be1, h);
    mm_acc<18, 4>(x, We1, h);
    relu_v<4>(h);
    load_bias<8>(be2, out8);
    mm_acc<4, 8>(h, We2, out8);
    relu_v<8>(out8);
}

__device__ __forceinline__ int lower_bound_i(const int* __restrict__ a, int n, int key) {
    int lo = 0, hi = n;
    while (lo < hi) {
        int mid = (lo + hi) >> 1;
        if (a[mid] < key) lo = mid + 1; else hi = mid;
    }
    return lo;
}

// ---------------- CSR build ----------------

__global__ void __launch_bounds__(256) k_count(
    const int* __restrict__ senders, const int* __restrict__ receivers,
    int* __restrict__ ideg, int E)
{
    const int e = blockIdx.x * blockDim.x + threadIdx.x;
    if (e >= E) return;
    atomicAdd(&ideg[receivers[e]], 1);
    atomicAdd(&ideg[senders[e]], 1);
}

__global__ void __launch_bounds__(256) k_blocksum(
    const int* __restrict__ ideg, int* __restrict__ bsum, int N)
{
    __shared__ int s[256];
    const int t = threadIdx.x;
    const int i = blockIdx.x * 256 + t;
    s[t] = (i < N) ? ideg[i] : 0;
    __syncthreads();
#pragma unroll
    for (int d = 128; d > 0; d >>= 1) {
        if (t < d) s[t] += s[t + d];
        __syncthreads();
    }
    if (t == 0) bsum[blockIdx.x] = s[0];
}

__global__ void __launch_bounds__(1024) k_scan_partials(int* __restrict__ bsum, int nb)
{
    __shared__ int s[1024];
    const int t = threadIdx.x;
    const int v = (t < nb) ? bsum[t] : 0;
    s[t] = v;
    __syncthreads();
    for (int d = 1; d < 1024; d <<= 1) {
        const int w = (t >= d) ? s[t - d] : 0;
        __syncthreads();
        s[t] += w;
        __syncthreads();
    }
    if (t < nb) bsum[t] = s[t] - v;   // exclusive
}

__global__ void __launch_bounds__(256) k_blockscan(
    const int* __restrict__ ideg, const int* __restrict__ bsum,
    int* __restrict__ offs, int* __restrict__ cursor, int N)
{
    __shared__ int s[256];
    const int t = threadIdx.x;
    const int i = blockIdx.x * 256 + t;
    const int v = (i < N) ? ideg[i] : 0;
    s[t] = v;
    __syncthreads();
    for (int d = 1; d < 256; d <<= 1) {
        const int w = (t >= d) ? s[t - d] : 0;
        __syncthreads();
        s[t] += w;
        __syncthreads();
    }
    if (i < N) {
        const int o = bsum[blockIdx.x] + s[t] - v;
        offs[i] = o;
        cursor[i] = o;
    }
}

__global__ void __launch_bounds__(256) k_scatter(
    const int* __restrict__ senders, const int* __restrict__ receivers,
    int* __restrict__ cursor, int* __restrict__ eidx, int E)
{
    const int e = blockIdx.x * blockDim.x + threadIdx.x;
    if (e >= E) return;
    const int p = atomicAdd(&cursor[receivers[e]], 1);
    eidx[p] = e;                 // dup id e:  sender = senders[e]
    const int q = atomicAdd(&cursor[senders[e]], 1);
    eidx[q] = e + E;             // dup id e+E: sender = receivers[e]
}

// ---------------- kernels ----------------

__global__ void __launch_bounds__(256) node_enc_kernel(
    const float* __restrict__ node_raw, const int* __restrict__ residues,
    const float* __restrict__ emb,
    const float* __restrict__ Wn1, const float* __restrict__ bn1,
    const float* __restrict__ Wn2, const float* __restrict__ bn2,
    float* __restrict__ nf0, int N)
{
    const int n = blockIdx.x * blockDim.x + threadIdx.x;
    if (n >= N) return;
    float h[8];
    load_bias<8>(bn1, h);
    {
        const float* er = emb + (size_t)residues[n] * 32;
        float x[32];
        load_row<32>(er, x);
        mm_acc<32, 8>(x, Wn1, h);
    }
    {
        const float* nr = node_raw + (size_t)n * 51;
#pragma unroll 4
        for (int k = 0; k < 51; ++k) {
            const float v = nr[k];
#pragma unroll
            for (int j = 0; j < 8; ++j) h[j] = fmaf(v, Wn1[(32 + k) * 8 + j], h[j]);
        }
    }
    relu_v<8>(h);
    float o[16];
    load_bias<16>(bn2, o);
    mm_acc<8, 16>(h, Wn2, o);
    relu_v<16>(o);
    float* dst = nf0 + (size_t)n * 16;
#pragma unroll
    for (int j = 0; j < 16; ++j) dst[j] = o[j];
}

// Gather-based aggregation for layer LAYER: for node n, iterate incoming
// duplicated edges, recompute the edge-feature chain in registers, accumulate
// the SUM into agg[n]. No atomics.
template<int LAYER>
__global__ void __launch_bounds__(256) agg_gather_kernel(
    const float* __restrict__ dist, const float* __restrict__ eraw,
    const int* __restrict__ senders, const int* __restrict__ receivers,
    const float* __restrict__ nf0, const float* __restrict__ nf1, const float* __restrict__ nf2,
    const float* __restrict__ eWe1, const float* __restrict__ ebe1,
    const float* __restrict__ eWe2, const float* __restrict__ ebe2,
    const float* __restrict__ We0, const float* __restrict__ Ws0, const float* __restrict__ b0,
    const float* __restrict__ We1, const float* __restrict__ Ws1, const float* __restrict__ b1,
    const float* __restrict__ We2, const float* __restrict__ Ws2, const float* __restrict__ b2,
    const int* __restrict__ offs, const int* __restrict__ ideg, const int* __restrict__ eidx,
    float* __restrict__ agg, int N, int E)
{
    constexpr int TPN = (LAYER == 2) ? 2 : 1;
    constexpr int OE  = (LAYER == 0) ? 16 : (LAYER == 1 ? 32 : 64);
    constexpr int JT  = OE / TPN;

    const int gid = blockIdx.x * blockDim.x + threadIdx.x;
    const int n = gid / TPN;
    const int half = gid % TPN;
    if (n >= N) return;

    const int lo = offs[n];
    const int hi = lo + ideg[n];

    float acc[JT];
#pragma unroll
    for (int j = 0; j < JT; ++j) acc[j] = 0.0f;

    for (int p = lo; p < hi; ++p) {
        const int de = eidx[p];
        const int orig = (de < E) ? de : de - E;
        const int s = (de < E) ? senders[orig] : receivers[orig];

        float enc[8];
        enc_edge(orig, dist, eraw, eWe1, ebe1, eWe2, ebe2, enc);

        float a0[16];
        load_bias<16>(b0, a0);
        mm_acc<8, 16>(enc, We0, a0);
        {
            float x[16];
            load_row<16>(nf0 + (size_t)s * 16, x);
            mm_acc<16, 16>(x, Ws0, a0);
        }
        relu_v<16>(a0);

        if constexpr (LAYER == 0) {
#pragma unroll
            for (int j = 0; j < JT; ++j) acc[j] += a0[j];
        } else {
            float a1[32];
            load_bias<32>(b1, a1);
            mm_acc<16, 32>(a0, We1, a1);
            {
                float x[32];
                load_row<32>(nf1 + (size_t)s * 32, x);
                mm_acc<32, 32>(x, Ws1, a1);
            }
            relu_v<32>(a1);

            if constexpr (LAYER == 1) {
#pragma unroll
                for (int j = 0; j < JT; ++j) acc[j] += a1[j];
            } else {
                // a2 columns [half*JT, half*JT+JT)
                float a2[JT];
#pragma unroll
                for (int j = 0; j < JT; ++j) a2[j] = b2[half * JT + j];
#pragma unroll 4
                for (int k = 0; k < 32; ++k) {
                    const float v = a1[k];
#pragma unroll
                    for (int j = 0; j < JT; ++j)
                        a2[j] = fmaf(v, We2[k * 64 + half * JT + j], a2[j]);
                }
                {
                    const float* xr = nf2 + (size_t)s * 64;
#pragma unroll
                    for (int k4 = 0; k4 < 16; ++k4) {
                        float4 v = reinterpret_cast<const float4*>(xr)[k4];
                        const float vv[4] = {v.x, v.y, v.z, v.w};
#pragma unroll
                        for (int u = 0; u < 4; ++u) {
                            const float val = vv[u];
                            const int k = k4 * 4 + u;
#pragma unroll
                            for (int j = 0; j < JT; ++j)
                                a2[j] = fmaf(val, Ws2[k * 64 + half * JT + j], a2[j]);
                        }
                    }
                }
#pragma unroll
                for (int j = 0; j < JT; ++j) acc[j] += fmaxf(a2[j], 0.0f);
            }
        }
    }

    float* dst = agg + (size_t)n * OE + half * JT;
#pragma unroll
    for (int j = 0; j < JT; ++j) dst[j] = acc[j];
}

// nf_new = relu(nf_in @ Wn + (agg/deg) @ Wi + bn)
template<int INN, int OE, int ON>
__global__ void __launch_bounds__(256) node_layer_kernel(
    const float* __restrict__ nf_in, const float* __restrict__ agg, const int* __restrict__ ideg,
    const float* __restrict__ Wn, const float* __restrict__ Wi, const float* __restrict__ bn,
    float* __restrict__ nf_out, int N)
{
    constexpr int TPN = (ON + 31) / 32;
    constexpr int JT = ON / TPN;
    const int gid = blockIdx.x * blockDim.x + threadIdx.x;
    const int n = gid / TPN;
    const int c = gid % TPN;
    if (n >= N) return;
    const int jb = c * JT;

    float acc[JT];
#pragma unroll
    for (int j = 0; j < JT; ++j) acc[j] = bn[jb + j];

    {
        const float* x = nf_in + (size_t)n * INN;
#pragma unroll 4
        for (int k = 0; k < INN; ++k) {
            const float v = x[k];
#pragma unroll
            for (int j = 0; j < JT; ++j) acc[j] = fmaf(v, Wn[k * ON + jb + j], acc[j]);
        }
    }
    {
        const float inv = 1.0f / fmaxf((float)ideg[n], 1.0f);
        const float* ag = agg + (size_t)n * OE;
#pragma unroll 4
        for (int k = 0; k < OE; ++k) {
            const float v = ag[k] * inv;
#pragma unroll
            for (int j = 0; j < JT; ++j) acc[j] = fmaf(v, Wi[k * ON + jb + j], acc[j]);
        }
    }
    float* o = nf_out + (size_t)n * ON + jb;
#pragma unroll
    for (int j = 0; j < JT; ++j) o[j] = fmaxf(acc[j], 0.0f);
}

__global__ void __launch_bounds__(256) node_out_kernel(
    const float* __restrict__ nf3,
    const float* __restrict__ roWn, const float* __restrict__ robn,
    float* __restrict__ node_out, int N)
{
    const int n = blockIdx.x * blockDim.x + threadIdx.x;
    if (n >= N) return;
    const float* x = nf3 + (size_t)n * 128;
    float a0 = robn[0], a1 = robn[1];
#pragma unroll 4
    for (int k4 = 0; k4 < 32; ++k4) {
        float4 v = reinterpret_cast<const float4*>(x)[k4];
        const float vv[4] = {v.x, v.y, v.z, v.w};
#pragma unroll
        for (int u = 0; u < 4; ++u) {
            const int k = k4 * 4 + u;
            a0 = fmaf(vv[u], roWn[k * 2 + 0], a0);
            a1 = fmaf(vv[u], roWn[k * 2 + 1], a1);
        }
    }
    node_out[(size_t)n * 2 + 0] = sigmoidf_(a0);
    node_out[(size_t)n * 2 + 1] = sigmoidf_(a1);
}

// one block per graph; node_graph_idx is sorted so the graph's nodes are a
// contiguous range found by binary search. No atomics.
__global__ void __launch_bounds__(256) graph_out_kernel(
    const float* __restrict__ nf3, const int* __restrict__ gidx,
    const float* __restrict__ roWg, const float* __restrict__ robg,
    float* __restrict__ glob_out, int N)
{
    __shared__ float sred[256];
    __shared__ float gm[128];
    const int g = blockIdx.x;
    const int t = threadIdx.x;
    const int lo = lower_bound_i(gidx, N, g);
    const int hi = lower_bound_i(gidx, N, g + 1);
    const int cnt = hi - lo;

    const int c = t & 127;          // column
    const int h = t >> 7;           // 0/1
    float acc = 0.0f;
    for (int i = lo + h; i < hi; i += 2)
        acc += nf3[(size_t)i * 128 + c];
    sred[t] = acc;
    __syncthreads();
    if (t < 128) {
        const float m = (sred[t] + sred[t + 128]) / fmaxf((float)cnt, 1.0f);
        gm[t] = m * roWg[t];
    }
    __syncthreads();
    // reduce gm[0..127]
    if (t < 64) gm[t] += gm[t + 64];
    __syncthreads();
    if (t < 32) gm[t] += gm[t + 32];
    __syncthreads();
    if (t < 16) gm[t] += gm[t + 16];
    __syncthreads();
    if (t == 0) {
        float s = 0.0f;
#pragma unroll
        for (int i = 0; i < 16; ++i) s += gm[i];
        glob_out[g] = sigmoidf_(s + robg[0]);
    }
}

// ---------------- launch ----------------

static inline size_t align_up(size_t x, size_t a) { return (x + a - 1) & ~(a - 1); }

extern "C" void kernel_launch(void* const* d_in, const int* in_sizes, int n_in,
                              void* d_out, int out_size, void* d_ws, size_t ws_size,
                              hipStream_t stream) {
    const float* node_raw  = (const float*)d_in[0];
    const float* edge_raw  = (const float*)d_in[1];
    const float* distances = (const float*)d_in[2];
    const int*   residues  = (const int*)d_in[3];
    const int*   senders   = (const int*)d_in[4];
    const int*   receivers = (const int*)d_in[5];
    const int*   gidx      = (const int*)d_in[6];
    const float* emb       = (const float*)d_in[7];
    const float* eWe1 = (const float*)d_in[8];  const float* ebe1 = (const float*)d_in[9];
    const float* eWe2 = (const float*)d_in[10]; const float* ebe2 = (const float*)d_in[11];
    const float* nWn1 = (const float*)d_in[12]; const float* nbn1 = (const float*)d_in[13];
    const float* nWn2 = (const float*)d_in[14]; const float* nbn2 = (const float*)d_in[15];
    const float* roWg = (const float*)d_in[16]; const float* robg = (const float*)d_in[17];
    const float* roWn = (const float*)d_in[18]; const float* robn = (const float*)d_in[19];
    const float* l0We = (const float*)d_in[20]; const float* l0Ws = (const float*)d_in[21];
    const float* l0be = (const float*)d_in[22]; const float* l0Wn = (const float*)d_in[23];
    const float* l0Wi = (const float*)d_in[24]; const float* l0bn = (const float*)d_in[25];
    const float* l1We = (const float*)d_in[26]; const float* l1Ws = (const float*)d_in[27];
    const float* l1be = (const float*)d_in[28]; const float* l1Wn = (const float*)d_in[29];
    const float* l1Wi = (const float*)d_in[30]; const float* l1bn = (const float*)d_in[31];
    const float* l2We = (const float*)d_in[32]; const float* l2Ws = (const float*)d_in[33];
    const float* l2be = (const float*)d_in[34]; const float* l2Wn = (const float*)d_in[35];
    const float* l2Wi = (const float*)d_in[36]; const float* l2bn = (const float*)d_in[37];

    const int N  = in_sizes[3];
    const int E  = in_sizes[2];
    const int G  = out_size - 2 * N;
    const int E2 = 2 * E;
    const int nb = (N + 255) / 256;   // <= 1024 assumed (N <= 262144)

    // ---- workspace layout (ints first, then 16B-aligned floats) ----
    char* base = (char*)d_ws;
    size_t off = 0;
    int* ideg   = (int*)(base + off); off += align_up((size_t)N * 4, 16);
    int* offs   = (int*)(base + off); off += align_up((size_t)N * 4, 16);
    int* cursor = (int*)(base + off); off += align_up((size_t)N * 4, 16);
    int* eidx   = (int*)(base + off); off += align_up((size_t)E2 * 4, 16);
    int* bsum   = (int*)(base + off); off += align_up((size_t)1024 * 4, 16);
    float* nf0  = (float*)(base + off); off += (size_t)N * 16 * 4;
    float* nf1  = (float*)(base + off); off += (size_t)N * 32 * 4;
    float* nf2  = (float*)(base + off); off += (size_t)N * 64 * 4;
    float* nf3  = (float*)(base + off); off += (size_t)N * 128 * 4;
    float* agg  = (float*)(base + off); off += (size_t)N * 64 * 4;
    (void)ws_size; // ~133 MB required

    const dim3 blk(256);
    const int nb_N  = (N + 255) / 256;
    const int nb_E  = (E + 255) / 256;

    // ---- CSR build (receiver -> duplicated edge ids) ----
    hipMemsetAsync(ideg, 0, (size_t)N * 4, stream);
    k_count<<<nb_E, blk, 0, stream>>>(senders, receivers, ideg, E);
    k_blocksum<<<nb, blk, 0, stream>>>(ideg, bsum, N);
    k_scan_partials<<<1, 1024, 0, stream>>>(bsum, nb);
    k_blockscan<<<nb, blk, 0, stream>>>(ideg, bsum, offs, cursor, N);
    k_scatter<<<nb_E, blk, 0, stream>>>(senders, receivers, cursor, eidx, E);

    // ---- encoder ----
    node_enc_kernel<<<nb_N, blk, 0, stream>>>(node_raw, residues, emb, nWn1, nbn1, nWn2, nbn2, nf0, N);

    // ---- layer 0 ----
    agg_gather_kernel<0><<<nb_N, blk, 0, stream>>>(distances, edge_raw, senders, receivers,
        nf0, nf0, nf0, eWe1, ebe1, eWe2, ebe2,
        l0We, l0Ws, l0be, l1We, l1Ws, l1be, l2We, l2Ws, l2be,
        offs, ideg, eidx, agg, N, E);
    node_layer_kernel<16, 16, 32><<<nb_N, blk, 0, stream>>>(nf0, agg, ideg, l0Wn, l0Wi, l0bn, nf1, N);

    // ---- layer 1 ----
    agg_gather_kernel<1><<<nb_N, blk, 0, stream>>>(distances, edge_raw, senders, receivers,
        nf0, nf1, nf1, eWe1, ebe1, eWe2, ebe2,
        l0We, l0Ws, l0be, l1We, l1Ws, l1be, l2We, l2Ws, l2be,
        offs, ideg, eidx, agg, N, E);
    node_layer_kernel<32, 32, 64><<<(N * 2 + 255) / 256, blk, 0, stream>>>(nf1, agg, ideg, l1Wn, l1Wi, l1bn, nf2, N);

    // ---- layer 2 (2 threads per node) ----
    agg_gather_kernel<2><<<(N * 2 + 255) / 256, blk, 0, stream>>>(distances, edge_raw, senders, receivers,
        nf0, nf1, nf2, eWe1, ebe1, eWe2, ebe2,
        l0We, l0Ws, l0be, l1We, l1Ws, l1be, l2We, l2Ws, l2be,
        offs, ideg, eidx, agg, N, E);
    node_layer_kernel<64, 64, 128><<<(N * 4 + 255) / 256, blk, 0, stream>>>(nf2, agg, ideg, l2Wn, l2Wi, l2bn, nf3, N);

    // ---- readout ----
    node_out_kernel<<<nb_N, blk, 0, stream>>>(nf3, roWn, robn, (float*)d_out, N);
    graph_out_kernel<<<G, blk, 0, stream>>>(nf3, gidx, roWg, robg, (float*)d_out + (size_t)2 * N, N);
}

// Round 3
// 15278.981 us; speedup vs baseline: 1.7181x; 1.7181x over previous
//
#include <hip/hip_runtime.h>
#include <cstdint>
#include <cstddef>

// ---------------- helpers ----------------

__device__ __forceinline__ float sigmoidf_(float x) {
    return 1.0f / (1.0f + __expf(-x));
}

template<int OUT>
__device__ __forceinline__ void load_bias(const float* __restrict__ b, float* __restrict__ acc) {
#pragma unroll
    for (int j = 0; j < OUT; ++j) acc[j] = b[j];
}

template<int OUT>
__device__ __forceinline__ void relu_v(float* __restrict__ acc) {
#pragma unroll
    for (int j = 0; j < OUT; ++j) acc[j] = fmaxf(acc[j], 0.0f);
}

// acc[OUT] += x[IN] @ W[IN,OUT]  (W row-major; W addresses wave-uniform)
template<int IN, int OUT>
__device__ __forceinline__ void mm_acc(const float* __restrict__ x,
                                       const float* __restrict__ W,
                                       float* __restrict__ acc) {
#pragma unroll 4
    for (int k = 0; k < IN; ++k) {
        const float v = x[k];
#pragma unroll
        for (int j = 0; j < OUT; ++j) acc[j] = fmaf(v, W[k * OUT + j], acc[j]);
    }
}

template<int WIDTH>
__device__ __forceinline__ void load_row(const float* __restrict__ p, float* __restrict__ x) {
#pragma unroll
    for (int k4 = 0; k4 < WIDTH / 4; ++k4) {
        float4 v = reinterpret_cast<const float4*>(p)[k4];
        x[k4 * 4 + 0] = v.x; x[k4 * 4 + 1] = v.y;
        x[k4 * 4 + 2] = v.z; x[k4 * 4 + 3] = v.w;
    }
}

// edge encoder: rbf(16)+raw(2) -> 4 -> 8 (relu after each)
__device__ __forceinline__ void enc_edge(int orig,
                                         const float* __restrict__ dist,
                                         const float* __restrict__ eraw,
                                         const float* __restrict__ We1, const float* __restrict__ be1,
                                         const float* __restrict__ We2, const float* __restrict__ be2,
                                         float* __restrict__ out8) {
    float x[18];
    const float d = dist[orig];
#pragma unroll
    for (int i = 0; i < 16; ++i) {
        const float c = (float)i * (20.0f / 15.0f);
        const float t = d - c;
        x[i] = __expf(-t * t);
    }
    x[16] = eraw[(size_t)orig * 2 + 0];
    x[17] = eraw[(size_t)orig * 2 + 1];
    float h[4];
    load_bias<4>(be1, h);
    mm_acc<18, 4>(x, We1, h);
    relu_v<4>(h);
    load_bias<8>(be2, out8);
    mm_acc<4, 8>(h, We2, out8);
    relu_v<8>(out8);
}

__device__ __forceinline__ int lower_bound_i(const int* __restrict__ a, int n, int key) {
    int lo = 0, hi = n;
    while (lo < hi) {
        int mid = (lo + hi) >> 1;
        if (a[mid] < key) lo = mid + 1; else hi = mid;
    }
    return lo;
}

// ---------------- CSR build (verified round 2) ----------------

__global__ void __launch_bounds__(256) k_count(
    const int* __restrict__ senders, const int* __restrict__ receivers,
    int* __restrict__ ideg, int E)
{
    const int e = blockIdx.x * blockDim.x + threadIdx.x;
    if (e >= E) return;
    atomicAdd(&ideg[receivers[e]], 1);
    atomicAdd(&ideg[senders[e]], 1);
}

__global__ void __launch_bounds__(256) k_blocksum(
    const int* __restrict__ ideg, int* __restrict__ bsum, int N)
{
    __shared__ int s[256];
    const int t = threadIdx.x;
    const int i = blockIdx.x * 256 + t;
    s[t] = (i < N) ? ideg[i] : 0;
    __syncthreads();
#pragma unroll
    for (int d = 128; d > 0; d >>= 1) {
        if (t < d) s[t] += s[t + d];
        __syncthreads();
    }
    if (t == 0) bsum[blockIdx.x] = s[0];
}

__global__ void __launch_bounds__(1024) k_scan_partials(int* __restrict__ bsum, int nb)
{
    __shared__ int s[1024];
    const int t = threadIdx.x;
    const int v = (t < nb) ? bsum[t] : 0;
    s[t] = v;
    __syncthreads();
    for (int d = 1; d < 1024; d <<= 1) {
        const int w = (t >= d) ? s[t - d] : 0;
        __syncthreads();
        s[t] += w;
        __syncthreads();
    }
    if (t < nb) bsum[t] = s[t] - v;   // exclusive
}

__global__ void __launch_bounds__(256) k_blockscan(
    const int* __restrict__ ideg, const int* __restrict__ bsum,
    int* __restrict__ offs, int* __restrict__ cursor, int N)
{
    __shared__ int s[256];
    const int t = threadIdx.x;
    const int i = blockIdx.x * 256 + t;
    const int v = (i < N) ? ideg[i] : 0;
    s[t] = v;
    __syncthreads();
    for (int d = 1; d < 256; d <<= 1) {
        const int w = (t >= d) ? s[t - d] : 0;
        __syncthreads();
        s[t] += w;
        __syncthreads();
    }
    if (i < N) {
        const int o = bsum[blockIdx.x] + s[t] - v;
        offs[i] = o;
        cursor[i] = o;
    }
}

__global__ void __launch_bounds__(256) k_scatter(
    const int* __restrict__ senders, const int* __restrict__ receivers,
    int* __restrict__ cursor, int* __restrict__ eidx, int E)
{
    const int e = blockIdx.x * blockDim.x + threadIdx.x;
    if (e >= E) return;
    const int p = atomicAdd(&cursor[receivers[e]], 1);
    eidx[p] = e;                 // dup id e:   sender = senders[e]
    const int q = atomicAdd(&cursor[senders[e]], 1);
    eidx[q] = e + E;             // dup id e+E: sender = receivers[e]
}

// slot p -> (orig edge id, sender node id)
__global__ void __launch_bounds__(256) k_perm(
    const int* __restrict__ eidx, const int* __restrict__ senders, const int* __restrict__ receivers,
    int* __restrict__ orig_perm, int* __restrict__ snd_perm, int E, int E2)
{
    const int p = blockIdx.x * blockDim.x + threadIdx.x;
    if (p >= E2) return;
    const int de = eidx[p];
    const int orig = (de < E) ? de : de - E;
    orig_perm[p] = orig;
    snd_perm[p] = (de < E) ? senders[orig] : receivers[orig];
}

// ---------------- shared kernels ----------------

__global__ void __launch_bounds__(256) node_enc_kernel(
    const float* __restrict__ node_raw, const int* __restrict__ residues,
    const float* __restrict__ emb,
    const float* __restrict__ Wn1, const float* __restrict__ bn1,
    const float* __restrict__ Wn2, const float* __restrict__ bn2,
    float* __restrict__ nf0, int N)
{
    const int n = blockIdx.x * blockDim.x + threadIdx.x;
    if (n >= N) return;
    float h[8];
    load_bias<8>(bn1, h);
    {
        const float* er = emb + (size_t)residues[n] * 32;
        float x[32];
        load_row<32>(er, x);
        mm_acc<32, 8>(x, Wn1, h);
    }
    {
        const float* nr = node_raw + (size_t)n * 51;
#pragma unroll 4
        for (int k = 0; k < 51; ++k) {
            const float v = nr[k];
#pragma unroll
            for (int j = 0; j < 8; ++j) h[j] = fmaf(v, Wn1[(32 + k) * 8 + j], h[j]);
        }
    }
    relu_v<8>(h);
    float o[16];
    load_bias<16>(bn2, o);
    mm_acc<8, 16>(h, Wn2, o);
    relu_v<16>(o);
    float* dst = nf0 + (size_t)n * 16;
#pragma unroll
    for (int j = 0; j < 16; ++j) dst[j] = o[j];
}

// nf_new = relu(nf_in @ Wn + (agg/deg) @ Wi + bn)
template<int INN, int OE, int ON>
__global__ void __launch_bounds__(256) node_layer_kernel(
    const float* __restrict__ nf_in, const float* __restrict__ agg, const int* __restrict__ ideg,
    const float* __restrict__ Wn, const float* __restrict__ Wi, const float* __restrict__ bn,
    float* __restrict__ nf_out, int N)
{
    constexpr int TPN = (ON + 31) / 32;
    constexpr int JT = ON / TPN;
    const int gid = blockIdx.x * blockDim.x + threadIdx.x;
    const int n = gid / TPN;
    const int c = gid % TPN;
    if (n >= N) return;
    const int jb = c * JT;

    float acc[JT];
#pragma unroll
    for (int j = 0; j < JT; ++j) acc[j] = bn[jb + j];

    {
        const float* x = nf_in + (size_t)n * INN;
#pragma unroll 4
        for (int k = 0; k < INN; ++k) {
            const float v = x[k];
#pragma unroll
            for (int j = 0; j < JT; ++j) acc[j] = fmaf(v, Wn[k * ON + jb + j], acc[j]);
        }
    }
    {
        const float inv = 1.0f / fmaxf((float)ideg[n], 1.0f);
        const float* ag = agg + (size_t)n * OE;
#pragma unroll 4
        for (int k = 0; k < OE; ++k) {
            const float v = ag[k] * inv;
#pragma unroll
            for (int j = 0; j < JT; ++j) acc[j] = fmaf(v, Wi[k * ON + jb + j], acc[j]);
        }
    }
    float* o = nf_out + (size_t)n * ON + jb;
#pragma unroll
    for (int j = 0; j < JT; ++j) o[j] = fmaxf(acc[j], 0.0f);
}

__global__ void __launch_bounds__(256) node_out_kernel(
    const float* __restrict__ nf3,
    const float* __restrict__ roWn, const float* __restrict__ robn,
    float* __restrict__ node_out, int N)
{
    const int n = blockIdx.x * blockDim.x + threadIdx.x;
    if (n >= N) return;
    const float* x = nf3 + (size_t)n * 128;
    float a0 = robn[0], a1 = robn[1];
#pragma unroll 4
    for (int k4 = 0; k4 < 32; ++k4) {
        float4 v = reinterpret_cast<const float4*>(x)[k4];
        const float vv[4] = {v.x, v.y, v.z, v.w};
#pragma unroll
        for (int u = 0; u < 4; ++u) {
            const int k = k4 * 4 + u;
            a0 = fmaf(vv[u], roWn[k * 2 + 0], a0);
            a1 = fmaf(vv[u], roWn[k * 2 + 1], a1);
        }
    }
    node_out[(size_t)n * 2 + 0] = sigmoidf_(a0);
    node_out[(size_t)n * 2 + 1] = sigmoidf_(a1);
}

__global__ void __launch_bounds__(256) graph_out_kernel(
    const float* __restrict__ nf3, const int* __restrict__ gidx,
    const float* __restrict__ roWg, const float* __restrict__ robg,
    float* __restrict__ glob_out, int N)
{
    __shared__ float sred[256];
    __shared__ float gm[128];
    const int g = blockIdx.x;
    const int t = threadIdx.x;
    const int lo = lower_bound_i(gidx, N, g);
    const int hi = lower_bound_i(gidx, N, g + 1);
    const int cnt = hi - lo;

    const int c = t & 127;
    const int h = t >> 7;
    float acc = 0.0f;
    for (int i = lo + h; i < hi; i += 2)
        acc += nf3[(size_t)i * 128 + c];
    sred[t] = acc;
    __syncthreads();
    if (t < 128) {
        const float m = (sred[t] + sred[t + 128]) / fmaxf((float)cnt, 1.0f);
        gm[t] = m * roWg[t];
    }
    __syncthreads();
    if (t < 64) gm[t] += gm[t + 64];
    __syncthreads();
    if (t < 32) gm[t] += gm[t + 32];
    __syncthreads();
    if (t < 16) gm[t] += gm[t + 16];
    __syncthreads();
    if (t == 0) {
        float s = 0.0f;
#pragma unroll
        for (int i = 0; i < 16; ++i) s += gm[i];
        glob_out[g] = sigmoidf_(s + robg[0]);
    }
}

// ---------------- fast path: slot-ordered edge pipeline ----------------

// ef0_perm[p] = relu(enc(orig[p]) @ We0 + nf0[snd[p]] @ Ws0 + b0)
__global__ void __launch_bounds__(256) ef0_kernel(
    const float* __restrict__ dist, const float* __restrict__ eraw,
    const int* __restrict__ orig_perm, const int* __restrict__ snd_perm,
    const float* __restrict__ nf0,
    const float* __restrict__ eWe1, const float* __restrict__ ebe1,
    const float* __restrict__ eWe2, const float* __restrict__ ebe2,
    const float* __restrict__ We0, const float* __restrict__ Ws0, const float* __restrict__ b0,
    float* __restrict__ ef0, int E2)
{
    const int p = blockIdx.x * blockDim.x + threadIdx.x;
    if (p >= E2) return;
    float enc[8];
    enc_edge(orig_perm[p], dist, eraw, eWe1, ebe1, eWe2, ebe2, enc);
    float a[16];
    load_bias<16>(b0, a);
    mm_acc<8, 16>(enc, We0, a);
    {
        float x[16];
        load_row<16>(nf0 + (size_t)snd_perm[p] * 16, x);
        mm_acc<16, 16>(x, Ws0, a);
    }
    relu_v<16>(a);
    float* dst = ef0 + (size_t)p * 16;
#pragma unroll
    for (int j = 0; j < 16; ++j) dst[j] = a[j];
}

// ef1_perm[p] = relu(ef0_perm[p] @ We1 + nf1[snd[p]] @ Ws1 + b1)
__global__ void __launch_bounds__(256) ef1_kernel(
    const float* __restrict__ ef0, const int* __restrict__ snd_perm,
    const float* __restrict__ nf1,
    const float* __restrict__ We1, const float* __restrict__ Ws1, const float* __restrict__ b1,
    float* __restrict__ ef1, int E2)
{
    const int p = blockIdx.x * blockDim.x + threadIdx.x;
    if (p >= E2) return;
    float a[32];
    load_bias<32>(b1, a);
    {
        float x[16];
        load_row<16>(ef0 + (size_t)p * 16, x);
        mm_acc<16, 32>(x, We1, a);
    }
    {
        float x[32];
        load_row<32>(nf1 + (size_t)snd_perm[p] * 32, x);
        mm_acc<32, 32>(x, Ws1, a);
    }
    relu_v<32>(a);
    float* dst = ef1 + (size_t)p * 32;
#pragma unroll
    for (int j = 0; j < 32; ++j) dst[j] = a[j];
}

// contiguous-range sum: agg[n][c] = sum_{i<deg} ef[(offs[n]+i)*OE + c]
template<int OE>
__global__ void __launch_bounds__(256) agg_sum_kernel(
    const float* __restrict__ ef, const int* __restrict__ offs, const int* __restrict__ ideg,
    float* __restrict__ agg, int N)
{
    const int gid = blockIdx.x * blockDim.x + threadIdx.x;
    const int n = gid / OE;
    const int c = gid % OE;
    if (n >= N) return;
    const int lo = offs[n];
    const int d = ideg[n];
    float acc = 0.0f;
    for (int i = 0; i < d; ++i)
        acc += ef[(size_t)(lo + i) * OE + c];
    agg[(size_t)n * OE + c] = acc;
}

// fused layer-2 transform + aggregation: one wave per node, lane = output col.
// Weight columns live in VGPRs; x-rows are wave-uniform -> scalar loads.
__global__ void __launch_bounds__(256) agg2_fused_kernel(
    const float* __restrict__ ef1, const float* __restrict__ nf2,
    const int* __restrict__ snd_perm,
    const float* __restrict__ We2, const float* __restrict__ Ws2, const float* __restrict__ b2,
    const int* __restrict__ offs, const int* __restrict__ ideg,
    float* __restrict__ agg, int N)
{
    const int wave = threadIdx.x >> 6;
    const int lane = threadIdx.x & 63;
    const int n = blockIdx.x * 4 + wave;
    if (n >= N) return;

    float we[32], ws[64];
#pragma unroll
    for (int k = 0; k < 32; ++k) we[k] = We2[k * 64 + lane];
#pragma unroll
    for (int k = 0; k < 64; ++k) ws[k] = Ws2[k * 64 + lane];
    const float bias = b2[lane];

    const int lo = __builtin_amdgcn_readfirstlane(offs[n]);
    const int d  = __builtin_amdgcn_readfirstlane(ideg[n]);

    float acc = 0.0f;
    for (int i = 0; i < d; ++i) {
        const int p = lo + i;
        const int s = __builtin_amdgcn_readfirstlane(snd_perm[p]);
        const float* __restrict__ x1 = ef1 + (size_t)p * 32;
        const float* __restrict__ x2 = nf2 + (size_t)s * 64;
        float t = bias;
#pragma unroll
        for (int k = 0; k < 32; ++k) t = fmaf(x1[k], we[k], t);
#pragma unroll
        for (int k = 0; k < 64; ++k) t = fmaf(x2[k], ws[k], t);
        acc += fmaxf(t, 0.0f);
    }
    agg[(size_t)n * 64 + lane] = acc;
}

// ---------------- fallback path (verified round 1): atomic scatter ----------------

template<int LAYER>
__global__ void __launch_bounds__(256) edge_scatter_kernel(
    const float* __restrict__ dist, const float* __restrict__ eraw,
    const int* __restrict__ senders, const int* __restrict__ receivers,
    const float* __restrict__ nf0, const float* __restrict__ nf1, const float* __restrict__ nf2,
    const float* __restrict__ eWe1, const float* __restrict__ ebe1,
    const float* __restrict__ eWe2, const float* __restrict__ ebe2,
    const float* __restrict__ We0, const float* __restrict__ Ws0, const float* __restrict__ b0,
    const float* __restrict__ We1, const float* __restrict__ Ws1, const float* __restrict__ b1,
    const float* __restrict__ We2, const float* __restrict__ Ws2, const float* __restrict__ b2,
    float* __restrict__ agg, int E, int E2)
{
    const int e = blockIdx.x * blockDim.x + threadIdx.x;
    if (e >= E2) return;
    const int orig = (e < E) ? e : e - E;
    const int s = (e < E) ? senders[orig] : receivers[orig];
    const int r = (e < E) ? receivers[orig] : senders[orig];

    float enc[8];
    enc_edge(orig, dist, eraw, eWe1, ebe1, eWe2, ebe2, enc);

    float a0[16];
    load_bias<16>(b0, a0);
    mm_acc<8, 16>(enc, We0, a0);
    {
        float x[16];
        load_row<16>(nf0 + (size_t)s * 16, x);
        mm_acc<16, 16>(x, Ws0, a0);
    }
    relu_v<16>(a0);

    if constexpr (LAYER == 0) {
        float* dst = agg + (size_t)r * 16;
#pragma unroll
        for (int j = 0; j < 16; ++j) atomicAdd(dst + j, a0[j]);
    } else {
        float a1[32];
        load_bias<32>(b1, a1);
        mm_acc<16, 32>(a0, We1, a1);
        {
            float x[32];
            load_row<32>(nf1 + (size_t)s * 32, x);
            mm_acc<32, 32>(x, Ws1, a1);
        }
        relu_v<32>(a1);

        if constexpr (LAYER == 1) {
            float* dst = agg + (size_t)r * 32;
#pragma unroll
            for (int j = 0; j < 32; ++j) atomicAdd(dst + j, a1[j]);
        } else {
            float a2[64];
            load_bias<64>(b2, a2);
            mm_acc<32, 64>(a1, We2, a2);
            {
                const float* xr = nf2 + (size_t)s * 64;
#pragma unroll 2
                for (int k4 = 0; k4 < 16; ++k4) {
                    float4 v = reinterpret_cast<const float4*>(xr)[k4];
                    const float vv[4] = {v.x, v.y, v.z, v.w};
#pragma unroll
                    for (int u = 0; u < 4; ++u) {
                        const float val = vv[u];
                        const int k = k4 * 4 + u;
#pragma unroll
                        for (int j = 0; j < 64; ++j) a2[j] = fmaf(val, Ws2[k * 64 + j], a2[j]);
                    }
                }
            }
            relu_v<64>(a2);
            float* dst = agg + (size_t)r * 64;
#pragma unroll
            for (int j = 0; j < 64; ++j) atomicAdd(dst + j, a2[j]);
        }
    }
}

// ---------------- launch ----------------

static inline size_t align_up(size_t x, size_t a) { return (x + a - 1) & ~(a - 1); }

extern "C" void kernel_launch(void* const* d_in, const int* in_sizes, int n_in,
                              void* d_out, int out_size, void* d_ws, size_t ws_size,
                              hipStream_t stream) {
    const float* node_raw  = (const float*)d_in[0];
    const float* edge_raw  = (const float*)d_in[1];
    const float* distances = (const float*)d_in[2];
    const int*   residues  = (const int*)d_in[3];
    const int*   senders   = (const int*)d_in[4];
    const int*   receivers = (const int*)d_in[5];
    const int*   gidx      = (const int*)d_in[6];
    const float* emb       = (const float*)d_in[7];
    const float* eWe1 = (const float*)d_in[8];  const float* ebe1 = (const float*)d_in[9];
    const float* eWe2 = (const float*)d_in[10]; const float* ebe2 = (const float*)d_in[11];
    const float* nWn1 = (const float*)d_in[12]; const float* nbn1 = (const float*)d_in[13];
    const float* nWn2 = (const float*)d_in[14]; const float* nbn2 = (const float*)d_in[15];
    const float* roWg = (const float*)d_in[16]; const float* robg = (const float*)d_in[17];
    const float* roWn = (const float*)d_in[18]; const float* robn = (const float*)d_in[19];
    const float* l0We = (const float*)d_in[20]; const float* l0Ws = (const float*)d_in[21];
    const float* l0be = (const float*)d_in[22]; const float* l0Wn = (const float*)d_in[23];
    const float* l0Wi = (const float*)d_in[24]; const float* l0bn = (const float*)d_in[25];
    const float* l1We = (const float*)d_in[26]; const float* l1Ws = (const float*)d_in[27];
    const float* l1be = (const float*)d_in[28]; const float* l1Wn = (const float*)d_in[29];
    const float* l1Wi = (const float*)d_in[30]; const float* l1bn = (const float*)d_in[31];
    const float* l2We = (const float*)d_in[32]; const float* l2Ws = (const float*)d_in[33];
    const float* l2be = (const float*)d_in[34]; const float* l2Wn = (const float*)d_in[35];
    const float* l2Wi = (const float*)d_in[36]; const float* l2bn = (const float*)d_in[37];

    const int N  = in_sizes[3];
    const int E  = in_sizes[2];
    const int G  = out_size - 2 * N;
    const int E2 = 2 * E;
    const int nb = (N + 255) / 256;     // block count for scans (<=1024)

    const dim3 blk(256);
    const int nb_N  = (N + 255) / 256;
    const int nb_E  = (E + 255) / 256;
    const int nb_E2 = (E2 + 255) / 256;

    // ---- fast-path workspace layout ----
    char* base = (char*)d_ws;
    size_t off = 0;
    int* ideg      = (int*)(base + off); off += align_up((size_t)N * 4, 16);
    int* offs      = (int*)(base + off); off += align_up((size_t)N * 4, 16);
    int* cursor    = (int*)(base + off); off += align_up((size_t)N * 4, 16);
    int* bsum      = (int*)(base + off); off += align_up((size_t)1024 * 4, 16);
    int* eidx      = (int*)(base + off); off += align_up((size_t)E2 * 4, 16);
    int* orig_perm = (int*)(base + off); off += align_up((size_t)E2 * 4, 16);
    int* snd_perm  = (int*)(base + off); off += align_up((size_t)E2 * 4, 16);
    float* nf0 = (float*)(base + off); off += (size_t)N * 16 * 4;
    float* nf1 = (float*)(base + off); off += (size_t)N * 32 * 4;
    float* nf2 = (float*)(base + off); off += (size_t)N * 64 * 4;
    float* nf3 = (float*)(base + off); off += (size_t)N * 128 * 4;
    float* agg = (float*)(base + off); off += (size_t)N * 64 * 4;
    float* ef0 = (float*)(base + off); off += (size_t)E2 * 16 * 4;
    float* ef1 = (float*)(base + off); off += (size_t)E2 * 32 * 4;
    const size_t need_fast = off;

    const bool fast = (ws_size >= need_fast);

    // shared prologue
    hipMemsetAsync(ideg, 0, (size_t)N * 4, stream);
    k_count<<<nb_E, blk, 0, stream>>>(senders, receivers, ideg, E);
    node_enc_kernel<<<nb_N, blk, 0, stream>>>(node_raw, residues, emb, nWn1, nbn1, nWn2, nbn2, nf0, N);

    if (fast) {
        // CSR permutation
        k_blocksum<<<nb, blk, 0, stream>>>(ideg, bsum, N);
        k_scan_partials<<<1, 1024, 0, stream>>>(bsum, nb);
        k_blockscan<<<nb, blk, 0, stream>>>(ideg, bsum, offs, cursor, N);
        k_scatter<<<nb_E, blk, 0, stream>>>(senders, receivers, cursor, eidx, E);
        k_perm<<<nb_E2, blk, 0, stream>>>(eidx, senders, receivers, orig_perm, snd_perm, E, E2);

        // layer 0
        ef0_kernel<<<nb_E2, blk, 0, stream>>>(distances, edge_raw, orig_perm, snd_perm, nf0,
            eWe1, ebe1, eWe2, ebe2, l0We, l0Ws, l0be, ef0, E2);
        agg_sum_kernel<16><<<(N * 16 + 255) / 256, blk, 0, stream>>>(ef0, offs, ideg, agg, N);
        node_layer_kernel<16, 16, 32><<<nb_N, blk, 0, stream>>>(nf0, agg, ideg, l0Wn, l0Wi, l0bn, nf1, N);

        // layer 1
        ef1_kernel<<<nb_E2, blk, 0, stream>>>(ef0, snd_perm, nf1, l1We, l1Ws, l1be, ef1, E2);
        agg_sum_kernel<32><<<(N * 32 + 255) / 256, blk, 0, stream>>>(ef1, offs, ideg, agg, N);
        node_layer_kernel<32, 32, 64><<<(N * 2 + 255) / 256, blk, 0, stream>>>(nf1, agg, ideg, l1Wn, l1Wi, l1bn, nf2, N);

        // layer 2 (fused transform + aggregation, no ef2 buffer)
        agg2_fused_kernel<<<(N + 3) / 4, blk, 0, stream>>>(ef1, nf2, snd_perm,
            l2We, l2Ws, l2be, offs, ideg, agg, N);
        node_layer_kernel<64, 64, 128><<<(N * 4 + 255) / 256, blk, 0, stream>>>(nf2, agg, ideg, l2Wn, l2Wi, l2bn, nf3, N);
    } else {
        // verified round-1 scatter path (~122 MB)
        hipMemsetAsync(agg, 0, sizeof(float) * (size_t)N * 16, stream);
        edge_scatter_kernel<0><<<nb_E2, blk, 0, stream>>>(distances, edge_raw, senders, receivers,
            nf0, nf0, nf0, eWe1, ebe1, eWe2, ebe2,
            l0We, l0Ws, l0be, l1We, l1Ws, l1be, l2We, l2Ws, l2be, agg, E, E2);
        node_layer_kernel<16, 16, 32><<<nb_N, blk, 0, stream>>>(nf0, agg, ideg, l0Wn, l0Wi, l0bn, nf1, N);

        hipMemsetAsync(agg, 0, sizeof(float) * (size_t)N * 32, stream);
        edge_scatter_kernel<1><<<nb_E2, blk, 0, stream>>>(distances, edge_raw, senders, receivers,
            nf0, nf1, nf1, eWe1, ebe1, eWe2, ebe2,
            l0We, l0Ws, l0be, l1We, l1Ws, l1be, l2We, l2Ws, l2be, agg, E, E2);
        node_layer_kernel<32, 32, 64><<<(N * 2 + 255) / 256, blk, 0, stream>>>(nf1, agg, ideg, l1Wn, l1Wi, l1bn, nf2, N);

        hipMemsetAsync(agg, 0, sizeof(float) * (size_t)N * 64, stream);
        edge_scatter_kernel<2><<<nb_E2, blk, 0, stream>>>(distances, edge_raw, senders, receivers,
            nf0, nf1, nf2, eWe1, ebe1, eWe2, ebe2,
            l0We, l0Ws, l0be, l1We, l1Ws, l1be, l2We, l2Ws, l2be, agg, E, E2);
        node_layer_kernel<64, 64, 128><<<(N * 4 + 255) / 256, blk, 0, stream>>>(nf2, agg, ideg, l2Wn, l2Wi, l2bn, nf3, N);
    }

    // readout (no atomics, no extra ws)
    node_out_kernel<<<nb_N, blk, 0, stream>>>(nf3, roWn, robn, (float*)d_out, N);
    graph_out_kernel<<<G, blk, 0, stream>>>(nf3, gidx, roWg, robg, (float*)d_out + (size_t)2 * N, N);
}

// Round 4
// 3843.345 us; speedup vs baseline: 6.8301x; 3.9754x over previous
//
#include <hip/hip_runtime.h>
#include <cstdint>
#include <cstddef>

// ---------------- helpers ----------------

__device__ __forceinline__ float sigmoidf_(float x) {
    return 1.0f / (1.0f + __expf(-x));
}

template<int OUT>
__device__ __forceinline__ void load_bias(const float* __restrict__ b, float* __restrict__ acc) {
#pragma unroll
    for (int j = 0; j < OUT; ++j) acc[j] = b[j];
}

template<int OUT>
__device__ __forceinline__ void relu_v(float* __restrict__ acc) {
#pragma unroll
    for (int j = 0; j < OUT; ++j) acc[j] = fmaxf(acc[j], 0.0f);
}

// acc[OUT] += x[IN] @ W[IN,OUT]  (W row-major; W addresses wave-uniform)
template<int IN, int OUT>
__device__ __forceinline__ void mm_acc(const float* __restrict__ x,
                                       const float* __restrict__ W,
                                       float* __restrict__ acc) {
#pragma unroll 4
    for (int k = 0; k < IN; ++k) {
        const float v = x[k];
#pragma unroll
        for (int j = 0; j < OUT; ++j) acc[j] = fmaf(v, W[k * OUT + j], acc[j]);
    }
}

// acc[OUT] += row[IN] @ W[IN,OUT], streaming the row via float4 (low reg use)
template<int IN, int OUT>
__device__ __forceinline__ void mm_row_stream(const float* __restrict__ row,
                                              const float* __restrict__ W,
                                              float* __restrict__ acc) {
#pragma unroll
    for (int k4 = 0; k4 < IN / 4; ++k4) {
        float4 v = reinterpret_cast<const float4*>(row)[k4];
        const float vv[4] = {v.x, v.y, v.z, v.w};
#pragma unroll
        for (int u = 0; u < 4; ++u) {
            const float val = vv[u];
#pragma unroll
            for (int j = 0; j < OUT; ++j)
                acc[j] = fmaf(val, W[(k4 * 4 + u) * OUT + j], acc[j]);
        }
    }
}

template<int WIDTH>
__device__ __forceinline__ void load_row(const float* __restrict__ p, float* __restrict__ x) {
#pragma unroll
    for (int k4 = 0; k4 < WIDTH / 4; ++k4) {
        float4 v = reinterpret_cast<const float4*>(p)[k4];
        x[k4 * 4 + 0] = v.x; x[k4 * 4 + 1] = v.y;
        x[k4 * 4 + 2] = v.z; x[k4 * 4 + 3] = v.w;
    }
}

// edge encoder: rbf(16)+raw(2) -> 4 -> 8 (relu after each)
__device__ __forceinline__ void enc_edge(int orig,
                                         const float* __restrict__ dist,
                                         const float* __restrict__ eraw,
                                         const float* __restrict__ We1, const float* __restrict__ be1,
                                         const float* __restrict__ We2, const float* __restrict__ be2,
                                         float* __restrict__ out8) {
    float x[18];
    const float d = dist[orig];
#pragma unroll
    for (int i = 0; i < 16; ++i) {
        const float c = (float)i * (20.0f / 15.0f);
        const float t = d - c;
        x[i] = __expf(-t * t);
    }
    x[16] = eraw[(size_t)orig * 2 + 0];
    x[17] = eraw[(size_t)orig * 2 + 1];
    float h[4];
    load_bias<4>(be1, h);
    mm_acc<18, 4>(x, We1, h);
    relu_v<4>(h);
    load_bias<8>(be2, out8);
    mm_acc<4, 8>(h, We2, out8);
    relu_v<8>(out8);
}

// chain: enc -> ef0[16]
__device__ __forceinline__ void chain_ef0(int orig, int s,
    const float* __restrict__ dist, const float* __restrict__ eraw,
    const float* __restrict__ eWe1, const float* __restrict__ ebe1,
    const float* __restrict__ eWe2, const float* __restrict__ ebe2,
    const float* __restrict__ We0, const float* __restrict__ Ws0, const float* __restrict__ b0,
    const float* __restrict__ nf0, float* __restrict__ a0)
{
    float enc[8];
    enc_edge(orig, dist, eraw, eWe1, ebe1, eWe2, ebe2, enc);
    load_bias<16>(b0, a0);
    mm_acc<8, 16>(enc, We0, a0);
    mm_row_stream<16, 16>(nf0 + (size_t)s * 16, Ws0, a0);
    relu_v<16>(a0);
}

__device__ __forceinline__ int lower_bound_i(const int* __restrict__ a, int n, int key) {
    int lo = 0, hi = n;
    while (lo < hi) {
        int mid = (lo + hi) >> 1;
        if (a[mid] < key) lo = mid + 1; else hi = mid;
    }
    return lo;
}

// ---------------- CSR build (verified) ----------------

__global__ void __launch_bounds__(256) k_count(
    const int* __restrict__ senders, const int* __restrict__ receivers,
    int* __restrict__ ideg, int E)
{
    const int e = blockIdx.x * blockDim.x + threadIdx.x;
    if (e >= E) return;
    atomicAdd(&ideg[receivers[e]], 1);
    atomicAdd(&ideg[senders[e]], 1);
}

__global__ void __launch_bounds__(256) k_blocksum(
    const int* __restrict__ ideg, int* __restrict__ bsum, int N)
{
    __shared__ int s[256];
    const int t = threadIdx.x;
    const int i = blockIdx.x * 256 + t;
    s[t] = (i < N) ? ideg[i] : 0;
    __syncthreads();
#pragma unroll
    for (int d = 128; d > 0; d >>= 1) {
        if (t < d) s[t] += s[t + d];
        __syncthreads();
    }
    if (t == 0) bsum[blockIdx.x] = s[0];
}

__global__ void __launch_bounds__(1024) k_scan_partials(int* __restrict__ bsum, int nb)
{
    __shared__ int s[1024];
    const int t = threadIdx.x;
    const int v = (t < nb) ? bsum[t] : 0;
    s[t] = v;
    __syncthreads();
    for (int d = 1; d < 1024; d <<= 1) {
        const int w = (t >= d) ? s[t - d] : 0;
        __syncthreads();
        s[t] += w;
        __syncthreads();
    }
    if (t < nb) bsum[t] = s[t] - v;   // exclusive
}

__global__ void __launch_bounds__(256) k_blockscan(
    const int* __restrict__ ideg, const int* __restrict__ bsum,
    int* __restrict__ offs, int* __restrict__ cursor, int N)
{
    __shared__ int s[256];
    const int t = threadIdx.x;
    const int i = blockIdx.x * 256 + t;
    const int v = (i < N) ? ideg[i] : 0;
    s[t] = v;
    __syncthreads();
    for (int d = 1; d < 256; d <<= 1) {
        const int w = (t >= d) ? s[t - d] : 0;
        __syncthreads();
        s[t] += w;
        __syncthreads();
    }
    if (i < N) {
        const int o = bsum[blockIdx.x] + s[t] - v;
        offs[i] = o;
        cursor[i] = o;
    }
}

__global__ void __launch_bounds__(256) k_scatter(
    const int* __restrict__ senders, const int* __restrict__ receivers,
    int* __restrict__ cursor, int* __restrict__ eidx, int E)
{
    const int e = blockIdx.x * blockDim.x + threadIdx.x;
    if (e >= E) return;
    const int p = atomicAdd(&cursor[receivers[e]], 1);
    eidx[p] = e;                 // dup id e:   sender = senders[e]
    const int q = atomicAdd(&cursor[senders[e]], 1);
    eidx[q] = e + E;             // dup id e+E: sender = receivers[e]
}

// ---------------- shared kernels ----------------

__global__ void __launch_bounds__(256) node_enc_kernel(
    const float* __restrict__ node_raw, const int* __restrict__ residues,
    const float* __restrict__ emb,
    const float* __restrict__ Wn1, const float* __restrict__ bn1,
    const float* __restrict__ Wn2, const float* __restrict__ bn2,
    float* __restrict__ nf0, int N)
{
    const int n = blockIdx.x * blockDim.x + threadIdx.x;
    if (n >= N) return;
    float h[8];
    load_bias<8>(bn1, h);
    {
        const float* er = emb + (size_t)residues[n] * 32;
        float x[32];
        load_row<32>(er, x);
        mm_acc<32, 8>(x, Wn1, h);
    }
    {
        const float* nr = node_raw + (size_t)n * 51;
#pragma unroll 4
        for (int k = 0; k < 51; ++k) {
            const float v = nr[k];
#pragma unroll
            for (int j = 0; j < 8; ++j) h[j] = fmaf(v, Wn1[(32 + k) * 8 + j], h[j]);
        }
    }
    relu_v<8>(h);
    float o[16];
    load_bias<16>(bn2, o);
    mm_acc<8, 16>(h, Wn2, o);
    relu_v<16>(o);
    float* dst = nf0 + (size_t)n * 16;
#pragma unroll
    for (int j = 0; j < 16; ++j) dst[j] = o[j];
}

// nf_new = relu(nf_in @ Wn + (agg/deg) @ Wi + bn)
template<int INN, int OE, int ON>
__global__ void __launch_bounds__(256) node_layer_kernel(
    const float* __restrict__ nf_in, const float* __restrict__ agg, const int* __restrict__ ideg,
    const float* __restrict__ Wn, const float* __restrict__ Wi, const float* __restrict__ bn,
    float* __restrict__ nf_out, int N)
{
    constexpr int TPN = (ON + 31) / 32;
    constexpr int JT = ON / TPN;
    const int gid = blockIdx.x * blockDim.x + threadIdx.x;
    const int n = gid / TPN;
    const int c = gid % TPN;
    if (n >= N) return;
    const int jb = c * JT;

    float acc[JT];
#pragma unroll
    for (int j = 0; j < JT; ++j) acc[j] = bn[jb + j];

    {
        const float* x = nf_in + (size_t)n * INN;
#pragma unroll 4
        for (int k = 0; k < INN; ++k) {
            const float v = x[k];
#pragma unroll
            for (int j = 0; j < JT; ++j) acc[j] = fmaf(v, Wn[k * ON + jb + j], acc[j]);
        }
    }
    {
        const float inv = 1.0f / fmaxf((float)ideg[n], 1.0f);
        const float* ag = agg + (size_t)n * OE;
#pragma unroll 4
        for (int k = 0; k < OE; ++k) {
            const float v = ag[k] * inv;
#pragma unroll
            for (int j = 0; j < JT; ++j) acc[j] = fmaf(v, Wi[k * ON + jb + j], acc[j]);
        }
    }
    float* o = nf_out + (size_t)n * ON + jb;
#pragma unroll
    for (int j = 0; j < JT; ++j) o[j] = fmaxf(acc[j], 0.0f);
}

__global__ void __launch_bounds__(256) node_out_kernel(
    const float* __restrict__ nf3,
    const float* __restrict__ roWn, const float* __restrict__ robn,
    float* __restrict__ node_out, int N)
{
    const int n = blockIdx.x * blockDim.x + threadIdx.x;
    if (n >= N) return;
    const float* x = nf3 + (size_t)n * 128;
    float a0 = robn[0], a1 = robn[1];
#pragma unroll 4
    for (int k4 = 0; k4 < 32; ++k4) {
        float4 v = reinterpret_cast<const float4*>(x)[k4];
        const float vv[4] = {v.x, v.y, v.z, v.w};
#pragma unroll
        for (int u = 0; u < 4; ++u) {
            const int k = k4 * 4 + u;
            a0 = fmaf(vv[u], roWn[k * 2 + 0], a0);
            a1 = fmaf(vv[u], roWn[k * 2 + 1], a1);
        }
    }
    node_out[(size_t)n * 2 + 0] = sigmoidf_(a0);
    node_out[(size_t)n * 2 + 1] = sigmoidf_(a1);
}

__global__ void __launch_bounds__(256) graph_out_kernel(
    const float* __restrict__ nf3, const int* __restrict__ gidx,
    const float* __restrict__ roWg, const float* __restrict__ robg,
    float* __restrict__ glob_out, int N)
{
    __shared__ float sred[256];
    __shared__ float gm[128];
    const int g = blockIdx.x;
    const int t = threadIdx.x;
    const int lo = lower_bound_i(gidx, N, g);
    const int hi = lower_bound_i(gidx, N, g + 1);
    const int cnt = hi - lo;

    const int c = t & 127;
    const int h = t >> 7;
    float acc = 0.0f;
    for (int i = lo + h; i < hi; i += 2)
        acc += nf3[(size_t)i * 128 + c];
    sred[t] = acc;
    __syncthreads();
    if (t < 128) {
        const float m = (sred[t] + sred[t + 128]) / fmaxf((float)cnt, 1.0f);
        gm[t] = m * roWg[t];
    }
    __syncthreads();
    if (t < 64) gm[t] += gm[t + 64];
    __syncthreads();
    if (t < 32) gm[t] += gm[t + 32];
    __syncthreads();
    if (t < 16) gm[t] += gm[t + 16];
    __syncthreads();
    if (t == 0) {
        float s = 0.0f;
#pragma unroll
        for (int i = 0; i < 16; ++i) s += gm[i];
        glob_out[g] = sigmoidf_(s + robg[0]);
    }
}

// ---------------- fast path: chunked slot-ordered pipeline ----------------

// chunk ef0: one thread per slot in [cLo, cLo+cnt)
__global__ void __launch_bounds__(256) ef0c_kernel(
    const float* __restrict__ dist, const float* __restrict__ eraw,
    const int* __restrict__ eidx, const int* __restrict__ senders, const int* __restrict__ receivers,
    const float* __restrict__ nf0,
    const float* __restrict__ eWe1, const float* __restrict__ ebe1,
    const float* __restrict__ eWe2, const float* __restrict__ ebe2,
    const float* __restrict__ We0, const float* __restrict__ Ws0, const float* __restrict__ b0,
    float* __restrict__ efb, int E, int cLo, int cnt)
{
    const int g = blockIdx.x * blockDim.x + threadIdx.x;
    if (g >= cnt) return;
    const int de = eidx[cLo + g];
    const int orig = (de < E) ? de : de - E;
    const int s = (de < E) ? senders[orig] : receivers[orig];
    float a0[16];
    chain_ef0(orig, s, dist, eraw, eWe1, ebe1, eWe2, ebe2, We0, Ws0, b0, nf0, a0);
    float* dst = efb + (size_t)g * 16;
#pragma unroll
    for (int j = 0; j < 16; ++j) dst[j] = a0[j];
}

// chunk ef1 (recomputes enc->ef0->ef1)
__global__ void __launch_bounds__(256) ef1c_kernel(
    const float* __restrict__ dist, const float* __restrict__ eraw,
    const int* __restrict__ eidx, const int* __restrict__ senders, const int* __restrict__ receivers,
    const float* __restrict__ nf0, const float* __restrict__ nf1,
    const float* __restrict__ eWe1, const float* __restrict__ ebe1,
    const float* __restrict__ eWe2, const float* __restrict__ ebe2,
    const float* __restrict__ We0, const float* __restrict__ Ws0, const float* __restrict__ b0,
    const float* __restrict__ We1, const float* __restrict__ Ws1, const float* __restrict__ b1,
    float* __restrict__ efb, int E, int cLo, int cnt)
{
    const int g = blockIdx.x * blockDim.x + threadIdx.x;
    if (g >= cnt) return;
    const int de = eidx[cLo + g];
    const int orig = (de < E) ? de : de - E;
    const int s = (de < E) ? senders[orig] : receivers[orig];
    float a0[16];
    chain_ef0(orig, s, dist, eraw, eWe1, ebe1, eWe2, ebe2, We0, Ws0, b0, nf0, a0);
    float a1[32];
    load_bias<32>(b1, a1);
    mm_acc<16, 32>(a0, We1, a1);
    mm_row_stream<32, 32>(nf1 + (size_t)s * 32, Ws1, a1);
    relu_v<32>(a1);
    float* dst = efb + (size_t)g * 32;
#pragma unroll
    for (int j = 0; j < 32; ++j) dst[j] = a1[j];
}

// agg[n][c] += sum over slots of node n intersected with chunk [cLo, cHi)
template<int OE>
__global__ void __launch_bounds__(256) agg_add_kernel(
    const float* __restrict__ efb, const int* __restrict__ offs, const int* __restrict__ ideg,
    float* __restrict__ agg, int N, int cLo, int cHi)
{
    const int gid = blockIdx.x * blockDim.x + threadIdx.x;
    const int n = gid / OE;
    const int c = gid % OE;
    if (n >= N) return;
    int lo = offs[n];
    int hi = lo + ideg[n];
    lo = lo > cLo ? lo : cLo;
    hi = hi < cHi ? hi : cHi;
    if (lo >= hi) return;
    float acc = 0.0f;
    for (int p = lo; p < hi; ++p)
        acc += efb[(size_t)(p - cLo) * OE + c];
    agg[(size_t)n * OE + c] += acc;
}

// fused layer-2 transform + aggregation over one chunk: wave per node,
// lane = output column; weight columns in VGPRs; x-rows wave-uniform.
__global__ void __launch_bounds__(256) agg2_chunk_kernel(
    const float* __restrict__ efb, const float* __restrict__ nf2,
    const int* __restrict__ eidx, const int* __restrict__ senders, const int* __restrict__ receivers,
    const float* __restrict__ We2, const float* __restrict__ Ws2, const float* __restrict__ b2,
    const int* __restrict__ offs, const int* __restrict__ ideg,
    float* __restrict__ agg, int N, int E, int cLo, int cHi)
{
    const int wave = threadIdx.x >> 6;
    const int lane = threadIdx.x & 63;
    const int n = blockIdx.x * 4 + wave;
    if (n >= N) return;
    int lo = __builtin_amdgcn_readfirstlane(offs[n]);
    int hi = lo + __builtin_amdgcn_readfirstlane(ideg[n]);
    lo = lo > cLo ? lo : cLo;
    hi = hi < cHi ? hi : cHi;
    if (lo >= hi) return;

    float we[32], ws[64];
#pragma unroll
    for (int k = 0; k < 32; ++k) we[k] = We2[k * 64 + lane];
#pragma unroll
    for (int k = 0; k < 64; ++k) ws[k] = Ws2[k * 64 + lane];
    const float bias = b2[lane];

    float acc = 0.0f;
    for (int p = lo; p < hi; ++p) {
        const int de = __builtin_amdgcn_readfirstlane(eidx[p]);
        const int orig = (de < E) ? de : de - E;
        const int s = __builtin_amdgcn_readfirstlane((de < E) ? senders[orig] : receivers[orig]);
        const float* __restrict__ x1 = efb + (size_t)(p - cLo) * 32;
        const float* __restrict__ x2 = nf2 + (size_t)s * 64;
        float t = bias;
#pragma unroll
        for (int k = 0; k < 32; ++k) t = fmaf(x1[k], we[k], t);
#pragma unroll
        for (int k = 0; k < 64; ++k) t = fmaf(x2[k], ws[k], t);
        acc += fmaxf(t, 0.0f);
    }
    agg[(size_t)n * 64 + lane] += acc;
}

// ---------------- fallback path (verified round 1): atomic scatter ----------------

template<int LAYER>
__global__ void __launch_bounds__(256) edge_scatter_kernel(
    const float* __restrict__ dist, const float* __restrict__ eraw,
    const int* __restrict__ senders, const int* __restrict__ receivers,
    const float* __restrict__ nf0, const float* __restrict__ nf1, const float* __restrict__ nf2,
    const float* __restrict__ eWe1, const float* __restrict__ ebe1,
    const float* __restrict__ eWe2, const float* __restrict__ ebe2,
    const float* __restrict__ We0, const float* __restrict__ Ws0, const float* __restrict__ b0,
    const float* __restrict__ We1, const float* __restrict__ Ws1, const float* __restrict__ b1,
    const float* __restrict__ We2, const float* __restrict__ Ws2, const float* __restrict__ b2,
    float* __restrict__ agg, int E, int E2)
{
    const int e = blockIdx.x * blockDim.x + threadIdx.x;
    if (e >= E2) return;
    const int orig = (e < E) ? e : e - E;
    const int s = (e < E) ? senders[orig] : receivers[orig];
    const int r = (e < E) ? receivers[orig] : senders[orig];

    float enc[8];
    enc_edge(orig, dist, eraw, eWe1, ebe1, eWe2, ebe2, enc);

    float a0[16];
    load_bias<16>(b0, a0);
    mm_acc<8, 16>(enc, We0, a0);
    {
        float x[16];
        load_row<16>(nf0 + (size_t)s * 16, x);
        mm_acc<16, 16>(x, Ws0, a0);
    }
    relu_v<16>(a0);

    if constexpr (LAYER == 0) {
        float* dst = agg + (size_t)r * 16;
#pragma unroll
        for (int j = 0; j < 16; ++j) atomicAdd(dst + j, a0[j]);
    } else {
        float a1[32];
        load_bias<32>(b1, a1);
        mm_acc<16, 32>(a0, We1, a1);
        {
            float x[32];
            load_row<32>(nf1 + (size_t)s * 32, x);
            mm_acc<32, 32>(x, Ws1, a1);
        }
        relu_v<32>(a1);

        if constexpr (LAYER == 1) {
            float* dst = agg + (size_t)r * 32;
#pragma unroll
            for (int j = 0; j < 32; ++j) atomicAdd(dst + j, a1[j]);
        } else {
            float a2[64];
            load_bias<64>(b2, a2);
            mm_acc<32, 64>(a1, We2, a2);
            mm_row_stream<64, 64>(nf2 + (size_t)s * 64, Ws2, a2);
            relu_v<64>(a2);
            float* dst = agg + (size_t)r * 64;
#pragma unroll
            for (int j = 0; j < 64; ++j) atomicAdd(dst + j, a2[j]);
        }
    }
}

// ---------------- launch ----------------

static inline size_t align_up(size_t x, size_t a) { return (x + a - 1) & ~(a - 1); }

extern "C" void kernel_launch(void* const* d_in, const int* in_sizes, int n_in,
                              void* d_out, int out_size, void* d_ws, size_t ws_size,
                              hipStream_t stream) {
    const float* node_raw  = (const float*)d_in[0];
    const float* edge_raw  = (const float*)d_in[1];
    const float* distances = (const float*)d_in[2];
    const int*   residues  = (const int*)d_in[3];
    const int*   senders   = (const int*)d_in[4];
    const int*   receivers = (const int*)d_in[5];
    const int*   gidx      = (const int*)d_in[6];
    const float* emb       = (const float*)d_in[7];
    const float* eWe1 = (const float*)d_in[8];  const float* ebe1 = (const float*)d_in[9];
    const float* eWe2 = (const float*)d_in[10]; const float* ebe2 = (const float*)d_in[11];
    const float* nWn1 = (const float*)d_in[12]; const float* nbn1 = (const float*)d_in[13];
    const float* nWn2 = (const float*)d_in[14]; const float* nbn2 = (const float*)d_in[15];
    const float* roWg = (const float*)d_in[16]; const float* robg = (const float*)d_in[17];
    const float* roWn = (const float*)d_in[18]; const float* robn = (const float*)d_in[19];
    const float* l0We = (const float*)d_in[20]; const float* l0Ws = (const float*)d_in[21];
    const float* l0be = (const float*)d_in[22]; const float* l0Wn = (const float*)d_in[23];
    const float* l0Wi = (const float*)d_in[24]; const float* l0bn = (const float*)d_in[25];
    const float* l1We = (const float*)d_in[26]; const float* l1Ws = (const float*)d_in[27];
    const float* l1be = (const float*)d_in[28]; const float* l1Wn = (const float*)d_in[29];
    const float* l1Wi = (const float*)d_in[30]; const float* l1bn = (const float*)d_in[31];
    const float* l2We = (const float*)d_in[32]; const float* l2Ws = (const float*)d_in[33];
    const float* l2be = (const float*)d_in[34]; const float* l2Wn = (const float*)d_in[35];
    const float* l2Wi = (const float*)d_in[36]; const float* l2bn = (const float*)d_in[37];

    const int N  = in_sizes[3];
    const int E  = in_sizes[2];
    const int G  = out_size - 2 * N;
    const int E2 = 2 * E;
    const int nb = (N + 255) / 256;   // scan blocks (<=1024 assumed)

    const dim3 blk(256);
    const int nb_N  = (N + 255) / 256;
    const int nb_E  = (E + 255) / 256;
    const int nb_E2 = (E2 + 255) / 256;

    // ---- fixed workspace layout (~132 MB, proven to fit) ----
    char* base = (char*)d_ws;
    size_t off = 0;
    int* ideg = (int*)(base + off); off += align_up((size_t)N * 4, 16);
    int* offs = (int*)(base + off); off += align_up((size_t)N * 4, 16);
    int* bsum = (int*)(base + off); off += align_up((size_t)1024 * 4, 16);
    int* eidx = (int*)(base + off); off += align_up((size_t)E2 * 4, 16);
    float* nf0 = (float*)(base + off); off += (size_t)N * 16 * 4;
    float* nf1 = (float*)(base + off); off += (size_t)N * 32 * 4;
    float* nf2 = (float*)(base + off); off += (size_t)N * 64 * 4;
    float* nf3 = (float*)(base + off); off += (size_t)N * 128 * 4;
    float* agg = (float*)(base + off); off += (size_t)N * 64 * 4;
    const size_t fixed = off;
    int* cursor = (int*)agg;   // alias: agg unused during CSR build
    float* efbuf = (float*)(base + fixed);

    // ---- chunking decision (host-side, deterministic) ----
    bool fast = false;
    size_t S = 0;   // chunk capacity in slots (each slot = 32 floats = 128 B)
    int K = 0;
    if (ws_size > fixed) {
        size_t avail = ws_size - fixed;
        size_t maxSlots = (avail / 128) & ~(size_t)255;
        size_t wantSlots = ((size_t)E2 + 255) & ~(size_t)255;
        if (maxSlots >= wantSlots) { S = wantSlots; K = 1; fast = true; }
        else if (maxSlots >= 4096) {
            int k = (int)(((size_t)E2 + maxSlots - 1) / maxSlots);
            if (k <= 16) { S = maxSlots; K = k; fast = true; }
        }
    }

    // ---- common prologue ----
    hipMemsetAsync(ideg, 0, (size_t)N * 4, stream);
    k_count<<<nb_E, blk, 0, stream>>>(senders, receivers, ideg, E);
    node_enc_kernel<<<nb_N, blk, 0, stream>>>(node_raw, residues, emb, nWn1, nbn1, nWn2, nbn2, nf0, N);

    if (fast) {
        // CSR permutation
        k_blocksum<<<nb, blk, 0, stream>>>(ideg, bsum, N);
        k_scan_partials<<<1, 1024, 0, stream>>>(bsum, nb);
        k_blockscan<<<nb, blk, 0, stream>>>(ideg, bsum, offs, cursor, N);
        k_scatter<<<nb_E, blk, 0, stream>>>(senders, receivers, cursor, eidx, E);

        // ---- layer 0 ----
        hipMemsetAsync(agg, 0, (size_t)N * 16 * 4, stream);
        for (int c = 0; c < K; ++c) {
            const int cLo = (int)((size_t)c * S);
            const int cHi = (int)((size_t)(c + 1) * S < (size_t)E2 ? (size_t)(c + 1) * S : (size_t)E2);
            const int cnt = cHi - cLo;
            if (cnt <= 0) break;
            ef0c_kernel<<<(cnt + 255) / 256, blk, 0, stream>>>(distances, edge_raw,
                eidx, senders, receivers, nf0, eWe1, ebe1, eWe2, ebe2, l0We, l0Ws, l0be,
                efbuf, E, cLo, cnt);
            agg_add_kernel<16><<<(N * 16 + 255) / 256, blk, 0, stream>>>(efbuf, offs, ideg, agg, N, cLo, cHi);
        }
        node_layer_kernel<16, 16, 32><<<nb_N, blk, 0, stream>>>(nf0, agg, ideg, l0Wn, l0Wi, l0bn, nf1, N);

        // ---- layer 1 ----
        hipMemsetAsync(agg, 0, (size_t)N * 32 * 4, stream);
        for (int c = 0; c < K; ++c) {
            const int cLo = (int)((size_t)c * S);
            const int cHi = (int)((size_t)(c + 1) * S < (size_t)E2 ? (size_t)(c + 1) * S : (size_t)E2);
            const int cnt = cHi - cLo;
            if (cnt <= 0) break;
            ef1c_kernel<<<(cnt + 255) / 256, blk, 0, stream>>>(distances, edge_raw,
                eidx, senders, receivers, nf0, nf1, eWe1, ebe1, eWe2, ebe2,
                l0We, l0Ws, l0be, l1We, l1Ws, l1be, efbuf, E, cLo, cnt);
            agg_add_kernel<32><<<(N * 32 + 255) / 256, blk, 0, stream>>>(efbuf, offs, ideg, agg, N, cLo, cHi);
        }
        node_layer_kernel<32, 32, 64><<<(N * 2 + 255) / 256, blk, 0, stream>>>(nf1, agg, ideg, l1Wn, l1Wi, l1bn, nf2, N);

        // ---- layer 2 (fused transform + aggregation; K==1 reuses ef1 in efbuf) ----
        hipMemsetAsync(agg, 0, (size_t)N * 64 * 4, stream);
        for (int c = 0; c < K; ++c) {
            const int cLo = (int)((size_t)c * S);
            const int cHi = (int)((size_t)(c + 1) * S < (size_t)E2 ? (size_t)(c + 1) * S : (size_t)E2);
            const int cnt = cHi - cLo;
            if (cnt <= 0) break;
            if (K > 1) {
                ef1c_kernel<<<(cnt + 255) / 256, blk, 0, stream>>>(distances, edge_raw,
                    eidx, senders, receivers, nf0, nf1, eWe1, ebe1, eWe2, ebe2,
                    l0We, l0Ws, l0be, l1We, l1Ws, l1be, efbuf, E, cLo, cnt);
            }
            agg2_chunk_kernel<<<(N + 3) / 4, blk, 0, stream>>>(efbuf, nf2,
                eidx, senders, receivers, l2We, l2Ws, l2be, offs, ideg, agg, N, E, cLo, cHi);
        }
        node_layer_kernel<64, 64, 128><<<(N * 4 + 255) / 256, blk, 0, stream>>>(nf2, agg, ideg, l2Wn, l2Wi, l2bn, nf3, N);
    } else {
        // verified scatter fallback
        hipMemsetAsync(agg, 0, (size_t)N * 16 * 4, stream);
        edge_scatter_kernel<0><<<nb_E2, blk, 0, stream>>>(distances, edge_raw, senders, receivers,
            nf0, nf0, nf0, eWe1, ebe1, eWe2, ebe2,
            l0We, l0Ws, l0be, l1We, l1Ws, l1be, l2We, l2Ws, l2be, agg, E, E2);
        node_layer_kernel<16, 16, 32><<<nb_N, blk, 0, stream>>>(nf0, agg, ideg, l0Wn, l0Wi, l0bn, nf1, N);

        hipMemsetAsync(agg, 0, (size_t)N * 32 * 4, stream);
        edge_scatter_kernel<1><<<nb_E2, blk, 0, stream>>>(distances, edge_raw, senders, receivers,
            nf0, nf1, nf1, eWe1, ebe1, eWe2, ebe2,
            l0We, l0Ws, l0be, l1We, l1Ws, l1be, l2We, l2Ws, l2be, agg, E, E2);
        node_layer_kernel<32, 32, 64><<<(N * 2 + 255) / 256, blk, 0, stream>>>(nf1, agg, ideg, l1Wn, l1Wi, l1bn, nf2, N);

        hipMemsetAsync(agg, 0, (size_t)N * 64 * 4, stream);
        edge_scatter_kernel<2><<<nb_E2, blk, 0, stream>>>(distances, edge_raw, senders, receivers,
            nf0, nf1, nf2, eWe1, ebe1, eWe2, ebe2,
            l0We, l0Ws, l0be, l1We, l1Ws, l1be, l2We, l2Ws, l2be, agg, E, E2);
        node_layer_kernel<64, 64, 128><<<(N * 4 + 255) / 256, blk, 0, stream>>>(nf2, agg, ideg, l2Wn, l2Wi, l2bn, nf3, N);
    }

    // ---- readout ----
    node_out_kernel<<<nb_N, blk, 0, stream>>>(nf3, roWn, robn, (float*)d_out, N);
    graph_out_kernel<<<G, blk, 0, stream>>>(nf3, gidx, roWg, robg, (float*)d_out + (size_t)2 * N, N);
}

// Round 5
// 2822.328 us; speedup vs baseline: 9.3010x; 1.3618x over previous
//
#include <hip/hip_runtime.h>
#include <cstdint>
#include <cstddef>

// ---------------- helpers ----------------

__device__ __forceinline__ float sigmoidf_(float x) {
    return 1.0f / (1.0f + __expf(-x));
}

template<int OUT>
__device__ __forceinline__ void load_bias(const float* __restrict__ b, float* __restrict__ acc) {
#pragma unroll
    for (int j = 0; j < OUT; ++j) acc[j] = b[j];
}

template<int OUT>
__device__ __forceinline__ void relu_v(float* __restrict__ acc) {
#pragma unroll
    for (int j = 0; j < OUT; ++j) acc[j] = fmaxf(acc[j], 0.0f);
}

// acc[OUT] += x[IN] @ W[IN,OUT]  (W row-major; W addresses wave-uniform)
template<int IN, int OUT>
__device__ __forceinline__ void mm_acc(const float* __restrict__ x,
                                       const float* __restrict__ W,
                                       float* __restrict__ acc) {
#pragma unroll 4
    for (int k = 0; k < IN; ++k) {
        const float v = x[k];
#pragma unroll
        for (int j = 0; j < OUT; ++j) acc[j] = fmaf(v, W[k * OUT + j], acc[j]);
    }
}

// acc[OUT] += row[IN] @ W[IN,OUT], streaming the row via float4 (low reg use)
template<int IN, int OUT>
__device__ __forceinline__ void mm_row_stream(const float* __restrict__ row,
                                              const float* __restrict__ W,
                                              float* __restrict__ acc) {
#pragma unroll
    for (int k4 = 0; k4 < IN / 4; ++k4) {
        float4 v = reinterpret_cast<const float4*>(row)[k4];
        const float vv[4] = {v.x, v.y, v.z, v.w};
#pragma unroll
        for (int u = 0; u < 4; ++u) {
            const float val = vv[u];
#pragma unroll
            for (int j = 0; j < OUT; ++j)
                acc[j] = fmaf(val, W[(k4 * 4 + u) * OUT + j], acc[j]);
        }
    }
}

template<int WIDTH>
__device__ __forceinline__ void load_row(const float* __restrict__ p, float* __restrict__ x) {
#pragma unroll
    for (int k4 = 0; k4 < WIDTH / 4; ++k4) {
        float4 v = reinterpret_cast<const float4*>(p)[k4];
        x[k4 * 4 + 0] = v.x; x[k4 * 4 + 1] = v.y;
        x[k4 * 4 + 2] = v.z; x[k4 * 4 + 3] = v.w;
    }
}

// edge encoder: rbf(16)+raw(2) -> 4 -> 8 (relu after each)
__device__ __forceinline__ void enc_edge(int orig,
                                         const float* __restrict__ dist,
                                         const float* __restrict__ eraw,
                                         const float* __restrict__ We1, const float* __restrict__ be1,
                                         const float* __restrict__ We2, const float* __restrict__ be2,
                                         float* __restrict__ out8) {
    float x[18];
    const float d = dist[orig];
#pragma unroll
    for (int i = 0; i < 16; ++i) {
        const float c = (float)i * (20.0f / 15.0f);
        const float t = d - c;
        x[i] = __expf(-t * t);
    }
    x[16] = eraw[(size_t)orig * 2 + 0];
    x[17] = eraw[(size_t)orig * 2 + 1];
    float h[4];
    load_bias<4>(be1, h);
    mm_acc<18, 4>(x, We1, h);
    relu_v<4>(h);
    load_bias<8>(be2, out8);
    mm_acc<4, 8>(h, We2, out8);
    relu_v<8>(out8);
}

// chain: enc -> ef0[16]
__device__ __forceinline__ void chain_ef0(int orig, int s,
    const float* __restrict__ dist, const float* __restrict__ eraw,
    const float* __restrict__ eWe1, const float* __restrict__ ebe1,
    const float* __restrict__ eWe2, const float* __restrict__ ebe2,
    const float* __restrict__ We0, const float* __restrict__ Ws0, const float* __restrict__ b0,
    const float* __restrict__ nf0, float* __restrict__ a0)
{
    float enc[8];
    enc_edge(orig, dist, eraw, eWe1, ebe1, eWe2, ebe2, enc);
    load_bias<16>(b0, a0);
    mm_acc<8, 16>(enc, We0, a0);
    mm_row_stream<16, 16>(nf0 + (size_t)s * 16, Ws0, a0);
    relu_v<16>(a0);
}

__device__ __forceinline__ int lower_bound_i(const int* __restrict__ a, int n, int key) {
    int lo = 0, hi = n;
    while (lo < hi) {
        int mid = (lo + hi) >> 1;
        if (a[mid] < key) lo = mid + 1; else hi = mid;
    }
    return lo;
}

// ---------------- CSR build ----------------

__global__ void __launch_bounds__(256) k_count(
    const int* __restrict__ senders, const int* __restrict__ receivers,
    int* __restrict__ ideg, int E)
{
    const int e = blockIdx.x * blockDim.x + threadIdx.x;
    if (e >= E) return;
    atomicAdd(&ideg[receivers[e]], 1);
    atomicAdd(&ideg[senders[e]], 1);
}

__global__ void __launch_bounds__(256) k_blocksum(
    const int* __restrict__ ideg, int* __restrict__ bsum, int N)
{
    __shared__ int s[256];
    const int t = threadIdx.x;
    const int i = blockIdx.x * 256 + t;
    s[t] = (i < N) ? ideg[i] : 0;
    __syncthreads();
#pragma unroll
    for (int d = 128; d > 0; d >>= 1) {
        if (t < d) s[t] += s[t + d];
        __syncthreads();
    }
    if (t == 0) bsum[blockIdx.x] = s[0];
}

__global__ void __launch_bounds__(1024) k_scan_partials(int* __restrict__ bsum, int nb)
{
    __shared__ int s[1024];
    const int t = threadIdx.x;
    const int v = (t < nb) ? bsum[t] : 0;
    s[t] = v;
    __syncthreads();
    for (int d = 1; d < 1024; d <<= 1) {
        const int w = (t >= d) ? s[t - d] : 0;
        __syncthreads();
        s[t] += w;
        __syncthreads();
    }
    if (t < nb) bsum[t] = s[t] - v;   // exclusive
}

__global__ void __launch_bounds__(256) k_blockscan(
    const int* __restrict__ ideg, const int* __restrict__ bsum,
    int* __restrict__ offs, int* __restrict__ cursor, int N)
{
    __shared__ int s[256];
    const int t = threadIdx.x;
    const int i = blockIdx.x * 256 + t;
    const int v = (i < N) ? ideg[i] : 0;
    s[t] = v;
    __syncthreads();
    for (int d = 1; d < 256; d <<= 1) {
        const int w = (t >= d) ? s[t - d] : 0;
        __syncthreads();
        s[t] += w;
        __syncthreads();
    }
    if (i < N) {
        const int o = bsum[blockIdx.x] + s[t] - v;
        offs[i] = o;
        cursor[i] = o;
    }
}

// writes slot -> (orig edge, sender node) directly
__global__ void __launch_bounds__(256) k_scatter(
    const int* __restrict__ senders, const int* __restrict__ receivers,
    int* __restrict__ cursor, int* __restrict__ orig_perm, int* __restrict__ snd_perm, int E)
{
    const int e = blockIdx.x * blockDim.x + threadIdx.x;
    if (e >= E) return;
    const int se = senders[e];
    const int re = receivers[e];
    const int p = atomicAdd(&cursor[re], 1);
    orig_perm[p] = e;  snd_perm[p] = se;
    const int q = atomicAdd(&cursor[se], 1);
    orig_perm[q] = e;  snd_perm[q] = re;
}

// ---------------- shared kernels ----------------

__global__ void __launch_bounds__(256) node_enc_kernel(
    const float* __restrict__ node_raw, const int* __restrict__ residues,
    const float* __restrict__ emb,
    const float* __restrict__ Wn1, const float* __restrict__ bn1,
    const float* __restrict__ Wn2, const float* __restrict__ bn2,
    float* __restrict__ nf0, int N)
{
    const int n = blockIdx.x * blockDim.x + threadIdx.x;
    if (n >= N) return;
    float h[8];
    load_bias<8>(bn1, h);
    {
        const float* er = emb + (size_t)residues[n] * 32;
        float x[32];
        load_row<32>(er, x);
        mm_acc<32, 8>(x, Wn1, h);
    }
    {
        const float* nr = node_raw + (size_t)n * 51;
#pragma unroll 4
        for (int k = 0; k < 51; ++k) {
            const float v = nr[k];
#pragma unroll
            for (int j = 0; j < 8; ++j) h[j] = fmaf(v, Wn1[(32 + k) * 8 + j], h[j]);
        }
    }
    relu_v<8>(h);
    float o[16];
    load_bias<16>(bn2, o);
    mm_acc<8, 16>(h, Wn2, o);
    relu_v<16>(o);
    float* dst = nf0 + (size_t)n * 16;
#pragma unroll
    for (int j = 0; j < 16; ++j) dst[j] = o[j];
}

// column-per-thread node layer: weights in VGPRs, x/agg rows broadcast.
// nf_out[n][j] = relu( sum_k nf_in[n][k]*Wn[k][j] + inv*sum_k agg[n][k]*Wi[k][j] + bn[j] )
template<int INN, int OE, int ON>
__global__ void __launch_bounds__(256) node_layer_v2(
    const float* __restrict__ nf_in, const float* __restrict__ agg, const int* __restrict__ ideg,
    const float* __restrict__ Wn, const float* __restrict__ Wi, const float* __restrict__ bn,
    float* __restrict__ nf_out, int N, int npb)
{
    constexpr int SUB = 256 / ON;          // nodes processed concurrently per block
    const int j = threadIdx.x % ON;        // output column
    const int m = threadIdx.x / ON;        // node sublane

    float wn[INN], wi[OE];
#pragma unroll
    for (int k = 0; k < INN; ++k) wn[k] = Wn[k * ON + j];   // coalesced across j
#pragma unroll
    for (int k = 0; k < OE; ++k)  wi[k] = Wi[k * ON + j];
    const float bj = bn[j];

    const int n_begin = blockIdx.x * npb;
    int n_end = n_begin + npb;
    if (n_end > N) n_end = N;

    for (int n = n_begin + m; n < n_end; n += SUB) {
        const float* __restrict__ x  = nf_in + (size_t)n * INN;
        const float* __restrict__ ag = agg + (size_t)n * OE;
        const float inv = 1.0f / fmaxf((float)ideg[n], 1.0f);

        float p0 = bj, p1 = 0.0f, p2 = 0.0f, p3 = 0.0f;
#pragma unroll
        for (int k4 = 0; k4 < INN / 4; ++k4) {
            float4 v = reinterpret_cast<const float4*>(x)[k4];
            p0 = fmaf(v.x, wn[4 * k4 + 0], p0);
            p1 = fmaf(v.y, wn[4 * k4 + 1], p1);
            p2 = fmaf(v.z, wn[4 * k4 + 2], p2);
            p3 = fmaf(v.w, wn[4 * k4 + 3], p3);
        }
        float q0 = 0.0f, q1 = 0.0f, q2 = 0.0f, q3 = 0.0f;
#pragma unroll
        for (int k4 = 0; k4 < OE / 4; ++k4) {
            float4 v = reinterpret_cast<const float4*>(ag)[k4];
            q0 = fmaf(v.x, wi[4 * k4 + 0], q0);
            q1 = fmaf(v.y, wi[4 * k4 + 1], q1);
            q2 = fmaf(v.z, wi[4 * k4 + 2], q2);
            q3 = fmaf(v.w, wi[4 * k4 + 3], q3);
        }
        const float t = (p0 + p1) + (p2 + p3) + inv * ((q0 + q1) + (q2 + q3));
        nf_out[(size_t)n * ON + j] = fmaxf(t, 0.0f);
    }
}

__global__ void __launch_bounds__(256) node_out_kernel(
    const float* __restrict__ nf3,
    const float* __restrict__ roWn, const float* __restrict__ robn,
    float* __restrict__ node_out, int N)
{
    const int n = blockIdx.x * blockDim.x + threadIdx.x;
    if (n >= N) return;
    const float* x = nf3 + (size_t)n * 128;
    float a0 = robn[0], a1 = robn[1];
#pragma unroll 4
    for (int k4 = 0; k4 < 32; ++k4) {
        float4 v = reinterpret_cast<const float4*>(x)[k4];
        const float vv[4] = {v.x, v.y, v.z, v.w};
#pragma unroll
        for (int u = 0; u < 4; ++u) {
            const int k = k4 * 4 + u;
            a0 = fmaf(vv[u], roWn[k * 2 + 0], a0);
            a1 = fmaf(vv[u], roWn[k * 2 + 1], a1);
        }
    }
    node_out[(size_t)n * 2 + 0] = sigmoidf_(a0);
    node_out[(size_t)n * 2 + 1] = sigmoidf_(a1);
}

__global__ void __launch_bounds__(256) graph_out_kernel(
    const float* __restrict__ nf3, const int* __restrict__ gidx,
    const float* __restrict__ roWg, const float* __restrict__ robg,
    float* __restrict__ glob_out, int N)
{
    __shared__ float sred[256];
    __shared__ float gm[128];
    const int g = blockIdx.x;
    const int t = threadIdx.x;
    const int lo = lower_bound_i(gidx, N, g);
    const int hi = lower_bound_i(gidx, N, g + 1);
    const int cnt = hi - lo;

    const int c = t & 127;
    const int h = t >> 7;
    float acc = 0.0f;
    for (int i = lo + h; i < hi; i += 2)
        acc += nf3[(size_t)i * 128 + c];
    sred[t] = acc;
    __syncthreads();
    if (t < 128) {
        const float m = (sred[t] + sred[t + 128]) / fmaxf((float)cnt, 1.0f);
        gm[t] = m * roWg[t];
    }
    __syncthreads();
    if (t < 64) gm[t] += gm[t + 64];
    __syncthreads();
    if (t < 32) gm[t] += gm[t + 32];
    __syncthreads();
    if (t < 16) gm[t] += gm[t + 16];
    __syncthreads();
    if (t == 0) {
        float s = 0.0f;
#pragma unroll
        for (int i = 0; i < 16; ++i) s += gm[i];
        glob_out[g] = sigmoidf_(s + robg[0]);
    }
}

// ---------------- fast path: chunked slot-ordered pipeline ----------------

__global__ void __launch_bounds__(256) ef0c_kernel(
    const float* __restrict__ dist, const float* __restrict__ eraw,
    const int* __restrict__ orig_perm, const int* __restrict__ snd_perm,
    const float* __restrict__ nf0,
    const float* __restrict__ eWe1, const float* __restrict__ ebe1,
    const float* __restrict__ eWe2, const float* __restrict__ ebe2,
    const float* __restrict__ We0, const float* __restrict__ Ws0, const float* __restrict__ b0,
    float* __restrict__ efb, int cLo, int cnt)
{
    const int g = blockIdx.x * blockDim.x + threadIdx.x;
    if (g >= cnt) return;
    const int orig = orig_perm[cLo + g];
    const int s    = snd_perm[cLo + g];
    float a0[16];
    chain_ef0(orig, s, dist, eraw, eWe1, ebe1, eWe2, ebe2, We0, Ws0, b0, nf0, a0);
    float* dst = efb + (size_t)g * 16;
#pragma unroll
    for (int j = 0; j < 16; ++j) dst[j] = a0[j];
}

__global__ void __launch_bounds__(256) ef1c_kernel(
    const float* __restrict__ dist, const float* __restrict__ eraw,
    const int* __restrict__ orig_perm, const int* __restrict__ snd_perm,
    const float* __restrict__ nf0, const float* __restrict__ nf1,
    const float* __restrict__ eWe1, const float* __restrict__ ebe1,
    const float* __restrict__ eWe2, const float* __restrict__ ebe2,
    const float* __restrict__ We0, const float* __restrict__ Ws0, const float* __restrict__ b0,
    const float* __restrict__ We1, const float* __restrict__ Ws1, const float* __restrict__ b1,
    float* __restrict__ efb, int cLo, int cnt)
{
    const int g = blockIdx.x * blockDim.x + threadIdx.x;
    if (g >= cnt) return;
    const int orig = orig_perm[cLo + g];
    const int s    = snd_perm[cLo + g];
    float a0[16];
    chain_ef0(orig, s, dist, eraw, eWe1, ebe1, eWe2, ebe2, We0, Ws0, b0, nf0, a0);
    float a1[32];
    load_bias<32>(b1, a1);
    mm_acc<16, 32>(a0, We1, a1);
    mm_row_stream<32, 32>(nf1 + (size_t)s * 32, Ws1, a1);
    relu_v<32>(a1);
    float* dst = efb + (size_t)g * 32;
#pragma unroll
    for (int j = 0; j < 32; ++j) dst[j] = a1[j];
}

// agg[n][c] += sum over slots of node n intersected with chunk [cLo, cHi)
template<int OE>
__global__ void __launch_bounds__(256) agg_add_kernel(
    const float* __restrict__ efb, const int* __restrict__ offs, const int* __restrict__ ideg,
    float* __restrict__ agg, int N, int cLo, int cHi)
{
    const int gid = blockIdx.x * blockDim.x + threadIdx.x;
    const int n = gid / OE;
    const int c = gid % OE;
    if (n >= N) return;
    int lo = offs[n];
    int hi = lo + ideg[n];
    lo = lo > cLo ? lo : cLo;
    hi = hi < cHi ? hi : cHi;
    if (lo >= hi) return;
    float acc = 0.0f;
    for (int p = lo; p < hi; ++p)
        acc += efb[(size_t)(p - cLo) * OE + c];
    agg[(size_t)n * OE + c] += acc;
}

// fused layer-2 transform + aggregation over one chunk: wave per node,
// lane = output column; weight columns in VGPRs; x-rows wave-uniform.
__global__ void __launch_bounds__(256) agg2_chunk_kernel(
    const float* __restrict__ efb, const float* __restrict__ nf2,
    const int* __restrict__ snd_perm,
    const float* __restrict__ We2, const float* __restrict__ Ws2, const float* __restrict__ b2,
    const int* __restrict__ offs, const int* __restrict__ ideg,
    float* __restrict__ agg, int N, int cLo, int cHi)
{
    const int wave = threadIdx.x >> 6;
    const int lane = threadIdx.x & 63;
    const int n = blockIdx.x * 4 + wave;
    if (n >= N) return;
    int lo = __builtin_amdgcn_readfirstlane(offs[n]);
    int hi = lo + __builtin_amdgcn_readfirstlane(ideg[n]);
    lo = lo > cLo ? lo : cLo;
    hi = hi < cHi ? hi : cHi;
    if (lo >= hi) return;

    float we[32], ws[64];
#pragma unroll
    for (int k = 0; k < 32; ++k) we[k] = We2[k * 64 + lane];
#pragma unroll
    for (int k = 0; k < 64; ++k) ws[k] = Ws2[k * 64 + lane];
    const float bias = b2[lane];

    float acc = 0.0f;
    for (int p = lo; p < hi; ++p) {
        const int s = __builtin_amdgcn_readfirstlane(snd_perm[p]);
        const float* __restrict__ x1 = efb + (size_t)(p - cLo) * 32;
        const float* __restrict__ x2 = nf2 + (size_t)s * 64;
        float t = bias;
#pragma unroll
        for (int k = 0; k < 32; ++k) t = fmaf(x1[k], we[k], t);
#pragma unroll
        for (int k = 0; k < 64; ++k) t = fmaf(x2[k], ws[k], t);
        acc += fmaxf(t, 0.0f);
    }
    agg[(size_t)n * 64 + lane] += acc;
}

// ---------------- fallback path (verified round 1): atomic scatter ----------------

template<int LAYER>
__global__ void __launch_bounds__(256) edge_scatter_kernel(
    const float* __restrict__ dist, const float* __restrict__ eraw,
    const int* __restrict__ senders, const int* __restrict__ receivers,
    const float* __restrict__ nf0, const float* __restrict__ nf1, const float* __restrict__ nf2,
    const float* __restrict__ eWe1, const float* __restrict__ ebe1,
    const float* __restrict__ eWe2, const float* __restrict__ ebe2,
    const float* __restrict__ We0, const float* __restrict__ Ws0, const float* __restrict__ b0,
    const float* __restrict__ We1, const float* __restrict__ Ws1, const float* __restrict__ b1,
    const float* __restrict__ We2, const float* __restrict__ Ws2, const float* __restrict__ b2,
    float* __restrict__ agg, int E, int E2)
{
    const int e = blockIdx.x * blockDim.x + threadIdx.x;
    if (e >= E2) return;
    const int orig = (e < E) ? e : e - E;
    const int s = (e < E) ? senders[orig] : receivers[orig];
    const int r = (e < E) ? receivers[orig] : senders[orig];

    float enc[8];
    enc_edge(orig, dist, eraw, eWe1, ebe1, eWe2, ebe2, enc);

    float a0[16];
    load_bias<16>(b0, a0);
    mm_acc<8, 16>(enc, We0, a0);
    {
        float x[16];
        load_row<16>(nf0 + (size_t)s * 16, x);
        mm_acc<16, 16>(x, Ws0, a0);
    }
    relu_v<16>(a0);

    if constexpr (LAYER == 0) {
        float* dst = agg + (size_t)r * 16;
#pragma unroll
        for (int j = 0; j < 16; ++j) atomicAdd(dst + j, a0[j]);
    } else {
        float a1[32];
        load_bias<32>(b1, a1);
        mm_acc<16, 32>(a0, We1, a1);
        {
            float x[32];
            load_row<32>(nf1 + (size_t)s * 32, x);
            mm_acc<32, 32>(x, Ws1, a1);
        }
        relu_v<32>(a1);

        if constexpr (LAYER == 1) {
            float* dst = agg + (size_t)r * 32;
#pragma unroll
            for (int j = 0; j < 32; ++j) atomicAdd(dst + j, a1[j]);
        } else {
            float a2[64];
            load_bias<64>(b2, a2);
            mm_acc<32, 64>(a1, We2, a2);
            mm_row_stream<64, 64>(nf2 + (size_t)s * 64, Ws2, a2);
            relu_v<64>(a2);
            float* dst = agg + (size_t)r * 64;
#pragma unroll
            for (int j = 0; j < 64; ++j) atomicAdd(dst + j, a2[j]);
        }
    }
}

// ---------------- launch ----------------

static inline size_t align_up(size_t x, size_t a) { return (x + a - 1) & ~(a - 1); }

extern "C" void kernel_launch(void* const* d_in, const int* in_sizes, int n_in,
                              void* d_out, int out_size, void* d_ws, size_t ws_size,
                              hipStream_t stream) {
    const float* node_raw  = (const float*)d_in[0];
    const float* edge_raw  = (const float*)d_in[1];
    const float* distances = (const float*)d_in[2];
    const int*   residues  = (const int*)d_in[3];
    const int*   senders   = (const int*)d_in[4];
    const int*   receivers = (const int*)d_in[5];
    const int*   gidx      = (const int*)d_in[6];
    const float* emb       = (const float*)d_in[7];
    const float* eWe1 = (const float*)d_in[8];  const float* ebe1 = (const float*)d_in[9];
    const float* eWe2 = (const float*)d_in[10]; const float* ebe2 = (const float*)d_in[11];
    const float* nWn1 = (const float*)d_in[12]; const float* nbn1 = (const float*)d_in[13];
    const float* nWn2 = (const float*)d_in[14]; const float* nbn2 = (const float*)d_in[15];
    const float* roWg = (const float*)d_in[16]; const float* robg = (const float*)d_in[17];
    const float* roWn = (const float*)d_in[18]; const float* robn = (const float*)d_in[19];
    const float* l0We = (const float*)d_in[20]; const float* l0Ws = (const float*)d_in[21];
    const float* l0be = (const float*)d_in[22]; const float* l0Wn = (const float*)d_in[23];
    const float* l0Wi = (const float*)d_in[24]; const float* l0bn = (const float*)d_in[25];
    const float* l1We = (const float*)d_in[26]; const float* l1Ws = (const float*)d_in[27];
    const float* l1be = (const float*)d_in[28]; const float* l1Wn = (const float*)d_in[29];
    const float* l1Wi = (const float*)d_in[30]; const float* l1bn = (const float*)d_in[31];
    const float* l2We = (const float*)d_in[32]; const float* l2Ws = (const float*)d_in[33];
    const float* l2be = (const float*)d_in[34]; const float* l2Wn = (const float*)d_in[35];
    const float* l2Wi = (const float*)d_in[36]; const float* l2bn = (const float*)d_in[37];

    const int N  = in_sizes[3];
    const int E  = in_sizes[2];
    const int G  = out_size - 2 * N;
    const int E2 = 2 * E;
    const int nb = (N + 255) / 256;   // scan blocks (<=1024 assumed)

    const dim3 blk(256);
    const int nb_N  = (N + 255) / 256;
    const int nb_E  = (E + 255) / 256;
    const int nb_E2 = (E2 + 255) / 256;

    // ---- fixed workspace layout (~123 MB) ----
    char* base = (char*)d_ws;
    size_t off = 0;
    int* ideg = (int*)(base + off); off += align_up((size_t)N * 4, 16);
    int* offs = (int*)(base + off); off += align_up((size_t)N * 4, 16);
    int* bsum = (int*)(base + off); off += align_up((size_t)1024 * 4, 16);
    float* nf0 = (float*)(base + off); off += (size_t)N * 16 * 4;
    float* nf1 = (float*)(base + off); off += (size_t)N * 32 * 4;
    float* nf2 = (float*)(base + off); off += (size_t)N * 64 * 4;
    float* nf3 = (float*)(base + off); off += (size_t)N * 128 * 4;
    float* agg = (float*)(base + off); off += (size_t)N * 64 * 4;
    const size_t fixed = off;
    // aliases (lifetime-disjoint):
    int* cursor    = (int*)agg;         // agg unused during CSR build
    int* orig_perm = (int*)nf3;         // nf3 written only after last perm use
    int* snd_perm  = orig_perm + E2;
    float* efbuf   = (float*)(base + fixed);
    const bool alias_ok = ((size_t)N * 128 >= (size_t)2 * E2);

    // ---- chunking decision (host-side, deterministic) ----
    bool fast = false;
    size_t S = 0;   // chunk capacity in slots (slot = 32 floats = 128 B)
    int K = 0;
    if (alias_ok && ws_size > fixed) {
        size_t avail = ws_size - fixed;
        size_t maxSlots = (avail / 128) & ~(size_t)255;
        size_t wantSlots = ((size_t)E2 + 255) & ~(size_t)255;
        if (maxSlots >= wantSlots) { S = wantSlots; K = 1; fast = true; }
        else if (maxSlots >= 4096) {
            int k = (int)(((size_t)E2 + maxSlots - 1) / maxSlots);
            if (k <= 16) { S = maxSlots; K = k; fast = true; }
        }
    }

    // ---- common prologue ----
    hipMemsetAsync(ideg, 0, (size_t)N * 4, stream);
    k_count<<<nb_E, blk, 0, stream>>>(senders, receivers, ideg, E);
    node_enc_kernel<<<nb_N, blk, 0, stream>>>(node_raw, residues, emb, nWn1, nbn1, nWn2, nbn2, nf0, N);

    const int NPB = 64;                       // nodes per block in node_layer_v2
    const int nlb = (N + NPB - 1) / NPB;

    if (fast) {
        // CSR permutation
        k_blocksum<<<nb, blk, 0, stream>>>(ideg, bsum, N);
        k_scan_partials<<<1, 1024, 0, stream>>>(bsum, nb);
        k_blockscan<<<nb, blk, 0, stream>>>(ideg, bsum, offs, cursor, N);
        k_scatter<<<nb_E, blk, 0, stream>>>(senders, receivers, cursor, orig_perm, snd_perm, E);

        // ---- layer 0 ----
        hipMemsetAsync(agg, 0, (size_t)N * 16 * 4, stream);
        for (int c = 0; c < K; ++c) {
            const int cLo = (int)((size_t)c * S);
            const int cHi = (int)((size_t)(c + 1) * S < (size_t)E2 ? (size_t)(c + 1) * S : (size_t)E2);
            const int cnt = cHi - cLo;
            if (cnt <= 0) break;
            ef0c_kernel<<<(cnt + 255) / 256, blk, 0, stream>>>(distances, edge_raw,
                orig_perm, snd_perm, nf0, eWe1, ebe1, eWe2, ebe2, l0We, l0Ws, l0be,
                efbuf, cLo, cnt);
            agg_add_kernel<16><<<(N * 16 + 255) / 256, blk, 0, stream>>>(efbuf, offs, ideg, agg, N, cLo, cHi);
        }
        node_layer_v2<16, 16, 32><<<nlb, blk, 0, stream>>>(nf0, agg, ideg, l0Wn, l0Wi, l0bn, nf1, N, NPB);

        // ---- layer 1 ----
        hipMemsetAsync(agg, 0, (size_t)N * 32 * 4, stream);
        for (int c = 0; c < K; ++c) {
            const int cLo = (int)((size_t)c * S);
            const int cHi = (int)((size_t)(c + 1) * S < (size_t)E2 ? (size_t)(c + 1) * S : (size_t)E2);
            const int cnt = cHi - cLo;
            if (cnt <= 0) break;
            ef1c_kernel<<<(cnt + 255) / 256, blk, 0, stream>>>(distances, edge_raw,
                orig_perm, snd_perm, nf0, nf1, eWe1, ebe1, eWe2, ebe2,
                l0We, l0Ws, l0be, l1We, l1Ws, l1be, efbuf, cLo, cnt);
            agg_add_kernel<32><<<(N * 32 + 255) / 256, blk, 0, stream>>>(efbuf, offs, ideg, agg, N, cLo, cHi);
        }
        node_layer_v2<32, 32, 64><<<nlb, blk, 0, stream>>>(nf1, agg, ideg, l1Wn, l1Wi, l1bn, nf2, N, NPB);

        // ---- layer 2 (fused transform + aggregation; K==1 reuses ef1 in efbuf) ----
        hipMemsetAsync(agg, 0, (size_t)N * 64 * 4, stream);
        for (int c = 0; c < K; ++c) {
            const int cLo = (int)((size_t)c * S);
            const int cHi = (int)((size_t)(c + 1) * S < (size_t)E2 ? (size_t)(c + 1) * S : (size_t)E2);
            const int cnt = cHi - cLo;
            if (cnt <= 0) break;
            if (K > 1) {
                ef1c_kernel<<<(cnt + 255) / 256, blk, 0, stream>>>(distances, edge_raw,
                    orig_perm, snd_perm, nf0, nf1, eWe1, ebe1, eWe2, ebe2,
                    l0We, l0Ws, l0be, l1We, l1Ws, l1be, efbuf, cLo, cnt);
            }
            agg2_chunk_kernel<<<(N + 3) / 4, blk, 0, stream>>>(efbuf, nf2,
                snd_perm, l2We, l2Ws, l2be, offs, ideg, agg, N, cLo, cHi);
        }
        // writes nf3 (clobbers perm arrays — safe, last use was above)
        node_layer_v2<64, 64, 128><<<nlb, blk, 0, stream>>>(nf2, agg, ideg, l2Wn, l2Wi, l2bn, nf3, N, NPB);
    } else {
        // verified scatter fallback
        hipMemsetAsync(agg, 0, (size_t)N * 16 * 4, stream);
        edge_scatter_kernel<0><<<nb_E2, blk, 0, stream>>>(distances, edge_raw, senders, receivers,
            nf0, nf0, nf0, eWe1, ebe1, eWe2, ebe2,
            l0We, l0Ws, l0be, l1We, l1Ws, l1be, l2We, l2Ws, l2be, agg, E, E2);
        node_layer_v2<16, 16, 32><<<nlb, blk, 0, stream>>>(nf0, agg, ideg, l0Wn, l0Wi, l0bn, nf1, N, NPB);

        hipMemsetAsync(agg, 0, (size_t)N * 32 * 4, stream);
        edge_scatter_kernel<1><<<nb_E2, blk, 0, stream>>>(distances, edge_raw, senders, receivers,
            nf0, nf1, nf1, eWe1, ebe1, eWe2, ebe2,
            l0We, l0Ws, l0be, l1We, l1Ws, l1be, l2We, l2Ws, l2be, agg, E, E2);
        node_layer_v2<32, 32, 64><<<nlb, blk, 0, stream>>>(nf1, agg, ideg, l1Wn, l1Wi, l1bn, nf2, N, NPB);

        hipMemsetAsync(agg, 0, (size_t)N * 64 * 4, stream);
        edge_scatter_kernel<2><<<nb_E2, blk, 0, stream>>>(distances, edge_raw, senders, receivers,
            nf0, nf1, nf2, eWe1, ebe1, eWe2, ebe2,
            l0We, l0Ws, l0be, l1We, l1Ws, l1be, l2We, l2Ws, l2be, agg, E, E2);
        node_layer_v2<64, 64, 128><<<nlb, blk, 0, stream>>>(nf2, agg, ideg, l2Wn, l2Wi, l2bn, nf3, N, NPB);
    }

    // ---- readout ----
    node_out_kernel<<<nb_N, blk, 0, stream>>>(nf3, roWn, robn, (float*)d_out, N);
    graph_out_kernel<<<G, blk, 0, stream>>>(nf3, gidx, roWg, robg, (float*)d_out + (size_t)2 * N, N);
}

// Round 6
// 2505.120 us; speedup vs baseline: 10.4788x; 1.1266x over previous
//
#include <hip/hip_runtime.h>
#include <cstdint>
#include <cstddef>

// ---------------- helpers ----------------

__device__ __forceinline__ float sigmoidf_(float x) {
    return 1.0f / (1.0f + __expf(-x));
}

template<int OUT>
__device__ __forceinline__ void load_bias(const float* __restrict__ b, float* __restrict__ acc) {
#pragma unroll
    for (int j = 0; j < OUT; ++j) acc[j] = b[j];
}

template<int OUT>
__device__ __forceinline__ void relu_v(float* __restrict__ acc) {
#pragma unroll
    for (int j = 0; j < OUT; ++j) acc[j] = fmaxf(acc[j], 0.0f);
}

// acc[OUT] += x[IN] @ W[IN,OUT]  (W row-major; W addresses wave-uniform)
template<int IN, int OUT>
__device__ __forceinline__ void mm_acc(const float* __restrict__ x,
                                       const float* __restrict__ W,
                                       float* __restrict__ acc) {
#pragma unroll 4
    for (int k = 0; k < IN; ++k) {
        const float v = x[k];
#pragma unroll
        for (int j = 0; j < OUT; ++j) acc[j] = fmaf(v, W[k * OUT + j], acc[j]);
    }
}

template<int WIDTH>
__device__ __forceinline__ void load_row(const float* __restrict__ p, float* __restrict__ x) {
#pragma unroll
    for (int k4 = 0; k4 < WIDTH / 4; ++k4) {
        float4 v = reinterpret_cast<const float4*>(p)[k4];
        x[k4 * 4 + 0] = v.x; x[k4 * 4 + 1] = v.y;
        x[k4 * 4 + 2] = v.z; x[k4 * 4 + 3] = v.w;
    }
}

// edge encoder: rbf(16)+raw(2) -> 4 -> 8 (relu after each)
__device__ __forceinline__ void enc_edge(int orig,
                                         const float* __restrict__ dist,
                                         const float* __restrict__ eraw,
                                         const float* __restrict__ We1, const float* __restrict__ be1,
                                         const float* __restrict__ We2, const float* __restrict__ be2,
                                         float* __restrict__ out8) {
    float x[18];
    const float d = dist[orig];
#pragma unroll
    for (int i = 0; i < 16; ++i) {
        const float c = (float)i * (20.0f / 15.0f);
        const float t = d - c;
        x[i] = __expf(-t * t);
    }
    x[16] = eraw[(size_t)orig * 2 + 0];
    x[17] = eraw[(size_t)orig * 2 + 1];
    float h[4];
    load_bias<4>(be1, h);
    mm_acc<18, 4>(x, We1, h);
    relu_v<4>(h);
    load_bias<8>(be2, out8);
    mm_acc<4, 8>(h, We2, out8);
    relu_v<8>(out8);
}

// chain: load nf0 row FIRST (hide gather latency under enc), then enc -> ef0[16]
__device__ __forceinline__ void chain_ef0(int orig, int s,
    const float* __restrict__ dist, const float* __restrict__ eraw,
    const float* __restrict__ eWe1, const float* __restrict__ ebe1,
    const float* __restrict__ eWe2, const float* __restrict__ ebe2,
    const float* __restrict__ We0, const float* __restrict__ Ws0, const float* __restrict__ b0,
    const float* __restrict__ nf0, float* __restrict__ a0)
{
    float x0[16];
    load_row<16>(nf0 + (size_t)s * 16, x0);   // issue gather early
    float enc[8];
    enc_edge(orig, dist, eraw, eWe1, ebe1, eWe2, ebe2, enc);
    load_bias<16>(b0, a0);
    mm_acc<8, 16>(enc, We0, a0);
    mm_acc<16, 16>(x0, Ws0, a0);
    relu_v<16>(a0);
}

__device__ __forceinline__ int lower_bound_i(const int* __restrict__ a, int n, int key) {
    int lo = 0, hi = n;
    while (lo < hi) {
        int mid = (lo + hi) >> 1;
        if (a[mid] < key) lo = mid + 1; else hi = mid;
    }
    return lo;
}

// ---------------- CSR build ----------------

__global__ void __launch_bounds__(256) k_count(
    const int* __restrict__ senders, const int* __restrict__ receivers,
    int* __restrict__ ideg, int E)
{
    const int e = blockIdx.x * blockDim.x + threadIdx.x;
    if (e >= E) return;
    atomicAdd(&ideg[receivers[e]], 1);
    atomicAdd(&ideg[senders[e]], 1);
}

__global__ void __launch_bounds__(256) k_blocksum(
    const int* __restrict__ ideg, int* __restrict__ bsum, int N)
{
    __shared__ int s[256];
    const int t = threadIdx.x;
    const int i = blockIdx.x * 256 + t;
    s[t] = (i < N) ? ideg[i] : 0;
    __syncthreads();
#pragma unroll
    for (int d = 128; d > 0; d >>= 1) {
        if (t < d) s[t] += s[t + d];
        __syncthreads();
    }
    if (t == 0) bsum[blockIdx.x] = s[0];
}

__global__ void __launch_bounds__(1024) k_scan_partials(int* __restrict__ bsum, int nb)
{
    __shared__ int s[1024];
    const int t = threadIdx.x;
    const int v = (t < nb) ? bsum[t] : 0;
    s[t] = v;
    __syncthreads();
    for (int d = 1; d < 1024; d <<= 1) {
        const int w = (t >= d) ? s[t - d] : 0;
        __syncthreads();
        s[t] += w;
        __syncthreads();
    }
    if (t < nb) bsum[t] = s[t] - v;   // exclusive
}

__global__ void __launch_bounds__(256) k_blockscan(
    const int* __restrict__ ideg, const int* __restrict__ bsum,
    int* __restrict__ offs, int* __restrict__ cursor, int N)
{
    __shared__ int s[256];
    const int t = threadIdx.x;
    const int i = blockIdx.x * 256 + t;
    const int v = (i < N) ? ideg[i] : 0;
    s[t] = v;
    __syncthreads();
    for (int d = 1; d < 256; d <<= 1) {
        const int w = (t >= d) ? s[t - d] : 0;
        __syncthreads();
        s[t] += w;
        __syncthreads();
    }
    if (i < N) {
        const int o = bsum[blockIdx.x] + s[t] - v;
        offs[i] = o;
        cursor[i] = o;
    }
}

// writes slot -> (orig edge, sender node) directly
__global__ void __launch_bounds__(256) k_scatter(
    const int* __restrict__ senders, const int* __restrict__ receivers,
    int* __restrict__ cursor, int* __restrict__ orig_perm, int* __restrict__ snd_perm, int E)
{
    const int e = blockIdx.x * blockDim.x + threadIdx.x;
    if (e >= E) return;
    const int se = senders[e];
    const int re = receivers[e];
    const int p = atomicAdd(&cursor[re], 1);
    orig_perm[p] = e;  snd_perm[p] = se;
    const int q = atomicAdd(&cursor[se], 1);
    orig_perm[q] = e;  snd_perm[q] = re;
}

// ---------------- shared kernels ----------------

// LDS-staged node encoder: coalesced load of 256 node_raw rows, then per-thread MLP.
__global__ void __launch_bounds__(256) node_enc_kernel(
    const float* __restrict__ node_raw, const int* __restrict__ residues,
    const float* __restrict__ emb,
    const float* __restrict__ Wn1, const float* __restrict__ bn1,
    const float* __restrict__ Wn2, const float* __restrict__ bn2,
    float* __restrict__ nf0, int N)
{
    __shared__ float raw[256 * 51];
    const int t = threadIdx.x;
    const int n0 = blockIdx.x * 256;
    int cnt = N - n0; if (cnt > 256) cnt = 256;
    const int tot = cnt * 51;
    for (int i = t; i < tot; i += 256)
        raw[i] = node_raw[(size_t)n0 * 51 + i];
    __syncthreads();

    const int n = n0 + t;
    if (n >= N) return;
    float h[8];
    load_bias<8>(bn1, h);
    {
        const float* er = emb + (size_t)residues[n] * 32;
        float x[32];
        load_row<32>(er, x);
        mm_acc<32, 8>(x, Wn1, h);
    }
    {
        const float* nr = &raw[t * 51];
#pragma unroll 4
        for (int k = 0; k < 51; ++k) {
            const float v = nr[k];
#pragma unroll
            for (int j = 0; j < 8; ++j) h[j] = fmaf(v, Wn1[(32 + k) * 8 + j], h[j]);
        }
    }
    relu_v<8>(h);
    float o[16];
    load_bias<16>(bn2, o);
    mm_acc<8, 16>(h, Wn2, o);
    relu_v<16>(o);
    float* dst = nf0 + (size_t)n * 16;
#pragma unroll
    for (int j = 0; j < 16; ++j) dst[j] = o[j];
}

// column-per-thread node layer: weights in VGPRs, x/agg rows broadcast.
template<int INN, int OE, int ON>
__global__ void __launch_bounds__(256) node_layer_v2(
    const float* __restrict__ nf_in, const float* __restrict__ agg, const int* __restrict__ ideg,
    const float* __restrict__ Wn, const float* __restrict__ Wi, const float* __restrict__ bn,
    float* __restrict__ nf_out, int N, int npb)
{
    constexpr int SUB = 256 / ON;
    const int j = threadIdx.x % ON;
    const int m = threadIdx.x / ON;

    float wn[INN], wi[OE];
#pragma unroll
    for (int k = 0; k < INN; ++k) wn[k] = Wn[k * ON + j];
#pragma unroll
    for (int k = 0; k < OE; ++k)  wi[k] = Wi[k * ON + j];
    const float bj = bn[j];

    const int n_begin = blockIdx.x * npb;
    int n_end = n_begin + npb;
    if (n_end > N) n_end = N;

    for (int n = n_begin + m; n < n_end; n += SUB) {
        const float* __restrict__ x  = nf_in + (size_t)n * INN;
        const float* __restrict__ ag = agg + (size_t)n * OE;
        const float inv = 1.0f / fmaxf((float)ideg[n], 1.0f);

        float p0 = bj, p1 = 0.0f, p2 = 0.0f, p3 = 0.0f;
#pragma unroll
        for (int k4 = 0; k4 < INN / 4; ++k4) {
            float4 v = reinterpret_cast<const float4*>(x)[k4];
            p0 = fmaf(v.x, wn[4 * k4 + 0], p0);
            p1 = fmaf(v.y, wn[4 * k4 + 1], p1);
            p2 = fmaf(v.z, wn[4 * k4 + 2], p2);
            p3 = fmaf(v.w, wn[4 * k4 + 3], p3);
        }
        float q0 = 0.0f, q1 = 0.0f, q2 = 0.0f, q3 = 0.0f;
#pragma unroll
        for (int k4 = 0; k4 < OE / 4; ++k4) {
            float4 v = reinterpret_cast<const float4*>(ag)[k4];
            q0 = fmaf(v.x, wi[4 * k4 + 0], q0);
            q1 = fmaf(v.y, wi[4 * k4 + 1], q1);
            q2 = fmaf(v.z, wi[4 * k4 + 2], q2);
            q3 = fmaf(v.w, wi[4 * k4 + 3], q3);
        }
        const float t = (p0 + p1) + (p2 + p3) + inv * ((q0 + q1) + (q2 + q3));
        nf_out[(size_t)n * ON + j] = fmaxf(t, 0.0f);
    }
}

__global__ void __launch_bounds__(256) node_out_kernel(
    const float* __restrict__ nf3,
    const float* __restrict__ roWn, const float* __restrict__ robn,
    float* __restrict__ node_out, int N)
{
    const int n = blockIdx.x * blockDim.x + threadIdx.x;
    if (n >= N) return;
    const float* x = nf3 + (size_t)n * 128;
    float a0 = robn[0], a1 = robn[1];
#pragma unroll 4
    for (int k4 = 0; k4 < 32; ++k4) {
        float4 v = reinterpret_cast<const float4*>(x)[k4];
        const float vv[4] = {v.x, v.y, v.z, v.w};
#pragma unroll
        for (int u = 0; u < 4; ++u) {
            const int k = k4 * 4 + u;
            a0 = fmaf(vv[u], roWn[k * 2 + 0], a0);
            a1 = fmaf(vv[u], roWn[k * 2 + 1], a1);
        }
    }
    node_out[(size_t)n * 2 + 0] = sigmoidf_(a0);
    node_out[(size_t)n * 2 + 1] = sigmoidf_(a1);
}

__global__ void __launch_bounds__(256) graph_out_kernel(
    const float* __restrict__ nf3, const int* __restrict__ gidx,
    const float* __restrict__ roWg, const float* __restrict__ robg,
    float* __restrict__ glob_out, int N)
{
    __shared__ float sred[256];
    __shared__ float gm[128];
    const int g = blockIdx.x;
    const int t = threadIdx.x;
    const int lo = lower_bound_i(gidx, N, g);
    const int hi = lower_bound_i(gidx, N, g + 1);
    const int cnt = hi - lo;

    const int c = t & 127;
    const int h = t >> 7;
    float acc = 0.0f;
    for (int i = lo + h; i < hi; i += 2)
        acc += nf3[(size_t)i * 128 + c];
    sred[t] = acc;
    __syncthreads();
    if (t < 128) {
        const float m = (sred[t] + sred[t + 128]) / fmaxf((float)cnt, 1.0f);
        gm[t] = m * roWg[t];
    }
    __syncthreads();
    if (t < 64) gm[t] += gm[t + 64];
    __syncthreads();
    if (t < 32) gm[t] += gm[t + 32];
    __syncthreads();
    if (t < 16) gm[t] += gm[t + 16];
    __syncthreads();
    if (t == 0) {
        float s = 0.0f;
#pragma unroll
        for (int i = 0; i < 16; ++i) s += gm[i];
        glob_out[g] = sigmoidf_(s + robg[0]);
    }
}

// ---------------- fast path: chunked slot-ordered pipeline ----------------

__global__ void __launch_bounds__(256) ef0c_kernel(
    const float* __restrict__ dist, const float* __restrict__ eraw,
    const int* __restrict__ orig_perm, const int* __restrict__ snd_perm,
    const float* __restrict__ nf0,
    const float* __restrict__ eWe1, const float* __restrict__ ebe1,
    const float* __restrict__ eWe2, const float* __restrict__ ebe2,
    const float* __restrict__ We0, const float* __restrict__ Ws0, const float* __restrict__ b0,
    float* __restrict__ efb, int cLo, int cnt)
{
    const int g = blockIdx.x * blockDim.x + threadIdx.x;
    if (g >= cnt) return;
    const int orig = orig_perm[cLo + g];
    const int s    = snd_perm[cLo + g];
    float a0[16];
    chain_ef0(orig, s, dist, eraw, eWe1, ebe1, eWe2, ebe2, We0, Ws0, b0, nf0, a0);
    float* dst = efb + (size_t)g * 16;
#pragma unroll
    for (int j = 0; j < 16; ++j) dst[j] = a0[j];
}

__global__ void __launch_bounds__(256) ef1c_kernel(
    const float* __restrict__ dist, const float* __restrict__ eraw,
    const int* __restrict__ orig_perm, const int* __restrict__ snd_perm,
    const float* __restrict__ nf0, const float* __restrict__ nf1,
    const float* __restrict__ eWe1, const float* __restrict__ ebe1,
    const float* __restrict__ eWe2, const float* __restrict__ ebe2,
    const float* __restrict__ We0, const float* __restrict__ Ws0, const float* __restrict__ b0,
    const float* __restrict__ We1, const float* __restrict__ Ws1, const float* __restrict__ b1,
    float* __restrict__ efb, int cLo, int cnt)
{
    const int g = blockIdx.x * blockDim.x + threadIdx.x;
    if (g >= cnt) return;
    const int orig = orig_perm[cLo + g];
    const int s    = snd_perm[cLo + g];
    float x1[32];
    load_row<32>(nf1 + (size_t)s * 32, x1);    // issue gather early
    float a0[16];
    chain_ef0(orig, s, dist, eraw, eWe1, ebe1, eWe2, ebe2, We0, Ws0, b0, nf0, a0);
    float a1[32];
    load_bias<32>(b1, a1);
    mm_acc<16, 32>(a0, We1, a1);
    mm_acc<32, 32>(x1, Ws1, a1);
    relu_v<32>(a1);
    float* dst = efb + (size_t)g * 32;
#pragma unroll
    for (int j = 0; j < 32; ++j) dst[j] = a1[j];
}

// agg[n][c] (+)= sum over slots of node n intersected with chunk [cLo, cHi)
template<int OE, bool FIRST>
__global__ void __launch_bounds__(256) agg_add_kernel(
    const float* __restrict__ efb, const int* __restrict__ offs, const int* __restrict__ ideg,
    float* __restrict__ agg, int N, int cLo, int cHi)
{
    const int gid = blockIdx.x * blockDim.x + threadIdx.x;
    const int n = gid / OE;
    const int c = gid % OE;
    if (n >= N) return;
    int lo = offs[n];
    int hi = lo + ideg[n];
    lo = lo > cLo ? lo : cLo;
    hi = hi < cHi ? hi : cHi;
    if (!FIRST && lo >= hi) return;
    float acc = 0.0f;
    for (int p = lo; p < hi; ++p)
        acc += efb[(size_t)(p - cLo) * OE + c];
    if (FIRST) agg[(size_t)n * OE + c] = acc;
    else       agg[(size_t)n * OE + c] += acc;
}

// fused layer-2 transform + aggregation over one chunk: wave per node,
// lane = output column; weight columns in VGPRs; edge loop unrolled x2.
template<bool FIRST>
__global__ void __launch_bounds__(256) agg2_chunk_kernel(
    const float* __restrict__ efb, const float* __restrict__ nf2,
    const int* __restrict__ snd_perm,
    const float* __restrict__ We2, const float* __restrict__ Ws2, const float* __restrict__ b2,
    const int* __restrict__ offs, const int* __restrict__ ideg,
    float* __restrict__ agg, int N, int cLo, int cHi)
{
    const int wave = threadIdx.x >> 6;
    const int lane = threadIdx.x & 63;
    const int n = blockIdx.x * 4 + wave;
    if (n >= N) return;
    int lo = __builtin_amdgcn_readfirstlane(offs[n]);
    int hi = lo + __builtin_amdgcn_readfirstlane(ideg[n]);
    lo = lo > cLo ? lo : cLo;
    hi = hi < cHi ? hi : cHi;
    if (!FIRST && lo >= hi) return;

    float we[32], ws[64];
#pragma unroll
    for (int k = 0; k < 32; ++k) we[k] = We2[k * 64 + lane];
#pragma unroll
    for (int k = 0; k < 64; ++k) ws[k] = Ws2[k * 64 + lane];
    const float bias = b2[lane];

    float acc = 0.0f;
    int p = lo;
    // unroll x2: two independent edges in flight (loads of edge b overlap FMAs of a)
    for (; p + 2 <= hi; p += 2) {
        const int s0 = __builtin_amdgcn_readfirstlane(snd_perm[p]);
        const int s1 = __builtin_amdgcn_readfirstlane(snd_perm[p + 1]);
        const float* __restrict__ x1a = efb + (size_t)(p - cLo) * 32;
        const float* __restrict__ x1b = x1a + 32;
        const float* __restrict__ x2a = nf2 + (size_t)s0 * 64;
        const float* __restrict__ x2b = nf2 + (size_t)s1 * 64;
        float t0 = bias, t1 = bias;
#pragma unroll
        for (int k = 0; k < 32; ++k) {
            t0 = fmaf(x1a[k], we[k], t0);
            t1 = fmaf(x1b[k], we[k], t1);
        }
#pragma unroll
        for (int k = 0; k < 64; ++k) {
            t0 = fmaf(x2a[k], ws[k], t0);
            t1 = fmaf(x2b[k], ws[k], t1);
        }
        acc += fmaxf(t0, 0.0f) + fmaxf(t1, 0.0f);
    }
    if (p < hi) {
        const int s0 = __builtin_amdgcn_readfirstlane(snd_perm[p]);
        const float* __restrict__ x1a = efb + (size_t)(p - cLo) * 32;
        const float* __restrict__ x2a = nf2 + (size_t)s0 * 64;
        float t0 = bias;
#pragma unroll
        for (int k = 0; k < 32; ++k) t0 = fmaf(x1a[k], we[k], t0);
#pragma unroll
        for (int k = 0; k < 64; ++k) t0 = fmaf(x2a[k], ws[k], t0);
        acc += fmaxf(t0, 0.0f);
    }
    if (FIRST) agg[(size_t)n * 64 + lane] = acc;
    else       agg[(size_t)n * 64 + lane] += acc;
}

// ---------------- fallback path (verified round 1): atomic scatter ----------------

template<int LAYER>
__global__ void __launch_bounds__(256) edge_scatter_kernel(
    const float* __restrict__ dist, const float* __restrict__ eraw,
    const int* __restrict__ senders, const int* __restrict__ receivers,
    const float* __restrict__ nf0, const float* __restrict__ nf1, const float* __restrict__ nf2,
    const float* __restrict__ eWe1, const float* __restrict__ ebe1,
    const float* __restrict__ eWe2, const float* __restrict__ ebe2,
    const float* __restrict__ We0, const float* __restrict__ Ws0, const float* __restrict__ b0,
    const float* __restrict__ We1, const float* __restrict__ Ws1, const float* __restrict__ b1,
    const float* __restrict__ We2, const float* __restrict__ Ws2, const float* __restrict__ b2,
    float* __restrict__ agg, int E, int E2)
{
    const int e = blockIdx.x * blockDim.x + threadIdx.x;
    if (e >= E2) return;
    const int orig = (e < E) ? e : e - E;
    const int s = (e < E) ? senders[orig] : receivers[orig];
    const int r = (e < E) ? receivers[orig] : senders[orig];

    float a0[16];
    chain_ef0(orig, s, dist, eraw, eWe1, ebe1, eWe2, ebe2, We0, Ws0, b0, nf0, a0);

    if constexpr (LAYER == 0) {
        float* dst = agg + (size_t)r * 16;
#pragma unroll
        for (int j = 0; j < 16; ++j) atomicAdd(dst + j, a0[j]);
    } else {
        float a1[32];
        load_bias<32>(b1, a1);
        mm_acc<16, 32>(a0, We1, a1);
        {
            float x[32];
            load_row<32>(nf1 + (size_t)s * 32, x);
            mm_acc<32, 32>(x, Ws1, a1);
        }
        relu_v<32>(a1);

        if constexpr (LAYER == 1) {
            float* dst = agg + (size_t)r * 32;
#pragma unroll
            for (int j = 0; j < 32; ++j) atomicAdd(dst + j, a1[j]);
        } else {
            float a2[64];
            load_bias<64>(b2, a2);
            mm_acc<32, 64>(a1, We2, a2);
            {
                const float* xr = nf2 + (size_t)s * 64;
#pragma unroll
                for (int k4 = 0; k4 < 16; ++k4) {
                    float4 v = reinterpret_cast<const float4*>(xr)[k4];
                    const float vv[4] = {v.x, v.y, v.z, v.w};
#pragma unroll
                    for (int u = 0; u < 4; ++u) {
                        const float val = vv[u];
                        const int k = k4 * 4 + u;
#pragma unroll
                        for (int j = 0; j < 64; ++j) a2[j] = fmaf(val, Ws2[k * 64 + j], a2[j]);
                    }
                }
            }
            relu_v<64>(a2);
            float* dst = agg + (size_t)r * 64;
#pragma unroll
            for (int j = 0; j < 64; ++j) atomicAdd(dst + j, a2[j]);
        }
    }
}

// ---------------- launch ----------------

static inline size_t align_up(size_t x, size_t a) { return (x + a - 1) & ~(a - 1); }

extern "C" void kernel_launch(void* const* d_in, const int* in_sizes, int n_in,
                              void* d_out, int out_size, void* d_ws, size_t ws_size,
                              hipStream_t stream) {
    const float* node_raw  = (const float*)d_in[0];
    const float* edge_raw  = (const float*)d_in[1];
    const float* distances = (const float*)d_in[2];
    const int*   residues  = (const int*)d_in[3];
    const int*   senders   = (const int*)d_in[4];
    const int*   receivers = (const int*)d_in[5];
    const int*   gidx      = (const int*)d_in[6];
    const float* emb       = (const float*)d_in[7];
    const float* eWe1 = (const float*)d_in[8];  const float* ebe1 = (const float*)d_in[9];
    const float* eWe2 = (const float*)d_in[10]; const float* ebe2 = (const float*)d_in[11];
    const float* nWn1 = (const float*)d_in[12]; const float* nbn1 = (const float*)d_in[13];
    const float* nWn2 = (const float*)d_in[14]; const float* nbn2 = (const float*)d_in[15];
    const float* roWg = (const float*)d_in[16]; const float* robg = (const float*)d_in[17];
    const float* roWn = (const float*)d_in[18]; const float* robn = (const float*)d_in[19];
    const float* l0We = (const float*)d_in[20]; const float* l0Ws = (const float*)d_in[21];
    const float* l0be = (const float*)d_in[22]; const float* l0Wn = (const float*)d_in[23];
    const float* l0Wi = (const float*)d_in[24]; const float* l0bn = (const float*)d_in[25];
    const float* l1We = (const float*)d_in[26]; const float* l1Ws = (const float*)d_in[27];
    const float* l1be = (const float*)d_in[28]; const float* l1Wn = (const float*)d_in[29];
    const float* l1Wi = (const float*)d_in[30]; const float* l1bn = (const float*)d_in[31];
    const float* l2We = (const float*)d_in[32]; const float* l2Ws = (const float*)d_in[33];
    const float* l2be = (const float*)d_in[34]; const float* l2Wn = (const float*)d_in[35];
    const float* l2Wi = (const float*)d_in[36]; const float* l2bn = (const float*)d_in[37];

    const int N  = in_sizes[3];
    const int E  = in_sizes[2];
    const int G  = out_size - 2 * N;
    const int E2 = 2 * E;
    const int nb = (N + 255) / 256;

    const dim3 blk(256);
    const int nb_N  = (N + 255) / 256;
    const int nb_E  = (E + 255) / 256;
    const int nb_E2 = (E2 + 255) / 256;

    // ---- fixed workspace layout (~123 MB) ----
    char* base = (char*)d_ws;
    size_t off = 0;
    int* ideg = (int*)(base + off); off += align_up((size_t)N * 4, 16);
    int* offs = (int*)(base + off); off += align_up((size_t)N * 4, 16);
    int* bsum = (int*)(base + off); off += align_up((size_t)1024 * 4, 16);
    float* nf0 = (float*)(base + off); off += (size_t)N * 16 * 4;
    float* nf1 = (float*)(base + off); off += (size_t)N * 32 * 4;
    float* nf2 = (float*)(base + off); off += (size_t)N * 64 * 4;
    float* nf3 = (float*)(base + off); off += (size_t)N * 128 * 4;
    float* agg = (float*)(base + off); off += (size_t)N * 64 * 4;
    const size_t fixed = off;
    // aliases (lifetime-disjoint):
    int* cursor    = (int*)agg;         // agg first written by FIRST-chunk agg_add
    int* orig_perm = (int*)nf3;         // nf3 written only after last perm use
    int* snd_perm  = orig_perm + E2;
    float* efbuf   = (float*)(base + fixed);
    const bool alias_ok = ((size_t)N * 128 >= (size_t)2 * E2);

    // ---- chunking decision (host-side, deterministic) ----
    bool fast = false;
    size_t S = 0;   // chunk capacity in slots (slot = 32 floats = 128 B)
    int K = 0;
    if (alias_ok && ws_size > fixed) {
        size_t avail = ws_size - fixed;
        size_t maxSlots = (avail / 128) & ~(size_t)255;
        size_t wantSlots = ((size_t)E2 + 255) & ~(size_t)255;
        if (maxSlots >= wantSlots) { S = wantSlots; K = 1; fast = true; }
        else if (maxSlots >= 4096) {
            int k = (int)(((size_t)E2 + maxSlots - 1) / maxSlots);
            if (k <= 16) { S = maxSlots; K = k; fast = true; }
        }
    }

    // ---- common prologue ----
    hipMemsetAsync(ideg, 0, (size_t)N * 4, stream);
    k_count<<<nb_E, blk, 0, stream>>>(senders, receivers, ideg, E);
    node_enc_kernel<<<nb_N, blk, 0, stream>>>(node_raw, residues, emb, nWn1, nbn1, nWn2, nbn2, nf0, N);

    const int NPB = 64;
    const int nlb = (N + NPB - 1) / NPB;

    if (fast) {
        // CSR permutation
        k_blocksum<<<nb, blk, 0, stream>>>(ideg, bsum, N);
        k_scan_partials<<<1, 1024, 0, stream>>>(bsum, nb);
        k_blockscan<<<nb, blk, 0, stream>>>(ideg, bsum, offs, cursor, N);
        k_scatter<<<nb_E, blk, 0, stream>>>(senders, receivers, cursor, orig_perm, snd_perm, E);

        // ---- layer 0 ----
        for (int c = 0; c < K; ++c) {
            const int cLo = (int)((size_t)c * S);
            const int cHi = (int)((size_t)(c + 1) * S < (size_t)E2 ? (size_t)(c + 1) * S : (size_t)E2);
            const int cnt = cHi - cLo;
            if (cnt <= 0) break;
            ef0c_kernel<<<(cnt + 255) / 256, blk, 0, stream>>>(distances, edge_raw,
                orig_perm, snd_perm, nf0, eWe1, ebe1, eWe2, ebe2, l0We, l0Ws, l0be,
                efbuf, cLo, cnt);
            if (c == 0)
                agg_add_kernel<16, true><<<(N * 16 + 255) / 256, blk, 0, stream>>>(efbuf, offs, ideg, agg, N, cLo, cHi);
            else
                agg_add_kernel<16, false><<<(N * 16 + 255) / 256, blk, 0, stream>>>(efbuf, offs, ideg, agg, N, cLo, cHi);
        }
        node_layer_v2<16, 16, 32><<<nlb, blk, 0, stream>>>(nf0, agg, ideg, l0Wn, l0Wi, l0bn, nf1, N, NPB);

        // ---- layer 1 ----
        for (int c = 0; c < K; ++c) {
            const int cLo = (int)((size_t)c * S);
            const int cHi = (int)((size_t)(c + 1) * S < (size_t)E2 ? (size_t)(c + 1) * S : (size_t)E2);
            const int cnt = cHi - cLo;
            if (cnt <= 0) break;
            ef1c_kernel<<<(cnt + 255) / 256, blk, 0, stream>>>(distances, edge_raw,
                orig_perm, snd_perm, nf0, nf1, eWe1, ebe1, eWe2, ebe2,
                l0We, l0Ws, l0be, l1We, l1Ws, l1be, efbuf, cLo, cnt);
            if (c == 0)
                agg_add_kernel<32, true><<<(N * 32 + 255) / 256, blk, 0, stream>>>(efbuf, offs, ideg, agg, N, cLo, cHi);
            else
                agg_add_kernel<32, false><<<(N * 32 + 255) / 256, blk, 0, stream>>>(efbuf, offs, ideg, agg, N, cLo, cHi);
        }
        node_layer_v2<32, 32, 64><<<nlb, blk, 0, stream>>>(nf1, agg, ideg, l1Wn, l1Wi, l1bn, nf2, N, NPB);

        // ---- layer 2 (fused transform + aggregation; K==1 reuses ef1 in efbuf) ----
        for (int c = 0; c < K; ++c) {
            const int cLo = (int)((size_t)c * S);
            const int cHi = (int)((size_t)(c + 1) * S < (size_t)E2 ? (size_t)(c + 1) * S : (size_t)E2);
            const int cnt = cHi - cLo;
            if (cnt <= 0) break;
            if (K > 1) {
                ef1c_kernel<<<(cnt + 255) / 256, blk, 0, stream>>>(distances, edge_raw,
                    orig_perm, snd_perm, nf0, nf1, eWe1, ebe1, eWe2, ebe2,
                    l0We, l0Ws, l0be, l1We, l1Ws, l1be, efbuf, cLo, cnt);
            }
            if (c == 0)
                agg2_chunk_kernel<true><<<(N + 3) / 4, blk, 0, stream>>>(efbuf, nf2,
                    snd_perm, l2We, l2Ws, l2be, offs, ideg, agg, N, cLo, cHi);
            else
                agg2_chunk_kernel<false><<<(N + 3) / 4, blk, 0, stream>>>(efbuf, nf2,
                    snd_perm, l2We, l2Ws, l2be, offs, ideg, agg, N, cLo, cHi);
        }
        // writes nf3 (clobbers perm arrays — safe, last use was above)
        node_layer_v2<64, 64, 128><<<nlb, blk, 0, stream>>>(nf2, agg, ideg, l2Wn, l2Wi, l2bn, nf3, N, NPB);
    } else {
        // verified scatter fallback
        hipMemsetAsync(agg, 0, (size_t)N * 16 * 4, stream);
        edge_scatter_kernel<0><<<nb_E2, blk, 0, stream>>>(distances, edge_raw, senders, receivers,
            nf0, nf0, nf0, eWe1, ebe1, eWe2, ebe2,
            l0We, l0Ws, l0be, l1We, l1Ws, l1be, l2We, l2Ws, l2be, agg, E, E2);
        node_layer_v2<16, 16, 32><<<nlb, blk, 0, stream>>>(nf0, agg, ideg, l0Wn, l0Wi, l0bn, nf1, N, NPB);

        hipMemsetAsync(agg, 0, (size_t)N * 32 * 4, stream);
        edge_scatter_kernel<1><<<nb_E2, blk, 0, stream>>>(distances, edge_raw, senders, receivers,
            nf0, nf1, nf1, eWe1, ebe1, eWe2, ebe2,
            l0We, l0Ws, l0be, l1We, l1Ws, l1be, l2We, l2Ws, l2be, agg, E, E2);
        node_layer_v2<32, 32, 64><<<nlb, blk, 0, stream>>>(nf1, agg, ideg, l1Wn, l1Wi, l1bn, nf2, N, NPB);

        hipMemsetAsync(agg, 0, (size_t)N * 64 * 4, stream);
        edge_scatter_kernel<2><<<nb_E2, blk, 0, stream>>>(distances, edge_raw, senders, receivers,
            nf0, nf1, nf2, eWe1, ebe1, eWe2, ebe2,
            l0We, l0Ws, l0be, l1We, l1Ws, l1be, l2We, l2Ws, l2be, agg, E, E2);
        node_layer_v2<64, 64, 128><<<nlb, blk, 0, stream>>>(nf2, agg, ideg, l2Wn, l2Wi, l2bn, nf3, N, NPB);
    }

    // ---- readout ----
    node_out_kernel<<<nb_N, blk, 0, stream>>>(nf3, roWn, robn, (float*)d_out, N);
    graph_out_kernel<<<G, blk, 0, stream>>>(nf3, gidx, roWg, robg, (float*)d_out + (size_t)2 * N, N);
}

// Round 7
// 2501.520 us; speedup vs baseline: 10.4938x; 1.0014x over previous
//
#include <hip/hip_runtime.h>
#include <cstdint>
#include <cstddef>

// ---------------- helpers ----------------

__device__ __forceinline__ float sigmoidf_(float x) {
    return 1.0f / (1.0f + __expf(-x));
}

template<int OUT>
__device__ __forceinline__ void load_bias(const float* __restrict__ b, float* __restrict__ acc) {
#pragma unroll
    for (int j = 0; j < OUT; ++j) acc[j] = b[j];
}

template<int OUT>
__device__ __forceinline__ void relu_v(float* __restrict__ acc) {
#pragma unroll
    for (int j = 0; j < OUT; ++j) acc[j] = fmaxf(acc[j], 0.0f);
}

// acc[OUT] += x[IN] @ W[IN,OUT]  (W row-major; W addresses wave-uniform)
template<int IN, int OUT>
__device__ __forceinline__ void mm_acc(const float* __restrict__ x,
                                       const float* __restrict__ W,
                                       float* __restrict__ acc) {
#pragma unroll 4
    for (int k = 0; k < IN; ++k) {
        const float v = x[k];
#pragma unroll
        for (int j = 0; j < OUT; ++j) acc[j] = fmaf(v, W[k * OUT + j], acc[j]);
    }
}

template<int WIDTH>
__device__ __forceinline__ void load_row(const float* __restrict__ p, float* __restrict__ x) {
#pragma unroll
    for (int k4 = 0; k4 < WIDTH / 4; ++k4) {
        float4 v = reinterpret_cast<const float4*>(p)[k4];
        x[k4 * 4 + 0] = v.x; x[k4 * 4 + 1] = v.y;
        x[k4 * 4 + 2] = v.z; x[k4 * 4 + 3] = v.w;
    }
}

// edge encoder: rbf(16)+raw(2) -> 4 -> 8 (relu after each)
__device__ __forceinline__ void enc_edge(int orig,
                                         const float* __restrict__ dist,
                                         const float* __restrict__ eraw,
                                         const float* __restrict__ We1, const float* __restrict__ be1,
                                         const float* __restrict__ We2, const float* __restrict__ be2,
                                         float* __restrict__ out8) {
    float x[18];
    const float d = dist[orig];
#pragma unroll
    for (int i = 0; i < 16; ++i) {
        const float c = (float)i * (20.0f / 15.0f);
        const float t = d - c;
        x[i] = __expf(-t * t);
    }
    x[16] = eraw[(size_t)orig * 2 + 0];
    x[17] = eraw[(size_t)orig * 2 + 1];
    float h[4];
    load_bias<4>(be1, h);
    mm_acc<18, 4>(x, We1, h);
    relu_v<4>(h);
    load_bias<8>(be2, out8);
    mm_acc<4, 8>(h, We2, out8);
    relu_v<8>(out8);
}

// chain: load nf0 row FIRST (hide gather latency under enc), then enc -> ef0[16]
__device__ __forceinline__ void chain_ef0(int orig, int s,
    const float* __restrict__ dist, const float* __restrict__ eraw,
    const float* __restrict__ eWe1, const float* __restrict__ ebe1,
    const float* __restrict__ eWe2, const float* __restrict__ ebe2,
    const float* __restrict__ We0, const float* __restrict__ Ws0, const float* __restrict__ b0,
    const float* __restrict__ nf0, float* __restrict__ a0)
{
    float x0[16];
    load_row<16>(nf0 + (size_t)s * 16, x0);   // issue gather early
    float enc[8];
    enc_edge(orig, dist, eraw, eWe1, ebe1, eWe2, ebe2, enc);
    load_bias<16>(b0, a0);
    mm_acc<8, 16>(enc, We0, a0);
    mm_acc<16, 16>(x0, Ws0, a0);
    relu_v<16>(a0);
}

__device__ __forceinline__ int lower_bound_i(const int* __restrict__ a, int n, int key) {
    int lo = 0, hi = n;
    while (lo < hi) {
        int mid = (lo + hi) >> 1;
        if (a[mid] < key) lo = mid + 1; else hi = mid;
    }
    return lo;
}

// ---------------- CSR build ----------------

__global__ void __launch_bounds__(256) k_count(
    const int* __restrict__ senders, const int* __restrict__ receivers,
    int* __restrict__ ideg, int E)
{
    const int e = blockIdx.x * blockDim.x + threadIdx.x;
    if (e >= E) return;
    atomicAdd(&ideg[receivers[e]], 1);
    atomicAdd(&ideg[senders[e]], 1);
}

__global__ void __launch_bounds__(256) k_blocksum(
    const int* __restrict__ ideg, int* __restrict__ bsum, int N)
{
    __shared__ int s[256];
    const int t = threadIdx.x;
    const int i = blockIdx.x * 256 + t;
    s[t] = (i < N) ? ideg[i] : 0;
    __syncthreads();
#pragma unroll
    for (int d = 128; d > 0; d >>= 1) {
        if (t < d) s[t] += s[t + d];
        __syncthreads();
    }
    if (t == 0) bsum[blockIdx.x] = s[0];
}

__global__ void __launch_bounds__(1024) k_scan_partials(int* __restrict__ bsum, int nb)
{
    __shared__ int s[1024];
    const int t = threadIdx.x;
    const int v = (t < nb) ? bsum[t] : 0;
    s[t] = v;
    __syncthreads();
    for (int d = 1; d < 1024; d <<= 1) {
        const int w = (t >= d) ? s[t - d] : 0;
        __syncthreads();
        s[t] += w;
        __syncthreads();
    }
    if (t < nb) bsum[t] = s[t] - v;   // exclusive
}

__global__ void __launch_bounds__(256) k_blockscan(
    const int* __restrict__ ideg, const int* __restrict__ bsum,
    int* __restrict__ offs, int* __restrict__ cursor, int N)
{
    __shared__ int s[256];
    const int t = threadIdx.x;
    const int i = blockIdx.x * 256 + t;
    const int v = (i < N) ? ideg[i] : 0;
    s[t] = v;
    __syncthreads();
    for (int d = 1; d < 256; d <<= 1) {
        const int w = (t >= d) ? s[t - d] : 0;
        __syncthreads();
        s[t] += w;
        __syncthreads();
    }
    if (i < N) {
        const int o = bsum[blockIdx.x] + s[t] - v;
        offs[i] = o;
        cursor[i] = o;
    }
}

// writes slot -> (orig edge, sender node) directly
__global__ void __launch_bounds__(256) k_scatter(
    const int* __restrict__ senders, const int* __restrict__ receivers,
    int* __restrict__ cursor, int* __restrict__ orig_perm, int* __restrict__ snd_perm, int E)
{
    const int e = blockIdx.x * blockDim.x + threadIdx.x;
    if (e >= E) return;
    const int se = senders[e];
    const int re = receivers[e];
    const int p = atomicAdd(&cursor[re], 1);
    orig_perm[p] = e;  snd_perm[p] = se;
    const int q = atomicAdd(&cursor[se], 1);
    orig_perm[q] = e;  snd_perm[q] = re;
}

// ---------------- shared kernels ----------------

// LDS-staged node encoder: coalesced load of 256 node_raw rows, then per-thread MLP.
__global__ void __launch_bounds__(256) node_enc_kernel(
    const float* __restrict__ node_raw, const int* __restrict__ residues,
    const float* __restrict__ emb,
    const float* __restrict__ Wn1, const float* __restrict__ bn1,
    const float* __restrict__ Wn2, const float* __restrict__ bn2,
    float* __restrict__ nf0, int N)
{
    __shared__ float raw[256 * 51];
    const int t = threadIdx.x;
    const int n0 = blockIdx.x * 256;
    int cnt = N - n0; if (cnt > 256) cnt = 256;
    const int tot = cnt * 51;
    for (int i = t; i < tot; i += 256)
        raw[i] = node_raw[(size_t)n0 * 51 + i];
    __syncthreads();

    const int n = n0 + t;
    if (n >= N) return;
    float h[8];
    load_bias<8>(bn1, h);
    {
        const float* er = emb + (size_t)residues[n] * 32;
        float x[32];
        load_row<32>(er, x);
        mm_acc<32, 8>(x, Wn1, h);
    }
    {
        const float* nr = &raw[t * 51];
#pragma unroll 4
        for (int k = 0; k < 51; ++k) {
            const float v = nr[k];
#pragma unroll
            for (int j = 0; j < 8; ++j) h[j] = fmaf(v, Wn1[(32 + k) * 8 + j], h[j]);
        }
    }
    relu_v<8>(h);
    float o[16];
    load_bias<16>(bn2, o);
    mm_acc<8, 16>(h, Wn2, o);
    relu_v<16>(o);
    float* dst = nf0 + (size_t)n * 16;
#pragma unroll
    for (int j = 0; j < 16; ++j) dst[j] = o[j];
}

// column-per-thread node layer: weights in VGPRs, x/agg rows broadcast.
// Used for the two small layers (<=64 weight regs).
template<int INN, int OE, int ON>
__global__ void __launch_bounds__(256) node_layer_v2(
    const float* __restrict__ nf_in, const float* __restrict__ agg, const int* __restrict__ ideg,
    const float* __restrict__ Wn, const float* __restrict__ Wi, const float* __restrict__ bn,
    float* __restrict__ nf_out, int N, int npb)
{
    constexpr int SUB = 256 / ON;
    const int j = threadIdx.x % ON;
    const int m = threadIdx.x / ON;

    float wn[INN], wi[OE];
#pragma unroll
    for (int k = 0; k < INN; ++k) wn[k] = Wn[k * ON + j];
#pragma unroll
    for (int k = 0; k < OE; ++k)  wi[k] = Wi[k * ON + j];
    const float bj = bn[j];

    const int n_begin = blockIdx.x * npb;
    int n_end = n_begin + npb;
    if (n_end > N) n_end = N;

    for (int n = n_begin + m; n < n_end; n += SUB) {
        const float* __restrict__ x  = nf_in + (size_t)n * INN;
        const float* __restrict__ ag = agg + (size_t)n * OE;
        const float inv = 1.0f / fmaxf((float)ideg[n], 1.0f);

        float p0 = bj, p1 = 0.0f, p2 = 0.0f, p3 = 0.0f;
#pragma unroll
        for (int k4 = 0; k4 < INN / 4; ++k4) {
            float4 v = reinterpret_cast<const float4*>(x)[k4];
            p0 = fmaf(v.x, wn[4 * k4 + 0], p0);
            p1 = fmaf(v.y, wn[4 * k4 + 1], p1);
            p2 = fmaf(v.z, wn[4 * k4 + 2], p2);
            p3 = fmaf(v.w, wn[4 * k4 + 3], p3);
        }
        float q0 = 0.0f, q1 = 0.0f, q2 = 0.0f, q3 = 0.0f;
#pragma unroll
        for (int k4 = 0; k4 < OE / 4; ++k4) {
            float4 v = reinterpret_cast<const float4*>(ag)[k4];
            q0 = fmaf(v.x, wi[4 * k4 + 0], q0);
            q1 = fmaf(v.y, wi[4 * k4 + 1], q1);
            q2 = fmaf(v.z, wi[4 * k4 + 2], q2);
            q3 = fmaf(v.w, wi[4 * k4 + 3], q3);
        }
        const float t = (p0 + p1) + (p2 + p3) + inv * ((q0 + q1) + (q2 + q3));
        nf_out[(size_t)n * ON + j] = fmaxf(t, 0.0f);
    }
}

// split-k node layer for 64->128: thread = (column j = tid>>1, k-half h = tid&1).
// Halves weight VGPRs (64 vs 128) -> double occupancy; combine via shfl_xor(1).
__global__ void __launch_bounds__(256) node_layer_v3(
    const float* __restrict__ nf_in, const float* __restrict__ agg, const int* __restrict__ ideg,
    const float* __restrict__ Wn, const float* __restrict__ Wi, const float* __restrict__ bn,
    float* __restrict__ nf_out, int N, int npb)
{
    const int j = threadIdx.x >> 1;     // output column 0..127
    const int h = threadIdx.x & 1;      // k-half 0/1

    float wn[32], wi[32];
#pragma unroll
    for (int k = 0; k < 32; ++k) wn[k] = Wn[(h * 32 + k) * 128 + j];
#pragma unroll
    for (int k = 0; k < 32; ++k) wi[k] = Wi[(h * 32 + k) * 128 + j];
    const float bj = bn[j];

    const int n_begin = blockIdx.x * npb;
    int n_end = n_begin + npb;
    if (n_end > N) n_end = N;

    for (int n = n_begin; n < n_end; ++n) {
        const float* __restrict__ x  = nf_in + (size_t)n * 64 + h * 32;
        const float* __restrict__ ag = agg  + (size_t)n * 64 + h * 32;
        const float inv = 1.0f / fmaxf((float)ideg[n], 1.0f);

        float p0 = 0.0f, p1 = 0.0f, p2 = 0.0f, p3 = 0.0f;
#pragma unroll
        for (int k4 = 0; k4 < 8; ++k4) {
            float4 v = reinterpret_cast<const float4*>(x)[k4];
            p0 = fmaf(v.x, wn[4 * k4 + 0], p0);
            p1 = fmaf(v.y, wn[4 * k4 + 1], p1);
            p2 = fmaf(v.z, wn[4 * k4 + 2], p2);
            p3 = fmaf(v.w, wn[4 * k4 + 3], p3);
        }
        float q0 = 0.0f, q1 = 0.0f, q2 = 0.0f, q3 = 0.0f;
#pragma unroll
        for (int k4 = 0; k4 < 8; ++k4) {
            float4 v = reinterpret_cast<const float4*>(ag)[k4];
            q0 = fmaf(v.x, wi[4 * k4 + 0], q0);
            q1 = fmaf(v.y, wi[4 * k4 + 1], q1);
            q2 = fmaf(v.z, wi[4 * k4 + 2], q2);
            q3 = fmaf(v.w, wi[4 * k4 + 3], q3);
        }
        float t = (p0 + p1) + (p2 + p3) + inv * ((q0 + q1) + (q2 + q3));
        t += __shfl_xor(t, 1);
        if (h == 0)
            nf_out[(size_t)n * 128 + j] = fmaxf(t + bj, 0.0f);
    }
}

__global__ void __launch_bounds__(256) node_out_kernel(
    const float* __restrict__ nf3,
    const float* __restrict__ roWn, const float* __restrict__ robn,
    float* __restrict__ node_out, int N)
{
    const int n = blockIdx.x * blockDim.x + threadIdx.x;
    if (n >= N) return;
    const float* x = nf3 + (size_t)n * 128;
    float a0 = robn[0], a1 = robn[1];
#pragma unroll 4
    for (int k4 = 0; k4 < 32; ++k4) {
        float4 v = reinterpret_cast<const float4*>(x)[k4];
        const float vv[4] = {v.x, v.y, v.z, v.w};
#pragma unroll
        for (int u = 0; u < 4; ++u) {
            const int k = k4 * 4 + u;
            a0 = fmaf(vv[u], roWn[k * 2 + 0], a0);
            a1 = fmaf(vv[u], roWn[k * 2 + 1], a1);
        }
    }
    node_out[(size_t)n * 2 + 0] = sigmoidf_(a0);
    node_out[(size_t)n * 2 + 1] = sigmoidf_(a1);
}

__global__ void __launch_bounds__(256) graph_out_kernel(
    const float* __restrict__ nf3, const int* __restrict__ gidx,
    const float* __restrict__ roWg, const float* __restrict__ robg,
    float* __restrict__ glob_out, int N)
{
    __shared__ float sred[256];
    __shared__ float gm[128];
    const int g = blockIdx.x;
    const int t = threadIdx.x;
    const int lo = lower_bound_i(gidx, N, g);
    const int hi = lower_bound_i(gidx, N, g + 1);
    const int cnt = hi - lo;

    const int c = t & 127;
    const int h = t >> 7;
    float acc = 0.0f;
    for (int i = lo + h; i < hi; i += 2)
        acc += nf3[(size_t)i * 128 + c];
    sred[t] = acc;
    __syncthreads();
    if (t < 128) {
        const float m = (sred[t] + sred[t + 128]) / fmaxf((float)cnt, 1.0f);
        gm[t] = m * roWg[t];
    }
    __syncthreads();
    if (t < 64) gm[t] += gm[t + 64];
    __syncthreads();
    if (t < 32) gm[t] += gm[t + 32];
    __syncthreads();
    if (t < 16) gm[t] += gm[t + 16];
    __syncthreads();
    if (t == 0) {
        float s = 0.0f;
#pragma unroll
        for (int i = 0; i < 16; ++i) s += gm[i];
        glob_out[g] = sigmoidf_(s + robg[0]);
    }
}

// ---------------- fast path: chunked slot-ordered pipeline ----------------

__global__ void __launch_bounds__(256) ef0c_kernel(
    const float* __restrict__ dist, const float* __restrict__ eraw,
    const int* __restrict__ orig_perm, const int* __restrict__ snd_perm,
    const float* __restrict__ nf0,
    const float* __restrict__ eWe1, const float* __restrict__ ebe1,
    const float* __restrict__ eWe2, const float* __restrict__ ebe2,
    const float* __restrict__ We0, const float* __restrict__ Ws0, const float* __restrict__ b0,
    float* __restrict__ efb, int cLo, int cnt)
{
    const int g = blockIdx.x * blockDim.x + threadIdx.x;
    if (g >= cnt) return;
    const int orig = orig_perm[cLo + g];
    const int s    = snd_perm[cLo + g];
    float a0[16];
    chain_ef0(orig, s, dist, eraw, eWe1, ebe1, eWe2, ebe2, We0, Ws0, b0, nf0, a0);
    float* dst = efb + (size_t)g * 16;
#pragma unroll
    for (int j = 0; j < 16; ++j) dst[j] = a0[j];
}

__global__ void __launch_bounds__(256) ef1c_kernel(
    const float* __restrict__ dist, const float* __restrict__ eraw,
    const int* __restrict__ orig_perm, const int* __restrict__ snd_perm,
    const float* __restrict__ nf0, const float* __restrict__ nf1,
    const float* __restrict__ eWe1, const float* __restrict__ ebe1,
    const float* __restrict__ eWe2, const float* __restrict__ ebe2,
    const float* __restrict__ We0, const float* __restrict__ Ws0, const float* __restrict__ b0,
    const float* __restrict__ We1, const float* __restrict__ Ws1, const float* __restrict__ b1,
    float* __restrict__ efb, int cLo, int cnt)
{
    const int g = blockIdx.x * blockDim.x + threadIdx.x;
    if (g >= cnt) return;
    const int orig = orig_perm[cLo + g];
    const int s    = snd_perm[cLo + g];
    float x1[32];
    load_row<32>(nf1 + (size_t)s * 32, x1);    // issue gather early
    float a0[16];
    chain_ef0(orig, s, dist, eraw, eWe1, ebe1, eWe2, ebe2, We0, Ws0, b0, nf0, a0);
    float a1[32];
    load_bias<32>(b1, a1);
    mm_acc<16, 32>(a0, We1, a1);
    mm_acc<32, 32>(x1, Ws1, a1);
    relu_v<32>(a1);
    float* dst = efb + (size_t)g * 32;
#pragma unroll
    for (int j = 0; j < 32; ++j) dst[j] = a1[j];
}

// agg[n][c] (+)= sum over slots of node n intersected with chunk [cLo, cHi)
template<int OE, bool FIRST>
__global__ void __launch_bounds__(256) agg_add_kernel(
    const float* __restrict__ efb, const int* __restrict__ offs, const int* __restrict__ ideg,
    float* __restrict__ agg, int N, int cLo, int cHi)
{
    const int gid = blockIdx.x * blockDim.x + threadIdx.x;
    const int n = gid / OE;
    const int c = gid % OE;
    if (n >= N) return;
    int lo = offs[n];
    int hi = lo + ideg[n];
    lo = lo > cLo ? lo : cLo;
    hi = hi < cHi ? hi : cHi;
    if (!FIRST && lo >= hi) return;
    float acc = 0.0f;
    for (int p = lo; p < hi; ++p)
        acc += efb[(size_t)(p - cLo) * OE + c];
    if (FIRST) agg[(size_t)n * OE + c] = acc;
    else       agg[(size_t)n * OE + c] += acc;
}

// fused layer-2 transform + aggregation over one chunk: wave per node,
// lane = output column; weight columns in VGPRs; edge loop unrolled x2.
template<bool FIRST>
__global__ void __launch_bounds__(256) agg2_chunk_kernel(
    const float* __restrict__ efb, const float* __restrict__ nf2,
    const int* __restrict__ snd_perm,
    const float* __restrict__ We2, const float* __restrict__ Ws2, const float* __restrict__ b2,
    const int* __restrict__ offs, const int* __restrict__ ideg,
    float* __restrict__ agg, int N, int cLo, int cHi)
{
    const int wave = threadIdx.x >> 6;
    const int lane = threadIdx.x & 63;
    const int n = blockIdx.x * 4 + wave;
    if (n >= N) return;
    int lo = __builtin_amdgcn_readfirstlane(offs[n]);
    int hi = lo + __builtin_amdgcn_readfirstlane(ideg[n]);
    lo = lo > cLo ? lo : cLo;
    hi = hi < cHi ? hi : cHi;
    if (!FIRST && lo >= hi) return;

    float we[32], ws[64];
#pragma unroll
    for (int k = 0; k < 32; ++k) we[k] = We2[k * 64 + lane];
#pragma unroll
    for (int k = 0; k < 64; ++k) ws[k] = Ws2[k * 64 + lane];
    const float bias = b2[lane];

    float acc = 0.0f;
    int p = lo;
    // unroll x2: two independent edges in flight (loads of edge b overlap FMAs of a)
    for (; p + 2 <= hi; p += 2) {
        const int s0 = __builtin_amdgcn_readfirstlane(snd_perm[p]);
        const int s1 = __builtin_amdgcn_readfirstlane(snd_perm[p + 1]);
        const float* __restrict__ x1a = efb + (size_t)(p - cLo) * 32;
        const float* __restrict__ x1b = x1a + 32;
        const float* __restrict__ x2a = nf2 + (size_t)s0 * 64;
        const float* __restrict__ x2b = nf2 + (size_t)s1 * 64;
        float t0 = bias, t1 = bias;
#pragma unroll
        for (int k = 0; k < 32; ++k) {
            t0 = fmaf(x1a[k], we[k], t0);
            t1 = fmaf(x1b[k], we[k], t1);
        }
#pragma unroll
        for (int k = 0; k < 64; ++k) {
            t0 = fmaf(x2a[k], ws[k], t0);
            t1 = fmaf(x2b[k], ws[k], t1);
        }
        acc += fmaxf(t0, 0.0f) + fmaxf(t1, 0.0f);
    }
    if (p < hi) {
        const int s0 = __builtin_amdgcn_readfirstlane(snd_perm[p]);
        const float* __restrict__ x1a = efb + (size_t)(p - cLo) * 32;
        const float* __restrict__ x2a = nf2 + (size_t)s0 * 64;
        float t0 = bias;
#pragma unroll
        for (int k = 0; k < 32; ++k) t0 = fmaf(x1a[k], we[k], t0);
#pragma unroll
        for (int k = 0; k < 64; ++k) t0 = fmaf(x2a[k], ws[k], t0);
        acc += fmaxf(t0, 0.0f);
    }
    if (FIRST) agg[(size_t)n * 64 + lane] = acc;
    else       agg[(size_t)n * 64 + lane] += acc;
}

// ---------------- fallback path (verified round 1): atomic scatter ----------------

template<int LAYER>
__global__ void __launch_bounds__(256) edge_scatter_kernel(
    const float* __restrict__ dist, const float* __restrict__ eraw,
    const int* __restrict__ senders, const int* __restrict__ receivers,
    const float* __restrict__ nf0, const float* __restrict__ nf1, const float* __restrict__ nf2,
    const float* __restrict__ eWe1, const float* __restrict__ ebe1,
    const float* __restrict__ eWe2, const float* __restrict__ ebe2,
    const float* __restrict__ We0, const float* __restrict__ Ws0, const float* __restrict__ b0,
    const float* __restrict__ We1, const float* __restrict__ Ws1, const float* __restrict__ b1,
    const float* __restrict__ We2, const float* __restrict__ Ws2, const float* __restrict__ b2,
    float* __restrict__ agg, int E, int E2)
{
    const int e = blockIdx.x * blockDim.x + threadIdx.x;
    if (e >= E2) return;
    const int orig = (e < E) ? e : e - E;
    const int s = (e < E) ? senders[orig] : receivers[orig];
    const int r = (e < E) ? receivers[orig] : senders[orig];

    float a0[16];
    chain_ef0(orig, s, dist, eraw, eWe1, ebe1, eWe2, ebe2, We0, Ws0, b0, nf0, a0);

    if constexpr (LAYER == 0) {
        float* dst = agg + (size_t)r * 16;
#pragma unroll
        for (int j = 0; j < 16; ++j) atomicAdd(dst + j, a0[j]);
    } else {
        float a1[32];
        load_bias<32>(b1, a1);
        mm_acc<16, 32>(a0, We1, a1);
        {
            float x[32];
            load_row<32>(nf1 + (size_t)s * 32, x);
            mm_acc<32, 32>(x, Ws1, a1);
        }
        relu_v<32>(a1);

        if constexpr (LAYER == 1) {
            float* dst = agg + (size_t)r * 32;
#pragma unroll
            for (int j = 0; j < 32; ++j) atomicAdd(dst + j, a1[j]);
        } else {
            float a2[64];
            load_bias<64>(b2, a2);
            mm_acc<32, 64>(a1, We2, a2);
            {
                const float* xr = nf2 + (size_t)s * 64;
#pragma unroll
                for (int k4 = 0; k4 < 16; ++k4) {
                    float4 v = reinterpret_cast<const float4*>(xr)[k4];
                    const float vv[4] = {v.x, v.y, v.z, v.w};
#pragma unroll
                    for (int u = 0; u < 4; ++u) {
                        const float val = vv[u];
                        const int k = k4 * 4 + u;
#pragma unroll
                        for (int j = 0; j < 64; ++j) a2[j] = fmaf(val, Ws2[k * 64 + j], a2[j]);
                    }
                }
            }
            relu_v<64>(a2);
            float* dst = agg + (size_t)r * 64;
#pragma unroll
            for (int j = 0; j < 64; ++j) atomicAdd(dst + j, a2[j]);
        }
    }
}

// ---------------- launch ----------------

static inline size_t align_up(size_t x, size_t a) { return (x + a - 1) & ~(a - 1); }

extern "C" void kernel_launch(void* const* d_in, const int* in_sizes, int n_in,
                              void* d_out, int out_size, void* d_ws, size_t ws_size,
                              hipStream_t stream) {
    const float* node_raw  = (const float*)d_in[0];
    const float* edge_raw  = (const float*)d_in[1];
    const float* distances = (const float*)d_in[2];
    const int*   residues  = (const int*)d_in[3];
    const int*   senders   = (const int*)d_in[4];
    const int*   receivers = (const int*)d_in[5];
    const int*   gidx      = (const int*)d_in[6];
    const float* emb       = (const float*)d_in[7];
    const float* eWe1 = (const float*)d_in[8];  const float* ebe1 = (const float*)d_in[9];
    const float* eWe2 = (const float*)d_in[10]; const float* ebe2 = (const float*)d_in[11];
    const float* nWn1 = (const float*)d_in[12]; const float* nbn1 = (const float*)d_in[13];
    const float* nWn2 = (const float*)d_in[14]; const float* nbn2 = (const float*)d_in[15];
    const float* roWg = (const float*)d_in[16]; const float* robg = (const float*)d_in[17];
    const float* roWn = (const float*)d_in[18]; const float* robn = (const float*)d_in[19];
    const float* l0We = (const float*)d_in[20]; const float* l0Ws = (const float*)d_in[21];
    const float* l0be = (const float*)d_in[22]; const float* l0Wn = (const float*)d_in[23];
    const float* l0Wi = (const float*)d_in[24]; const float* l0bn = (const float*)d_in[25];
    const float* l1We = (const float*)d_in[26]; const float* l1Ws = (const float*)d_in[27];
    const float* l1be = (const float*)d_in[28]; const float* l1Wn = (const float*)d_in[29];
    const float* l1Wi = (const float*)d_in[30]; const float* l1bn = (const float*)d_in[31];
    const float* l2We = (const float*)d_in[32]; const float* l2Ws = (const float*)d_in[33];
    const float* l2be = (const float*)d_in[34]; const float* l2Wn = (const float*)d_in[35];
    const float* l2Wi = (const float*)d_in[36]; const float* l2bn = (const float*)d_in[37];

    const int N  = in_sizes[3];
    const int E  = in_sizes[2];
    const int G  = out_size - 2 * N;
    const int E2 = 2 * E;
    const int nb = (N + 255) / 256;

    const dim3 blk(256);
    const int nb_N  = (N + 255) / 256;
    const int nb_E  = (E + 255) / 256;
    const int nb_E2 = (E2 + 255) / 256;

    // ---- fixed workspace layout (~123 MB) ----
    char* base = (char*)d_ws;
    size_t off = 0;
    int* ideg = (int*)(base + off); off += align_up((size_t)N * 4, 16);
    int* offs = (int*)(base + off); off += align_up((size_t)N * 4, 16);
    int* bsum = (int*)(base + off); off += align_up((size_t)1024 * 4, 16);
    float* nf0 = (float*)(base + off); off += (size_t)N * 16 * 4;
    float* nf1 = (float*)(base + off); off += (size_t)N * 32 * 4;
    float* nf2 = (float*)(base + off); off += (size_t)N * 64 * 4;
    float* nf3 = (float*)(base + off); off += (size_t)N * 128 * 4;
    float* agg = (float*)(base + off); off += (size_t)N * 64 * 4;
    const size_t fixed = off;
    // aliases (lifetime-disjoint):
    int* cursor    = (int*)agg;         // agg first written by FIRST-chunk agg_add
    int* orig_perm = (int*)nf3;         // nf3 written only after last perm use
    int* snd_perm  = orig_perm + E2;
    float* efbuf   = (float*)(base + fixed);
    const bool alias_ok = ((size_t)N * 128 >= (size_t)2 * E2);

    // ---- chunking decision (host-side, deterministic) ----
    bool fast = false;
    size_t S = 0;   // chunk capacity in slots (slot = 32 floats = 128 B)
    int K = 0;
    if (alias_ok && ws_size > fixed) {
        size_t avail = ws_size - fixed;
        size_t maxSlots = (avail / 128) & ~(size_t)255;
        size_t wantSlots = ((size_t)E2 + 255) & ~(size_t)255;
        if (maxSlots >= wantSlots) { S = wantSlots; K = 1; fast = true; }
        else if (maxSlots >= 4096) {
            int k = (int)(((size_t)E2 + maxSlots - 1) / maxSlots);
            if (k <= 16) { S = maxSlots; K = k; fast = true; }
        }
    }

    // ---- common prologue ----
    hipMemsetAsync(ideg, 0, (size_t)N * 4, stream);
    k_count<<<nb_E, blk, 0, stream>>>(senders, receivers, ideg, E);
    node_enc_kernel<<<nb_N, blk, 0, stream>>>(node_raw, residues, emb, nWn1, nbn1, nWn2, nbn2, nf0, N);

    const int NPB = 64;                     // nodes/block for v2 layers
    const int nlb = (N + NPB - 1) / NPB;
    const int NPB3 = 32;                    // nodes/block for v3 (64->128)
    const int nlb3 = (N + NPB3 - 1) / NPB3;

    if (fast) {
        // CSR permutation
        k_blocksum<<<nb, blk, 0, stream>>>(ideg, bsum, N);
        k_scan_partials<<<1, 1024, 0, stream>>>(bsum, nb);
        k_blockscan<<<nb, blk, 0, stream>>>(ideg, bsum, offs, cursor, N);
        k_scatter<<<nb_E, blk, 0, stream>>>(senders, receivers, cursor, orig_perm, snd_perm, E);

        // ---- layer 0 ----
        for (int c = 0; c < K; ++c) {
            const int cLo = (int)((size_t)c * S);
            const int cHi = (int)((size_t)(c + 1) * S < (size_t)E2 ? (size_t)(c + 1) * S : (size_t)E2);
            const int cnt = cHi - cLo;
            if (cnt <= 0) break;
            ef0c_kernel<<<(cnt + 255) / 256, blk, 0, stream>>>(distances, edge_raw,
                orig_perm, snd_perm, nf0, eWe1, ebe1, eWe2, ebe2, l0We, l0Ws, l0be,
                efbuf, cLo, cnt);
            if (c == 0)
                agg_add_kernel<16, true><<<(N * 16 + 255) / 256, blk, 0, stream>>>(efbuf, offs, ideg, agg, N, cLo, cHi);
            else
                agg_add_kernel<16, false><<<(N * 16 + 255) / 256, blk, 0, stream>>>(efbuf, offs, ideg, agg, N, cLo, cHi);
        }
        node_layer_v2<16, 16, 32><<<nlb, blk, 0, stream>>>(nf0, agg, ideg, l0Wn, l0Wi, l0bn, nf1, N, NPB);

        // ---- layer 1 ----
        for (int c = 0; c < K; ++c) {
            const int cLo = (int)((size_t)c * S);
            const int cHi = (int)((size_t)(c + 1) * S < (size_t)E2 ? (size_t)(c + 1) * S : (size_t)E2);
            const int cnt = cHi - cLo;
            if (cnt <= 0) break;
            ef1c_kernel<<<(cnt + 255) / 256, blk, 0, stream>>>(distances, edge_raw,
                orig_perm, snd_perm, nf0, nf1, eWe1, ebe1, eWe2, ebe2,
                l0We, l0Ws, l0be, l1We, l1Ws, l1be, efbuf, cLo, cnt);
            if (c == 0)
                agg_add_kernel<32, true><<<(N * 32 + 255) / 256, blk, 0, stream>>>(efbuf, offs, ideg, agg, N, cLo, cHi);
            else
                agg_add_kernel<32, false><<<(N * 32 + 255) / 256, blk, 0, stream>>>(efbuf, offs, ideg, agg, N, cLo, cHi);
        }
        node_layer_v2<32, 32, 64><<<nlb, blk, 0, stream>>>(nf1, agg, ideg, l1Wn, l1Wi, l1bn, nf2, N, NPB);

        // ---- layer 2 (fused transform + aggregation; K==1 reuses ef1 in efbuf) ----
        for (int c = 0; c < K; ++c) {
            const int cLo = (int)((size_t)c * S);
            const int cHi = (int)((size_t)(c + 1) * S < (size_t)E2 ? (size_t)(c + 1) * S : (size_t)E2);
            const int cnt = cHi - cLo;
            if (cnt <= 0) break;
            if (K > 1) {
                ef1c_kernel<<<(cnt + 255) / 256, blk, 0, stream>>>(distances, edge_raw,
                    orig_perm, snd_perm, nf0, nf1, eWe1, ebe1, eWe2, ebe2,
                    l0We, l0Ws, l0be, l1We, l1Ws, l1be, efbuf, cLo, cnt);
            }
            if (c == 0)
                agg2_chunk_kernel<true><<<(N + 3) / 4, blk, 0, stream>>>(efbuf, nf2,
                    snd_perm, l2We, l2Ws, l2be, offs, ideg, agg, N, cLo, cHi);
            else
                agg2_chunk_kernel<false><<<(N + 3) / 4, blk, 0, stream>>>(efbuf, nf2,
                    snd_perm, l2We, l2Ws, l2be, offs, ideg, agg, N, cLo, cHi);
        }
        // writes nf3 (clobbers perm arrays — safe, last use was above)
        node_layer_v3<<<nlb3, blk, 0, stream>>>(nf2, agg, ideg, l2Wn, l2Wi, l2bn, nf3, N, NPB3);
    } else {
        // verified scatter fallback
        hipMemsetAsync(agg, 0, (size_t)N * 16 * 4, stream);
        edge_scatter_kernel<0><<<nb_E2, blk, 0, stream>>>(distances, edge_raw, senders, receivers,
            nf0, nf0, nf0, eWe1, ebe1, eWe2, ebe2,
            l0We, l0Ws, l0be, l1We, l1Ws, l1be, l2We, l2Ws, l2be, agg, E, E2);
        node_layer_v2<16, 16, 32><<<nlb, blk, 0, stream>>>(nf0, agg, ideg, l0Wn, l0Wi, l0bn, nf1, N, NPB);

        hipMemsetAsync(agg, 0, (size_t)N * 32 * 4, stream);
        edge_scatter_kernel<1><<<nb_E2, blk, 0, stream>>>(distances, edge_raw, senders, receivers,
            nf0, nf1, nf1, eWe1, ebe1, eWe2, ebe2,
            l0We, l0Ws, l0be, l1We, l1Ws, l1be, l2We, l2Ws, l2be, agg, E, E2);
        node_layer_v2<32, 32, 64><<<nlb, blk, 0, stream>>>(nf1, agg, ideg, l1Wn, l1Wi, l1bn, nf2, N, NPB);

        hipMemsetAsync(agg, 0, (size_t)N * 64 * 4, stream);
        edge_scatter_kernel<2><<<nb_E2, blk, 0, stream>>>(distances, edge_raw, senders, receivers,
            nf0, nf1, nf2, eWe1, ebe1, eWe2, ebe2,
            l0We, l0Ws, l0be, l1We, l1Ws, l1be, l2We, l2Ws, l2be, agg, E, E2);
        node_layer_v3<<<nlb3, blk, 0, stream>>>(nf2, agg, ideg, l2Wn, l2Wi, l2bn, nf3, N, NPB3);
    }

    // ---- readout ----
    node_out_kernel<<<nb_N, blk, 0, stream>>>(nf3, roWn, robn, (float*)d_out, N);
    graph_out_kernel<<<G, blk, 0, stream>>>(nf3, gidx, roWg, robg, (float*)d_out + (size_t)2 * N, N);
}

// Round 8
// 2127.043 us; speedup vs baseline: 12.3413x; 1.1761x over previous
//
#include <hip/hip_runtime.h>
#include <cstdint>
#include <cstddef>

// ---------------- helpers ----------------

__device__ __forceinline__ float sigmoidf_(float x) {
    return 1.0f / (1.0f + __expf(-x));
}

template<int OUT>
__device__ __forceinline__ void load_bias(const float* __restrict__ b, float* __restrict__ acc) {
#pragma unroll
    for (int j = 0; j < OUT; ++j) acc[j] = b[j];
}

template<int OUT>
__device__ __forceinline__ void relu_v(float* __restrict__ acc) {
#pragma unroll
    for (int j = 0; j < OUT; ++j) acc[j] = fmaxf(acc[j], 0.0f);
}

// acc[OUT] += x[IN] @ W[IN,OUT]  (W row-major; W addresses wave-uniform)
template<int IN, int OUT>
__device__ __forceinline__ void mm_acc(const float* __restrict__ x,
                                       const float* __restrict__ W,
                                       float* __restrict__ acc) {
#pragma unroll 4
    for (int k = 0; k < IN; ++k) {
        const float v = x[k];
#pragma unroll
        for (int j = 0; j < OUT; ++j) acc[j] = fmaf(v, W[k * OUT + j], acc[j]);
    }
}

template<int WIDTH>
__device__ __forceinline__ void load_row(const float* __restrict__ p, float* __restrict__ x) {
#pragma unroll
    for (int k4 = 0; k4 < WIDTH / 4; ++k4) {
        float4 v = reinterpret_cast<const float4*>(p)[k4];
        x[k4 * 4 + 0] = v.x; x[k4 * 4 + 1] = v.y;
        x[k4 * 4 + 2] = v.z; x[k4 * 4 + 3] = v.w;
    }
}

// edge encoder: rbf(16)+raw(2) -> 4 -> 8 (relu after each)
__device__ __forceinline__ void enc_edge(int orig,
                                         const float* __restrict__ dist,
                                         const float* __restrict__ eraw,
                                         const float* __restrict__ We1, const float* __restrict__ be1,
                                         const float* __restrict__ We2, const float* __restrict__ be2,
                                         float* __restrict__ out8) {
    float x[18];
    const float d = dist[orig];
#pragma unroll
    for (int i = 0; i < 16; ++i) {
        const float c = (float)i * (20.0f / 15.0f);
        const float t = d - c;
        x[i] = __expf(-t * t);
    }
    x[16] = eraw[(size_t)orig * 2 + 0];
    x[17] = eraw[(size_t)orig * 2 + 1];
    float h[4];
    load_bias<4>(be1, h);
    mm_acc<18, 4>(x, We1, h);
    relu_v<4>(h);
    load_bias<8>(be2, out8);
    mm_acc<4, 8>(h, We2, out8);
    relu_v<8>(out8);
}

// chain: load nf0 row FIRST (hide gather latency under enc), then enc -> ef0[16]
__device__ __forceinline__ void chain_ef0(int orig, int s,
    const float* __restrict__ dist, const float* __restrict__ eraw,
    const float* __restrict__ eWe1, const float* __restrict__ ebe1,
    const float* __restrict__ eWe2, const float* __restrict__ ebe2,
    const float* __restrict__ We0, const float* __restrict__ Ws0, const float* __restrict__ b0,
    const float* __restrict__ nf0, float* __restrict__ a0)
{
    float x0[16];
    load_row<16>(nf0 + (size_t)s * 16, x0);   // issue gather early
    float enc[8];
    enc_edge(orig, dist, eraw, eWe1, ebe1, eWe2, ebe2, enc);
    load_bias<16>(b0, a0);
    mm_acc<8, 16>(enc, We0, a0);
    mm_acc<16, 16>(x0, Ws0, a0);
    relu_v<16>(a0);
}

__device__ __forceinline__ int lower_bound_i(const int* __restrict__ a, int n, int key) {
    int lo = 0, hi = n;
    while (lo < hi) {
        int mid = (lo + hi) >> 1;
        if (a[mid] < key) lo = mid + 1; else hi = mid;
    }
    return lo;
}

// ---------------- CSR build ----------------

__global__ void __launch_bounds__(256) k_count(
    const int* __restrict__ senders, const int* __restrict__ receivers,
    int* __restrict__ ideg, int E)
{
    const int e = blockIdx.x * blockDim.x + threadIdx.x;
    if (e >= E) return;
    atomicAdd(&ideg[receivers[e]], 1);
    atomicAdd(&ideg[senders[e]], 1);
}

__global__ void __launch_bounds__(256) k_blocksum(
    const int* __restrict__ ideg, int* __restrict__ bsum, int N)
{
    __shared__ int s[256];
    const int t = threadIdx.x;
    const int i = blockIdx.x * 256 + t;
    s[t] = (i < N) ? ideg[i] : 0;
    __syncthreads();
#pragma unroll
    for (int d = 128; d > 0; d >>= 1) {
        if (t < d) s[t] += s[t + d];
        __syncthreads();
    }
    if (t == 0) bsum[blockIdx.x] = s[0];
}

__global__ void __launch_bounds__(1024) k_scan_partials(int* __restrict__ bsum, int nb)
{
    __shared__ int s[1024];
    const int t = threadIdx.x;
    const int v = (t < nb) ? bsum[t] : 0;
    s[t] = v;
    __syncthreads();
    for (int d = 1; d < 1024; d <<= 1) {
        const int w = (t >= d) ? s[t - d] : 0;
        __syncthreads();
        s[t] += w;
        __syncthreads();
    }
    if (t < nb) bsum[t] = s[t] - v;   // exclusive
}

__global__ void __launch_bounds__(256) k_blockscan(
    const int* __restrict__ ideg, const int* __restrict__ bsum,
    int* __restrict__ offs, int* __restrict__ cursor, int N)
{
    __shared__ int s[256];
    const int t = threadIdx.x;
    const int i = blockIdx.x * 256 + t;
    const int v = (i < N) ? ideg[i] : 0;
    s[t] = v;
    __syncthreads();
    for (int d = 1; d < 256; d <<= 1) {
        const int w = (t >= d) ? s[t - d] : 0;
        __syncthreads();
        s[t] += w;
        __syncthreads();
    }
    if (i < N) {
        const int o = bsum[blockIdx.x] + s[t] - v;
        offs[i] = o;
        cursor[i] = o;
    }
}

// writes slot -> (orig edge, sender node) directly
__global__ void __launch_bounds__(256) k_scatter(
    const int* __restrict__ senders, const int* __restrict__ receivers,
    int* __restrict__ cursor, int* __restrict__ orig_perm, int* __restrict__ snd_perm, int E)
{
    const int e = blockIdx.x * blockDim.x + threadIdx.x;
    if (e >= E) return;
    const int se = senders[e];
    const int re = receivers[e];
    const int p = atomicAdd(&cursor[re], 1);
    orig_perm[p] = e;  snd_perm[p] = se;
    const int q = atomicAdd(&cursor[se], 1);
    orig_perm[q] = e;  snd_perm[q] = re;
}

// ---------------- shared kernels ----------------

// LDS-staged node encoder: coalesced load of 256 node_raw rows, then per-thread MLP.
__global__ void __launch_bounds__(256) node_enc_kernel(
    const float* __restrict__ node_raw, const int* __restrict__ residues,
    const float* __restrict__ emb,
    const float* __restrict__ Wn1, const float* __restrict__ bn1,
    const float* __restrict__ Wn2, const float* __restrict__ bn2,
    float* __restrict__ nf0, int N)
{
    __shared__ float raw[256 * 51];
    const int t = threadIdx.x;
    const int n0 = blockIdx.x * 256;
    int cnt = N - n0; if (cnt > 256) cnt = 256;
    const int tot = cnt * 51;
    for (int i = t; i < tot; i += 256)
        raw[i] = node_raw[(size_t)n0 * 51 + i];
    __syncthreads();

    const int n = n0 + t;
    if (n >= N) return;
    float h[8];
    load_bias<8>(bn1, h);
    {
        const float* er = emb + (size_t)residues[n] * 32;
        float x[32];
        load_row<32>(er, x);
        mm_acc<32, 8>(x, Wn1, h);
    }
    {
        const float* nr = &raw[t * 51];
#pragma unroll 4
        for (int k = 0; k < 51; ++k) {
            const float v = nr[k];
#pragma unroll
            for (int j = 0; j < 8; ++j) h[j] = fmaf(v, Wn1[(32 + k) * 8 + j], h[j]);
        }
    }
    relu_v<8>(h);
    float o[16];
    load_bias<16>(bn2, o);
    mm_acc<8, 16>(h, Wn2, o);
    relu_v<16>(o);
    float* dst = nf0 + (size_t)n * 16;
#pragma unroll
    for (int j = 0; j < 16; ++j) dst[j] = o[j];
}

// LDS-tiled node layer (small): block stages 64 nodes of x+agg into LDS with
// coalesced float4 loads, then thread=(column j, node-sublane m) computes from
// LDS broadcast reads. Weights in VGPRs (<=64/thread).
template<int INN, int OE, int ON>
__global__ void __launch_bounds__(256) node_layer_v4(
    const float* __restrict__ nf_in, const float* __restrict__ agg, const int* __restrict__ ideg,
    const float* __restrict__ Wn, const float* __restrict__ Wi, const float* __restrict__ bn,
    float* __restrict__ nf_out, int N)
{
    constexpr int BN = 64;
    __shared__ float xs[BN * INN];
    __shared__ float as_[BN * OE];
    __shared__ float inv_s[BN];
    const int t = threadIdx.x;
    const int n0 = blockIdx.x * BN;
    int cnt = N - n0; if (cnt > BN) cnt = BN;
    if (cnt <= 0) return;

    {
        const float4* gx = reinterpret_cast<const float4*>(nf_in + (size_t)n0 * INN);
        float4* lx = reinterpret_cast<float4*>(xs);
        const int nx = cnt * INN / 4;
        for (int i = t; i < nx; i += 256) lx[i] = gx[i];
        const float4* ga = reinterpret_cast<const float4*>(agg + (size_t)n0 * OE);
        float4* la = reinterpret_cast<float4*>(as_);
        const int na = cnt * OE / 4;
        for (int i = t; i < na; i += 256) la[i] = ga[i];
        if (t < cnt) inv_s[t] = 1.0f / fmaxf((float)ideg[n0 + t], 1.0f);
    }
    __syncthreads();

    constexpr int SUB = 256 / ON;
    const int j = t % ON;
    const int m = t / ON;

    float wn[INN], wi[OE];
#pragma unroll
    for (int k = 0; k < INN; ++k) wn[k] = Wn[k * ON + j];
#pragma unroll
    for (int k = 0; k < OE; ++k)  wi[k] = Wi[k * ON + j];
    const float bj = bn[j];

    for (int nl = m; nl < cnt; nl += SUB) {
        const float4* x4 = reinterpret_cast<const float4*>(&xs[nl * INN]);
        const float4* a4 = reinterpret_cast<const float4*>(&as_[nl * OE]);
        const float inv = inv_s[nl];

        float p0 = bj, p1 = 0.0f, p2 = 0.0f, p3 = 0.0f;
#pragma unroll
        for (int k4 = 0; k4 < INN / 4; ++k4) {
            float4 v = x4[k4];
            p0 = fmaf(v.x, wn[4 * k4 + 0], p0);
            p1 = fmaf(v.y, wn[4 * k4 + 1], p1);
            p2 = fmaf(v.z, wn[4 * k4 + 2], p2);
            p3 = fmaf(v.w, wn[4 * k4 + 3], p3);
        }
        float q0 = 0.0f, q1 = 0.0f, q2 = 0.0f, q3 = 0.0f;
#pragma unroll
        for (int k4 = 0; k4 < OE / 4; ++k4) {
            float4 v = a4[k4];
            q0 = fmaf(v.x, wi[4 * k4 + 0], q0);
            q1 = fmaf(v.y, wi[4 * k4 + 1], q1);
            q2 = fmaf(v.z, wi[4 * k4 + 2], q2);
            q3 = fmaf(v.w, wi[4 * k4 + 3], q3);
        }
        const float r = (p0 + p1) + (p2 + p3) + inv * ((q0 + q1) + (q2 + q3));
        nf_out[(size_t)(n0 + nl) * ON + j] = fmaxf(r, 0.0f);
    }
}

// LDS-tiled split-k node layer for 64->128: thread=(column j=tid>>1, k-half h=tid&1).
__global__ void __launch_bounds__(256) node_layer_v4b(
    const float* __restrict__ nf_in, const float* __restrict__ agg, const int* __restrict__ ideg,
    const float* __restrict__ Wn, const float* __restrict__ Wi, const float* __restrict__ bn,
    float* __restrict__ nf_out, int N)
{
    constexpr int BN = 64;
    __shared__ float xs[BN * 64];
    __shared__ float as_[BN * 64];
    __shared__ float inv_s[BN];
    const int t = threadIdx.x;
    const int n0 = blockIdx.x * BN;
    int cnt = N - n0; if (cnt > BN) cnt = BN;
    if (cnt <= 0) return;

    {
        const float4* gx = reinterpret_cast<const float4*>(nf_in + (size_t)n0 * 64);
        float4* lx = reinterpret_cast<float4*>(xs);
        const int nx = cnt * 16;
        for (int i = t; i < nx; i += 256) lx[i] = gx[i];
        const float4* ga = reinterpret_cast<const float4*>(agg + (size_t)n0 * 64);
        float4* la = reinterpret_cast<float4*>(as_);
        for (int i = t; i < nx; i += 256) la[i] = ga[i];
        if (t < cnt) inv_s[t] = 1.0f / fmaxf((float)ideg[n0 + t], 1.0f);
    }
    __syncthreads();

    const int j = t >> 1;     // output column 0..127
    const int h = t & 1;      // k-half 0/1

    float wn[32], wi[32];
#pragma unroll
    for (int k = 0; k < 32; ++k) wn[k] = Wn[(h * 32 + k) * 128 + j];
#pragma unroll
    for (int k = 0; k < 32; ++k) wi[k] = Wi[(h * 32 + k) * 128 + j];
    const float bj = bn[j];

    for (int nl = 0; nl < cnt; ++nl) {
        const float4* x4 = reinterpret_cast<const float4*>(&xs[nl * 64 + h * 32]);
        const float4* a4 = reinterpret_cast<const float4*>(&as_[nl * 64 + h * 32]);

        float p0 = 0.0f, p1 = 0.0f, p2 = 0.0f, p3 = 0.0f;
#pragma unroll
        for (int k4 = 0; k4 < 8; ++k4) {
            float4 v = x4[k4];
            p0 = fmaf(v.x, wn[4 * k4 + 0], p0);
            p1 = fmaf(v.y, wn[4 * k4 + 1], p1);
            p2 = fmaf(v.z, wn[4 * k4 + 2], p2);
            p3 = fmaf(v.w, wn[4 * k4 + 3], p3);
        }
        float q0 = 0.0f, q1 = 0.0f, q2 = 0.0f, q3 = 0.0f;
#pragma unroll
        for (int k4 = 0; k4 < 8; ++k4) {
            float4 v = a4[k4];
            q0 = fmaf(v.x, wi[4 * k4 + 0], q0);
            q1 = fmaf(v.y, wi[4 * k4 + 1], q1);
            q2 = fmaf(v.z, wi[4 * k4 + 2], q2);
            q3 = fmaf(v.w, wi[4 * k4 + 3], q3);
        }
        float r = (p0 + p1) + (p2 + p3) + inv_s[nl] * ((q0 + q1) + (q2 + q3));
        r += __shfl_xor(r, 1);
        if (h == 0)
            nf_out[(size_t)(n0 + nl) * 128 + j] = fmaxf(r + bj, 0.0f);
    }
}

__global__ void __launch_bounds__(256) node_out_kernel(
    const float* __restrict__ nf3,
    const float* __restrict__ roWn, const float* __restrict__ robn,
    float* __restrict__ node_out, int N)
{
    const int n = blockIdx.x * blockDim.x + threadIdx.x;
    if (n >= N) return;
    const float* x = nf3 + (size_t)n * 128;
    float a0 = robn[0], a1 = robn[1];
#pragma unroll 4
    for (int k4 = 0; k4 < 32; ++k4) {
        float4 v = reinterpret_cast<const float4*>(x)[k4];
        const float vv[4] = {v.x, v.y, v.z, v.w};
#pragma unroll
        for (int u = 0; u < 4; ++u) {
            const int k = k4 * 4 + u;
            a0 = fmaf(vv[u], roWn[k * 2 + 0], a0);
            a1 = fmaf(vv[u], roWn[k * 2 + 1], a1);
        }
    }
    node_out[(size_t)n * 2 + 0] = sigmoidf_(a0);
    node_out[(size_t)n * 2 + 1] = sigmoidf_(a1);
}

__global__ void __launch_bounds__(256) graph_out_kernel(
    const float* __restrict__ nf3, const int* __restrict__ gidx,
    const float* __restrict__ roWg, const float* __restrict__ robg,
    float* __restrict__ glob_out, int N)
{
    __shared__ float sred[256];
    __shared__ float gm[128];
    const int g = blockIdx.x;
    const int t = threadIdx.x;
    const int lo = lower_bound_i(gidx, N, g);
    const int hi = lower_bound_i(gidx, N, g + 1);
    const int cnt = hi - lo;

    const int c = t & 127;
    const int h = t >> 7;
    float acc = 0.0f;
    for (int i = lo + h; i < hi; i += 2)
        acc += nf3[(size_t)i * 128 + c];
    sred[t] = acc;
    __syncthreads();
    if (t < 128) {
        const float m = (sred[t] + sred[t + 128]) / fmaxf((float)cnt, 1.0f);
        gm[t] = m * roWg[t];
    }
    __syncthreads();
    if (t < 64) gm[t] += gm[t + 64];
    __syncthreads();
    if (t < 32) gm[t] += gm[t + 32];
    __syncthreads();
    if (t < 16) gm[t] += gm[t + 16];
    __syncthreads();
    if (t == 0) {
        float s = 0.0f;
#pragma unroll
        for (int i = 0; i < 16; ++i) s += gm[i];
        glob_out[g] = sigmoidf_(s + robg[0]);
    }
}

// ---------------- fast path: chunked slot-ordered pipeline ----------------

__global__ void __launch_bounds__(256) ef0c_kernel(
    const float* __restrict__ dist, const float* __restrict__ eraw,
    const int* __restrict__ orig_perm, const int* __restrict__ snd_perm,
    const float* __restrict__ nf0,
    const float* __restrict__ eWe1, const float* __restrict__ ebe1,
    const float* __restrict__ eWe2, const float* __restrict__ ebe2,
    const float* __restrict__ We0, const float* __restrict__ Ws0, const float* __restrict__ b0,
    float* __restrict__ efb, int cLo, int cnt)
{
    const int g = blockIdx.x * blockDim.x + threadIdx.x;
    if (g >= cnt) return;
    const int orig = orig_perm[cLo + g];
    const int s    = snd_perm[cLo + g];
    float a0[16];
    chain_ef0(orig, s, dist, eraw, eWe1, ebe1, eWe2, ebe2, We0, Ws0, b0, nf0, a0);
    float* dst = efb + (size_t)g * 16;
#pragma unroll
    for (int j = 0; j < 16; ++j) dst[j] = a0[j];
}

__global__ void __launch_bounds__(256) ef1c_kernel(
    const float* __restrict__ dist, const float* __restrict__ eraw,
    const int* __restrict__ orig_perm, const int* __restrict__ snd_perm,
    const float* __restrict__ nf0, const float* __restrict__ nf1,
    const float* __restrict__ eWe1, const float* __restrict__ ebe1,
    const float* __restrict__ eWe2, const float* __restrict__ ebe2,
    const float* __restrict__ We0, const float* __restrict__ Ws0, const float* __restrict__ b0,
    const float* __restrict__ We1, const float* __restrict__ Ws1, const float* __restrict__ b1,
    float* __restrict__ efb, int cLo, int cnt)
{
    const int g = blockIdx.x * blockDim.x + threadIdx.x;
    if (g >= cnt) return;
    const int orig = orig_perm[cLo + g];
    const int s    = snd_perm[cLo + g];
    float x1[32];
    load_row<32>(nf1 + (size_t)s * 32, x1);    // issue gather early
    float a0[16];
    chain_ef0(orig, s, dist, eraw, eWe1, ebe1, eWe2, ebe2, We0, Ws0, b0, nf0, a0);
    float a1[32];
    load_bias<32>(b1, a1);
    mm_acc<16, 32>(a0, We1, a1);
    mm_acc<32, 32>(x1, Ws1, a1);
    relu_v<32>(a1);
    float* dst = efb + (size_t)g * 32;
#pragma unroll
    for (int j = 0; j < 32; ++j) dst[j] = a1[j];
}

// agg[n][c] (+)= sum over slots of node n intersected with chunk [cLo, cHi)
template<int OE, bool FIRST>
__global__ void __launch_bounds__(256) agg_add_kernel(
    const float* __restrict__ efb, const int* __restrict__ offs, const int* __restrict__ ideg,
    float* __restrict__ agg, int N, int cLo, int cHi)
{
    const int gid = blockIdx.x * blockDim.x + threadIdx.x;
    const int n = gid / OE;
    const int c = gid % OE;
    if (n >= N) return;
    int lo = offs[n];
    int hi = lo + ideg[n];
    lo = lo > cLo ? lo : cLo;
    hi = hi < cHi ? hi : cHi;
    if (!FIRST && lo >= hi) return;
    float acc = 0.0f;
    for (int p = lo; p < hi; ++p)
        acc += efb[(size_t)(p - cLo) * OE + c];
    if (FIRST) agg[(size_t)n * OE + c] = acc;
    else       agg[(size_t)n * OE + c] += acc;
}

// fused layer-2 transform + aggregation over one chunk: wave per node,
// lane = output column; weight columns in VGPRs; edge loop unrolled x2.
template<bool FIRST>
__global__ void __launch_bounds__(256) agg2_chunk_kernel(
    const float* __restrict__ efb, const float* __restrict__ nf2,
    const int* __restrict__ snd_perm,
    const float* __restrict__ We2, const float* __restrict__ Ws2, const float* __restrict__ b2,
    const int* __restrict__ offs, const int* __restrict__ ideg,
    float* __restrict__ agg, int N, int cLo, int cHi)
{
    const int wave = threadIdx.x >> 6;
    const int lane = threadIdx.x & 63;
    const int n = blockIdx.x * 4 + wave;
    if (n >= N) return;
    int lo = __builtin_amdgcn_readfirstlane(offs[n]);
    int hi = lo + __builtin_amdgcn_readfirstlane(ideg[n]);
    lo = lo > cLo ? lo : cLo;
    hi = hi < cHi ? hi : cHi;
    if (!FIRST && lo >= hi) return;

    float we[32], ws[64];
#pragma unroll
    for (int k = 0; k < 32; ++k) we[k] = We2[k * 64 + lane];
#pragma unroll
    for (int k = 0; k < 64; ++k) ws[k] = Ws2[k * 64 + lane];
    const float bias = b2[lane];

    float acc = 0.0f;
    int p = lo;
    for (; p + 2 <= hi; p += 2) {
        const int s0 = __builtin_amdgcn_readfirstlane(snd_perm[p]);
        const int s1 = __builtin_amdgcn_readfirstlane(snd_perm[p + 1]);
        const float* __restrict__ x1a = efb + (size_t)(p - cLo) * 32;
        const float* __restrict__ x1b = x1a + 32;
        const float* __restrict__ x2a = nf2 + (size_t)s0 * 64;
        const float* __restrict__ x2b = nf2 + (size_t)s1 * 64;
        float t0 = bias, t1 = bias;
#pragma unroll
        for (int k = 0; k < 32; ++k) {
            t0 = fmaf(x1a[k], we[k], t0);
            t1 = fmaf(x1b[k], we[k], t1);
        }
#pragma unroll
        for (int k = 0; k < 64; ++k) {
            t0 = fmaf(x2a[k], ws[k], t0);
            t1 = fmaf(x2b[k], ws[k], t1);
        }
        acc += fmaxf(t0, 0.0f) + fmaxf(t1, 0.0f);
    }
    if (p < hi) {
        const int s0 = __builtin_amdgcn_readfirstlane(snd_perm[p]);
        const float* __restrict__ x1a = efb + (size_t)(p - cLo) * 32;
        const float* __restrict__ x2a = nf2 + (size_t)s0 * 64;
        float t0 = bias;
#pragma unroll
        for (int k = 0; k < 32; ++k) t0 = fmaf(x1a[k], we[k], t0);
#pragma unroll
        for (int k = 0; k < 64; ++k) t0 = fmaf(x2a[k], ws[k], t0);
        acc += fmaxf(t0, 0.0f);
    }
    if (FIRST) agg[(size_t)n * 64 + lane] = acc;
    else       agg[(size_t)n * 64 + lane] += acc;
}

// ---------------- fallback path (verified round 1): atomic scatter ----------------

template<int LAYER>
__global__ void __launch_bounds__(256) edge_scatter_kernel(
    const float* __restrict__ dist, const float* __restrict__ eraw,
    const int* __restrict__ senders, const int* __restrict__ receivers,
    const float* __restrict__ nf0, const float* __restrict__ nf1, const float* __restrict__ nf2,
    const float* __restrict__ eWe1, const float* __restrict__ ebe1,
    const float* __restrict__ eWe2, const float* __restrict__ ebe2,
    const float* __restrict__ We0, const float* __restrict__ Ws0, const float* __restrict__ b0,
    const float* __restrict__ We1, const float* __restrict__ Ws1, const float* __restrict__ b1,
    const float* __restrict__ We2, const float* __restrict__ Ws2, const float* __restrict__ b2,
    float* __restrict__ agg, int E, int E2)
{
    const int e = blockIdx.x * blockDim.x + threadIdx.x;
    if (e >= E2) return;
    const int orig = (e < E) ? e : e - E;
    const int s = (e < E) ? senders[orig] : receivers[orig];
    const int r = (e < E) ? receivers[orig] : senders[orig];

    float a0[16];
    chain_ef0(orig, s, dist, eraw, eWe1, ebe1, eWe2, ebe2, We0, Ws0, b0, nf0, a0);

    if constexpr (LAYER == 0) {
        float* dst = agg + (size_t)r * 16;
#pragma unroll
        for (int j = 0; j < 16; ++j) atomicAdd(dst + j, a0[j]);
    } else {
        float a1[32];
        load_bias<32>(b1, a1);
        mm_acc<16, 32>(a0, We1, a1);
        {
            float x[32];
            load_row<32>(nf1 + (size_t)s * 32, x);
            mm_acc<32, 32>(x, Ws1, a1);
        }
        relu_v<32>(a1);

        if constexpr (LAYER == 1) {
            float* dst = agg + (size_t)r * 32;
#pragma unroll
            for (int j = 0; j < 32; ++j) atomicAdd(dst + j, a1[j]);
        } else {
            float a2[64];
            load_bias<64>(b2, a2);
            mm_acc<32, 64>(a1, We2, a2);
            {
                const float* xr = nf2 + (size_t)s * 64;
#pragma unroll
                for (int k4 = 0; k4 < 16; ++k4) {
                    float4 v = reinterpret_cast<const float4*>(xr)[k4];
                    const float vv[4] = {v.x, v.y, v.z, v.w};
#pragma unroll
                    for (int u = 0; u < 4; ++u) {
                        const float val = vv[u];
                        const int k = k4 * 4 + u;
#pragma unroll
                        for (int j = 0; j < 64; ++j) a2[j] = fmaf(val, Ws2[k * 64 + j], a2[j]);
                    }
                }
            }
            relu_v<64>(a2);
            float* dst = agg + (size_t)r * 64;
#pragma unroll
            for (int j = 0; j < 64; ++j) atomicAdd(dst + j, a2[j]);
        }
    }
}

// ---------------- launch ----------------

static inline size_t align_up(size_t x, size_t a) { return (x + a - 1) & ~(a - 1); }

extern "C" void kernel_launch(void* const* d_in, const int* in_sizes, int n_in,
                              void* d_out, int out_size, void* d_ws, size_t ws_size,
                              hipStream_t stream) {
    const float* node_raw  = (const float*)d_in[0];
    const float* edge_raw  = (const float*)d_in[1];
    const float* distances = (const float*)d_in[2];
    const int*   residues  = (const int*)d_in[3];
    const int*   senders   = (const int*)d_in[4];
    const int*   receivers = (const int*)d_in[5];
    const int*   gidx      = (const int*)d_in[6];
    const float* emb       = (const float*)d_in[7];
    const float* eWe1 = (const float*)d_in[8];  const float* ebe1 = (const float*)d_in[9];
    const float* eWe2 = (const float*)d_in[10]; const float* ebe2 = (const float*)d_in[11];
    const float* nWn1 = (const float*)d_in[12]; const float* nbn1 = (const float*)d_in[13];
    const float* nWn2 = (const float*)d_in[14]; const float* nbn2 = (const float*)d_in[15];
    const float* roWg = (const float*)d_in[16]; const float* robg = (const float*)d_in[17];
    const float* roWn = (const float*)d_in[18]; const float* robn = (const float*)d_in[19];
    const float* l0We = (const float*)d_in[20]; const float* l0Ws = (const float*)d_in[21];
    const float* l0be = (const float*)d_in[22]; const float* l0Wn = (const float*)d_in[23];
    const float* l0Wi = (const float*)d_in[24]; const float* l0bn = (const float*)d_in[25];
    const float* l1We = (const float*)d_in[26]; const float* l1Ws = (const float*)d_in[27];
    const float* l1be = (const float*)d_in[28]; const float* l1Wn = (const float*)d_in[29];
    const float* l1Wi = (const float*)d_in[30]; const float* l1bn = (const float*)d_in[31];
    const float* l2We = (const float*)d_in[32]; const float* l2Ws = (const float*)d_in[33];
    const float* l2be = (const float*)d_in[34]; const float* l2Wn = (const float*)d_in[35];
    const float* l2Wi = (const float*)d_in[36]; const float* l2bn = (const float*)d_in[37];

    const int N  = in_sizes[3];
    const int E  = in_sizes[2];
    const int G  = out_size - 2 * N;
    const int E2 = 2 * E;
    const int nb = (N + 255) / 256;

    const dim3 blk(256);
    const int nb_N  = (N + 255) / 256;
    const int nb_E  = (E + 255) / 256;
    const int nb_E2 = (E2 + 255) / 256;
    const int nlb64 = (N + 63) / 64;      // blocks for v4 layers (64 nodes/block)

    // ---- fixed workspace layout (~123 MB) ----
    char* base = (char*)d_ws;
    size_t off = 0;
    int* ideg = (int*)(base + off); off += align_up((size_t)N * 4, 16);
    int* offs = (int*)(base + off); off += align_up((size_t)N * 4, 16);
    int* bsum = (int*)(base + off); off += align_up((size_t)1024 * 4, 16);
    float* nf0 = (float*)(base + off); off += (size_t)N * 16 * 4;
    float* nf1 = (float*)(base + off); off += (size_t)N * 32 * 4;
    float* nf2 = (float*)(base + off); off += (size_t)N * 64 * 4;
    float* nf3 = (float*)(base + off); off += (size_t)N * 128 * 4;
    float* agg = (float*)(base + off); off += (size_t)N * 64 * 4;
    const size_t fixed = off;
    // aliases (lifetime-disjoint):
    int* cursor    = (int*)agg;         // agg first written by FIRST-chunk agg_add
    int* orig_perm = (int*)nf3;         // nf3 written only after last perm use
    int* snd_perm  = orig_perm + E2;
    float* efbuf   = (float*)(base + fixed);
    const bool alias_ok = ((size_t)N * 128 >= (size_t)2 * E2);

    // ---- chunking decision (host-side, deterministic) ----
    bool fast = false;
    size_t S = 0;   // chunk capacity in slots (slot = 32 floats = 128 B)
    int K = 0;
    if (alias_ok && ws_size > fixed) {
        size_t avail = ws_size - fixed;
        size_t maxSlots = (avail / 128) & ~(size_t)255;
        size_t wantSlots = ((size_t)E2 + 255) & ~(size_t)255;
        if (maxSlots >= wantSlots) { S = wantSlots; K = 1; fast = true; }
        else if (maxSlots >= 4096) {
            int k = (int)(((size_t)E2 + maxSlots - 1) / maxSlots);
            if (k <= 16) { S = maxSlots; K = k; fast = true; }
        }
    }

    // ---- common prologue ----
    hipMemsetAsync(ideg, 0, (size_t)N * 4, stream);
    k_count<<<nb_E, blk, 0, stream>>>(senders, receivers, ideg, E);
    node_enc_kernel<<<nb_N, blk, 0, stream>>>(node_raw, residues, emb, nWn1, nbn1, nWn2, nbn2, nf0, N);

    if (fast) {
        // CSR permutation
        k_blocksum<<<nb, blk, 0, stream>>>(ideg, bsum, N);
        k_scan_partials<<<1, 1024, 0, stream>>>(bsum, nb);
        k_blockscan<<<nb, blk, 0, stream>>>(ideg, bsum, offs, cursor, N);
        k_scatter<<<nb_E, blk, 0, stream>>>(senders, receivers, cursor, orig_perm, snd_perm, E);

        // ---- layer 0 ----
        for (int c = 0; c < K; ++c) {
            const int cLo = (int)((size_t)c * S);
            const int cHi = (int)((size_t)(c + 1) * S < (size_t)E2 ? (size_t)(c + 1) * S : (size_t)E2);
            const int cnt = cHi - cLo;
            if (cnt <= 0) break;
            ef0c_kernel<<<(cnt + 255) / 256, blk, 0, stream>>>(distances, edge_raw,
                orig_perm, snd_perm, nf0, eWe1, ebe1, eWe2, ebe2, l0We, l0Ws, l0be,
                efbuf, cLo, cnt);
            if (c == 0)
                agg_add_kernel<16, true><<<(N * 16 + 255) / 256, blk, 0, stream>>>(efbuf, offs, ideg, agg, N, cLo, cHi);
            else
                agg_add_kernel<16, false><<<(N * 16 + 255) / 256, blk, 0, stream>>>(efbuf, offs, ideg, agg, N, cLo, cHi);
        }
        node_layer_v4<16, 16, 32><<<nlb64, blk, 0, stream>>>(nf0, agg, ideg, l0Wn, l0Wi, l0bn, nf1, N);

        // ---- layer 1 ----
        for (int c = 0; c < K; ++c) {
            const int cLo = (int)((size_t)c * S);
            const int cHi = (int)((size_t)(c + 1) * S < (size_t)E2 ? (size_t)(c + 1) * S : (size_t)E2);
            const int cnt = cHi - cLo;
            if (cnt <= 0) break;
            ef1c_kernel<<<(cnt + 255) / 256, blk, 0, stream>>>(distances, edge_raw,
                orig_perm, snd_perm, nf0, nf1, eWe1, ebe1, eWe2, ebe2,
                l0We, l0Ws, l0be, l1We, l1Ws, l1be, efbuf, cLo, cnt);
            if (c == 0)
                agg_add_kernel<32, true><<<(N * 32 + 255) / 256, blk, 0, stream>>>(efbuf, offs, ideg, agg, N, cLo, cHi);
            else
                agg_add_kernel<32, false><<<(N * 32 + 255) / 256, blk, 0, stream>>>(efbuf, offs, ideg, agg, N, cLo, cHi);
        }
        node_layer_v4<32, 32, 64><<<nlb64, blk, 0, stream>>>(nf1, agg, ideg, l1Wn, l1Wi, l1bn, nf2, N);

        // ---- layer 2 (fused transform + aggregation; K==1 reuses ef1 in efbuf) ----
        for (int c = 0; c < K; ++c) {
            const int cLo = (int)((size_t)c * S);
            const int cHi = (int)((size_t)(c + 1) * S < (size_t)E2 ? (size_t)(c + 1) * S : (size_t)E2);
            const int cnt = cHi - cLo;
            if (cnt <= 0) break;
            if (K > 1) {
                ef1c_kernel<<<(cnt + 255) / 256, blk, 0, stream>>>(distances, edge_raw,
                    orig_perm, snd_perm, nf0, nf1, eWe1, ebe1, eWe2, ebe2,
                    l0We, l0Ws, l0be, l1We, l1Ws, l1be, efbuf, cLo, cnt);
            }
            if (c == 0)
                agg2_chunk_kernel<true><<<(N + 3) / 4, blk, 0, stream>>>(efbuf, nf2,
                    snd_perm, l2We, l2Ws, l2be, offs, ideg, agg, N, cLo, cHi);
            else
                agg2_chunk_kernel<false><<<(N + 3) / 4, blk, 0, stream>>>(efbuf, nf2,
                    snd_perm, l2We, l2Ws, l2be, offs, ideg, agg, N, cLo, cHi);
        }
        // writes nf3 (clobbers perm arrays — safe, last use was above)
        node_layer_v4b<<<nlb64, blk, 0, stream>>>(nf2, agg, ideg, l2Wn, l2Wi, l2bn, nf3, N);
    } else {
        // verified scatter fallback
        hipMemsetAsync(agg, 0, (size_t)N * 16 * 4, stream);
        edge_scatter_kernel<0><<<nb_E2, blk, 0, stream>>>(distances, edge_raw, senders, receivers,
            nf0, nf0, nf0, eWe1, ebe1, eWe2, ebe2,
            l0We, l0Ws, l0be, l1We, l1Ws, l1be, l2We, l2Ws, l2be, agg, E, E2);
        node_layer_v4<16, 16, 32><<<nlb64, blk, 0, stream>>>(nf0, agg, ideg, l0Wn, l0Wi, l0bn, nf1, N);

        hipMemsetAsync(agg, 0, (size_t)N * 32 * 4, stream);
        edge_scatter_kernel<1><<<nb_E2, blk, 0, stream>>>(distances, edge_raw, senders, receivers,
            nf0, nf1, nf1, eWe1, ebe1, eWe2, ebe2,
            l0We, l0Ws, l0be, l1We, l1Ws, l1be, l2We, l2Ws, l2be, agg, E, E2);
        node_layer_v4<32, 32, 64><<<nlb64, blk, 0, stream>>>(nf1, agg, ideg, l1Wn, l1Wi, l1bn, nf2, N);

        hipMemsetAsync(agg, 0, (size_t)N * 64 * 4, stream);
        edge_scatter_kernel<2><<<nb_E2, blk, 0, stream>>>(distances, edge_raw, senders, receivers,
            nf0, nf1, nf2, eWe1, ebe1, eWe2, ebe2,
            l0We, l0Ws, l0be, l1We, l1Ws, l1be, l2We, l2Ws, l2be, agg, E, E2);
        node_layer_v4b<<<nlb64, blk, 0, stream>>>(nf2, agg, ideg, l2Wn, l2Wi, l2bn, nf3, N);
    }

    // ---- readout ----
    node_out_kernel<<<nb_N, blk, 0, stream>>>(nf3, roWn, robn, (float*)d_out, N);
    graph_out_kernel<<<G, blk, 0, stream>>>(nf3, gidx, roWg, robg, (float*)d_out + (size_t)2 * N, N);
}